// Round 8
// baseline (381.441 us; speedup 1.0000x reference)
//
#include <hip/hip_runtime.h>

#define B_ 4
#define T_ 4096
#define D_ 512
#define H_ 8
#define DH_ 64
#define NH_ 4
#define NB_ 64            // n_buckets = T/BUCKET
#define BH_ (B_*H_)       // 32
#define CHUNKS_ (NH_*NB_) // 256
#define NTICK_ (NH_*T_)   // 16384
#define M_ (B_*T_)        // 16384
#define FFN_ 2048

typedef __attribute__((ext_vector_type(8))) short bf16x8;
typedef __attribute__((ext_vector_type(4))) float f32x4;

// ---------- bf16 helpers ----------
__device__ __forceinline__ unsigned short f2bf(float x) {
  unsigned int u = __float_as_uint(x);
  return (unsigned short)((u + 0x7FFFu + ((u >> 16) & 1u)) >> 16);
}
__device__ __forceinline__ float bf2f(unsigned short s) {
  return __uint_as_float(((unsigned int)s) << 16);
}
__device__ __forceinline__ unsigned int cvt_pk_bf16(float lo, float hi) {
  unsigned int r;
  asm("v_cvt_pk_bf16_f32 %0, %1, %2" : "=v"(r) : "v"(lo), "v"(hi));
  return r;
}

// ---------- async global->LDS, 16B per lane ----------
__device__ __forceinline__ void gld_lds16(const void* g, void* l) {
  __builtin_amdgcn_global_load_lds(
      (const __attribute__((address_space(1))) unsigned int*)g,
      (__attribute__((address_space(3))) unsigned int*)l, 16, 0, 0);
}

// swizzled LDS offsets (shorts): XOR 16B-granule with (row ^ row>>3)&7
__device__ __forceinline__ int swf(int row) { return (row ^ (row >> 3)) & 7; }
__device__ __forceinline__ int off64(int row, int k) {
  return row * 64 + (((k >> 3) ^ swf(row)) << 3) + (k & 7);
}
__device__ __forceinline__ int off128(int row, int k) {
  return row * 128 + (((k >> 3) ^ swf(row)) << 3) + (k & 7);
}

// ---------- bf16 MFMA GEMM: C = op(A @ BT^T) ----------
// MODE 1: bf16 out (stride N).  MODE 3: fused qk+v — N logical 1024;
//   n0<512: qk (f32 Cf + bf16 Cb + invn, K=1024 split);
//   n0>=512: v (bf16 Cb2, Keff=512 hi halves).
// FUSE_COMB: A-stage = on-the-fly combine of 4 hash rounds (A=orows, lgin=logits).
template<int BM, int MODE, bool HAS_BIAS, bool RELU, bool HAS_RESID, bool FUSE_COMB>
__global__ __launch_bounds__(256) void gemm_bf16(
    const unsigned short* __restrict__ A, const unsigned short* __restrict__ BT,
    const float* __restrict__ bias, const unsigned short* __restrict__ resid,
    float* __restrict__ Cf, unsigned short* __restrict__ Cb,
    unsigned short* __restrict__ Cb2, const float* __restrict__ lgin,
    float* __restrict__ invn,
    int M, int N, int K, int lda, int ldbt, int ldr)
{
  constexpr int MI = BM / 32;
  __shared__ __align__(16) unsigned short smem[(BM + 128) * 64];  // As|Bs, then C-tile
  unsigned short* As = smem;
  unsigned short* Bs = smem + BM * 64;
  const int tid = threadIdx.x;
  const int lane = tid & 63;
  const int w = tid >> 6;
  const int wm = (w >> 1) * (BM / 2), wn = (w & 1) * 64;
  const int g = lane >> 4, cl = lane & 15;

  // XCD-aware block swizzle (T1): XCD k owns contiguous tile range
  const int gx = gridDim.x;
  const int id = blockIdx.x + blockIdx.y * gx;
  const int cpx = (gx * gridDim.y) >> 3;
  const int swz = (id & 7) * cpx + (id >> 3);
  const int m0 = (swz / gx) * BM, n0 = (swz % gx) * 128;

  const bool isv = (MODE == 3) && (n0 >= 512);
  const int Keff = isv ? (K >> 1) : K;

  f32x4 acc[MI][4];
#pragma unroll
  for (int i = 0; i < MI; ++i)
#pragma unroll
    for (int j = 0; j < 4; ++j) acc[i][j] = (f32x4){0.f, 0.f, 0.f, 0.f};

  const int srow = tid >> 3;
  const int skc  = (tid & 7) * 8;

  for (int k0 = 0; k0 < Keff; k0 += 64) {
    if constexpr (FUSE_COMB) {
      // A-stage = combine 4 hash rounds for head (k0>>6), rows of this tile
      const int head = k0 >> 6;
#pragma unroll
      for (int ci = 0; ci < BM / 32; ++ci) {
        const int m = m0 + ci * 32 + srow;
        const int bb = m >> 12, t = m & (T_ - 1);
        const size_t bht = (size_t)(bb * 8 + head) * T_ + t;
        const float4 lg = *(const float4*)&lgin[bht * NH_];
        const float mx = fmaxf(fmaxf(lg.x, lg.y), fmaxf(lg.z, lg.w));
        const float w0 = __expf(lg.x - mx), w1 = __expf(lg.y - mx);
        const float w2 = __expf(lg.z - mx), w3 = __expf(lg.w - mx);
        const float wiv = 1.f / (w0 + w1 + w2 + w3);
        const size_t ob = bht * (NH_ * DH_) + skc;
        const uint4 u0 = *(const uint4*)&A[ob];
        const uint4 u1 = *(const uint4*)&A[ob + DH_];
        const uint4 u2 = *(const uint4*)&A[ob + 2 * DH_];
        const uint4 u3 = *(const uint4*)&A[ob + 3 * DH_];
        const unsigned short* p0 = (const unsigned short*)&u0;
        const unsigned short* p1 = (const unsigned short*)&u1;
        const unsigned short* p2 = (const unsigned short*)&u2;
        const unsigned short* p3 = (const unsigned short*)&u3;
        unsigned short op[8];
#pragma unroll
        for (int e = 0; e < 8; e += 2) {
          const float a0 = (w0 * bf2f(p0[e]) + w1 * bf2f(p1[e])
                          + w2 * bf2f(p2[e]) + w3 * bf2f(p3[e])) * wiv;
          const float a1 = (w0 * bf2f(p0[e + 1]) + w1 * bf2f(p1[e + 1])
                          + w2 * bf2f(p2[e + 1]) + w3 * bf2f(p3[e + 1])) * wiv;
          const unsigned int pk = cvt_pk_bf16(a0, a1);
          op[e] = (unsigned short)pk; op[e + 1] = (unsigned short)(pk >> 16);
        }
        *(uint4*)&As[ci * 2048 + tid * 8] = *(const uint4*)&op[0];
      }
    } else {
#pragma unroll
      for (int ci = 0; ci < BM / 32; ++ci)
        gld_lds16(&A[(size_t)(m0 + ci * 32 + srow) * lda + k0 + skc],
                  &As[ci * 2048 + tid * 8]);
    }
#pragma unroll
    for (int ci = 0; ci < 4; ++ci)
      gld_lds16(&BT[(size_t)(n0 + ci * 32 + srow) * ldbt + k0 + skc],
                &Bs[ci * 2048 + tid * 8]);
    __syncthreads();
#pragma unroll
    for (int kk = 0; kk < 64; kk += 32) {
      bf16x8 af[MI], bfr[4];
#pragma unroll
      for (int i = 0; i < MI; ++i)
        af[i] = *(const bf16x8*)&As[(wm + i * 16 + cl) * 64 + kk + g * 8];
#pragma unroll
      for (int j = 0; j < 4; ++j)
        bfr[j] = *(const bf16x8*)&Bs[(wn + j * 16 + cl) * 64 + kk + g * 8];
#pragma unroll
      for (int i = 0; i < MI; ++i)
#pragma unroll
        for (int j = 0; j < 4; ++j)
          acc[i][j] = __builtin_amdgcn_mfma_f32_16x16x32_bf16(af[i], bfr[j], acc[i][j], 0, 0, 0);
    }
    __syncthreads();
  }

  // ---- epilogue: regs -> LDS C-tile (swizzled) -> coalesced out
  float bv[4];
  if constexpr (HAS_BIAS) {
#pragma unroll
    for (int j = 0; j < 4; ++j) bv[j] = bias[n0 + wn + j * 16 + cl];
  }
#pragma unroll
  for (int i = 0; i < MI; ++i) {
#pragma unroll
    for (int r = 0; r < 4; ++r) {
      const int lrow = wm + i * 16 + g * 4 + r;
      float v4[4];
      float ss = 0.f;
#pragma unroll
      for (int j = 0; j < 4; ++j) {
        float val = acc[i][j][r];
        if constexpr (HAS_BIAS) val += bv[j];
        if constexpr (RELU) val = fmaxf(val, 0.f);
        v4[j] = val;
        if constexpr (MODE == 3) {
          if (!isv) {
            ss += val * val;
            Cf[(size_t)(m0 + lrow) * 512 + n0 + wn + j * 16 + cl] = val;
          }
        }
      }
      const unsigned int p01 = cvt_pk_bf16(v4[0], v4[1]);
      const unsigned int p23 = cvt_pk_bf16(v4[2], v4[3]);
      const int sw = (lrow & 7) << 3;
      smem[lrow * 128 + ((wn +  0 + cl) ^ sw)] = (unsigned short)p01;
      smem[lrow * 128 + ((wn + 16 + cl) ^ sw)] = (unsigned short)(p01 >> 16);
      smem[lrow * 128 + ((wn + 32 + cl) ^ sw)] = (unsigned short)p23;
      smem[lrow * 128 + ((wn + 48 + cl) ^ sw)] = (unsigned short)(p23 >> 16);
      if constexpr (MODE == 3) {
        if (!isv) {
          ss += __shfl_xor(ss, 1); ss += __shfl_xor(ss, 2);
          ss += __shfl_xor(ss, 4); ss += __shfl_xor(ss, 8);
          if (cl == 0) {
            const int m = m0 + lrow;
            const int bb = m >> 12, t = m & (T_ - 1);
            const int hh = ((n0 + wn) >> 6) & 7;
            invn[((size_t)(bb * 8 + hh)) * T_ + t] = 1.0f / (sqrtf(ss) + 1e-6f);
          }
        }
      }
    }
  }
  __syncthreads();
#pragma unroll
  for (int l = 0; l < BM / 16; ++l) {
    const int idx = tid + l * 256;
    const int row = idx >> 4, c8 = (idx & 15) * 8;
    uint4 u = *(const uint4*)&smem[row * 128 + (c8 ^ ((row & 7) << 3))];
    if constexpr (HAS_RESID) {
      const uint4 rv = *(const uint4*)&resid[(size_t)(m0 + row) * ldr + n0 + c8];
      const unsigned short* sp = (const unsigned short*)&u;
      const unsigned short* rp = (const unsigned short*)&rv;
      float f[8];
#pragma unroll
      for (int e = 0; e < 8; ++e) f[e] = bf2f(sp[e]) + bf2f(rp[e]);
      u.x = cvt_pk_bf16(f[0], f[1]); u.y = cvt_pk_bf16(f[2], f[3]);
      u.z = cvt_pk_bf16(f[4], f[5]); u.w = cvt_pk_bf16(f[6], f[7]);
    }
    if constexpr (MODE == 3) {
      if (isv)
        *(uint4*)&Cb2[(size_t)(m0 + row) * 512 + (n0 - 512) + c8] = u;
      else
        *(uint4*)&Cb[(size_t)(m0 + row) * 512 + n0 + c8] = u;
    } else {
      *(uint4*)&Cb[(size_t)(m0 + row) * N + n0 + c8] = u;
    }
  }
}

// ---------- fused prep: transpose(+split) weights + split src rows ----------
__global__ __launch_bounds__(256) void prep_all(
    const float* __restrict__ Wqk, const float* __restrict__ Wv,
    const float* __restrict__ Wout, const float* __restrict__ W1,
    const float* __restrict__ W2, const float* __restrict__ src,
    unsigned short* __restrict__ WqkvTp, unsigned short* __restrict__ WoutT,
    unsigned short* __restrict__ W1T, unsigned short* __restrict__ W2T,
    unsigned short* __restrict__ src_pair)
{
  __shared__ float tile[32][33];
  int bid = blockIdx.x;
  if (bid >= 2816) {
    const int i = (bid - 2816) * 256 + threadIdx.x;
    const int gpr = D_ >> 3;
    const int m = i / gpr, d0 = (i - m * gpr) * 8;
    float x[8];
    *(float4*)&x[0] = *(const float4*)&src[(size_t)m * D_ + d0];
    *(float4*)&x[4] = *(const float4*)&src[(size_t)m * D_ + d0 + 4];
    unsigned short hi[8], lo[8];
#pragma unroll
    for (int e = 0; e < 8; ++e) {
      hi[e] = f2bf(x[e]);
      lo[e] = f2bf(x[e] - bf2f(hi[e]));
    }
    *(uint4*)&src_pair[(size_t)m * 2 * D_ + d0]      = *(const uint4*)&hi[0];
    *(uint4*)&src_pair[(size_t)m * 2 * D_ + D_ + d0] = *(const uint4*)&lo[0];
    return;
  }
  const float* W; unsigned short* WT; int K, N, bx, by; bool split = false;
  if (bid < 256)        { W = Wqk;  WT = WqkvTp; K = 512;  N = 512;  split = true;
                          bx = bid & 15; by = bid >> 4; }
  else if (bid < 512)   { bid -= 256;  W = Wv; WT = WqkvTp + (size_t)512 * 1024;
                          K = 512; N = 512; split = true;
                          bx = bid & 15; by = bid >> 4; }
  else if (bid < 768)   { bid -= 512;  W = Wout; WT = WoutT; K = 512;  N = 512;
                          bx = bid & 15; by = bid >> 4; }
  else if (bid < 1792)  { bid -= 768;  W = W1;   WT = W1T;   K = 512;  N = 2048;
                          bx = bid & 63; by = bid >> 6; }
  else                  { bid -= 1792; W = W2;   WT = W2T;   K = 2048; N = 512;
                          bx = bid & 15; by = bid >> 4; }
  const int k0 = by * 32, n0 = bx * 32;
  const int tx = threadIdx.x & 31, ty = threadIdx.x >> 5;
#pragma unroll
  for (int r = 0; r < 32; r += 8)
    tile[ty + r][tx] = W[(size_t)(k0 + ty + r) * N + n0 + tx];
  __syncthreads();
  const int ld = split ? 2 * K : K;
#pragma unroll
  for (int r = 0; r < 32; r += 8) {
    const float x = tile[tx][ty + r];
    const unsigned short hi = f2bf(x);
    WT[(size_t)(n0 + ty + r) * ld + k0 + tx] = hi;
    if (split)
      WT[(size_t)(n0 + ty + r) * ld + K + k0 + tx] = f2bf(x - bf2f(hi));
  }
}

// ---------- LSH hashing as GEMM + fused argmax (reads fp32 qk) ----------
__global__ __launch_bounds__(256) void hash_gemm_kernel(
    const float* __restrict__ qk, const float* __restrict__ rot,
    int* __restrict__ buckets)
{
  __shared__ __align__(16) float As[64][136];   // [k][m]
  __shared__ __align__(16) float Bs[64][132];   // [k][n]
  const int tid = threadIdx.x;
  const int tx = tid & 15, ty = tid >> 4;
  const int t0 = blockIdx.x * 128, bh = blockIdx.y;
  const int b = bh >> 3, hd = bh & 7;

#pragma unroll
  for (int l = 0; l < 8; ++l) {
    const int idx = tid + l * 256;
    const int row = idx >> 4;
    const int kq = (idx & 15) << 2;
    const float4 a = *(const float4*)&qk[((size_t)b * T_ + t0 + row) * D_ + hd * DH_ + kq];
    As[kq + 0][row] = a.x; As[kq + 1][row] = a.y;
    As[kq + 2][row] = a.z; As[kq + 3][row] = a.w;
  }
#pragma unroll
  for (int l = 0; l < 8; ++l) {
    const int idx = tid + l * 256;
    const int kr = idx >> 5;
    const int c4 = (idx & 31) << 2;
    *(float4*)&Bs[kr][c4] = *(const float4*)&rot[kr * 128 + c4];
  }
  __syncthreads();

  float acc[8][8];
#pragma unroll
  for (int i = 0; i < 8; ++i)
#pragma unroll
    for (int j = 0; j < 8; ++j) acc[i][j] = 0.f;

#pragma unroll 4
  for (int kk = 0; kk < 64; ++kk) {
    float a[8], bq[8];
    *(float4*)&a[0]  = *(const float4*)&As[kk][ty * 8];
    *(float4*)&a[4]  = *(const float4*)&As[kk][ty * 8 + 4];
    *(float4*)&bq[0] = *(const float4*)&Bs[kk][tx * 8];
    *(float4*)&bq[4] = *(const float4*)&Bs[kk][tx * 8 + 4];
#pragma unroll
    for (int i = 0; i < 8; ++i)
#pragma unroll
      for (int j = 0; j < 8; ++j)
        acc[i][j] = fmaf(a[i], bq[j], acc[i][j]);
  }
  __syncthreads();

  float* pval = &As[0][0];
  int*   pidx = (int*)&Bs[0][0];
  const int i0 = (tx & 3) * 8;
#pragma unroll
  for (int r = 0; r < 8; ++r) {
    float v = -3.0e38f; int idx = 127;
#pragma unroll
    for (int j = 0; j < 8; ++j) {
      const float p = acc[r][j];
      const int li = i0 + j;
      if (p > v || (p == v && li < idx)) { v = p; idx = li; }
      const float n = -p;
      const int ni = 32 + li;
      if (n > v || (n == v && ni < idx)) { v = n; idx = ni; }
    }
    pval[(ty * 8 + r) * 16 + tx] = v;
    pidx[(ty * 8 + r) * 16 + tx] = idx;
  }
  __syncthreads();

#pragma unroll
  for (int l = 0; l < 2; ++l) {
    const int id = tid + l * 256;
    const int tok = id >> 2, hh = id & 3;
    float v = pval[tok * 16 + hh * 4];
    int idx = pidx[tok * 16 + hh * 4];
#pragma unroll
    for (int e = 1; e < 4; ++e) {
      const float ov = pval[tok * 16 + hh * 4 + e];
      const int oi = pidx[tok * 16 + hh * 4 + e];
      if (ov > v || (ov == v && oi < idx)) { v = ov; idx = oi; }
    }
    buckets[((size_t)bh * NH_ + hh) * T_ + t0 + tok] = idx + hh * NB_;
  }
}

// ---------- per-bh bucket histogram + exclusive scan ----------
__global__ __launch_bounds__(256) void hist_kernel(
    const int* __restrict__ buckets, int* __restrict__ bstart)
{
  __shared__ int bins[256];
  const int bh = blockIdx.x;
  bins[threadIdx.x] = 0;
  __syncthreads();
  for (int e = threadIdx.x; e < NTICK_; e += 256)
    atomicAdd(&bins[buckets[(size_t)bh * NTICK_ + e]], 1);
  __syncthreads();
  if (threadIdx.x == 0) {
    int run = 0;
    for (int i = 0; i < 256; ++i) { const int c = bins[i]; bins[i] = run; run += c; }
  }
  __syncthreads();
  bstart[bh * 256 + threadIdx.x] = bins[threadIdx.x];
}

// ---------- stable compaction ----------
__global__ __launch_bounds__(64) void compact_kernel(
    const int* __restrict__ buckets, const int* __restrict__ bstart,
    int* __restrict__ sticker)
{
  const int bucket = blockIdx.x, bh = blockIdx.y;
  const int h = bucket >> 6;
  const int lane = threadIdx.x;
  int base = bstart[bh * 256 + bucket];
  const int* bk = buckets + (size_t)bh * NTICK_ + (size_t)h * T_;
  for (int it = 0; it < 64; ++it) {
    const int t = it * 64 + lane;
    const bool m = (bk[t] == bucket);
    const unsigned long long bal = __ballot(m);
    if (m) {
      const int pos = base + __popcll(bal & ((1ull << lane) - 1ull));
      sticker[(size_t)bh * NTICK_ + pos] = h * T_ + t;
    }
    base += __popcll(bal);
  }
}

// ---------- chunked LSH attention — MFMA, async staging ----------
__global__ __launch_bounds__(256) void attn_kernel(
    const unsigned short* __restrict__ qkb, const unsigned short* __restrict__ vb,
    const int* __restrict__ sticker, const float* __restrict__ invn,
    unsigned short* __restrict__ orowsb, float* __restrict__ logits)
{
  __shared__ __align__(16) unsigned short Rs[128 * 64];
  __shared__ __align__(16) unsigned short Vs[128 * 64];
  __shared__ int tks[128];
  __shared__ float invs[128];

  const int cx = blockIdx.x;
  const int c = (cx & 7) * 32 + (cx >> 3);   // XCD-aware chunk swizzle
  const int bh = blockIdx.y;
  const int b = bh >> 3, hd = bh & 7;
  const int tid = threadIdx.x;
  const int hr = c >> 6;
  const int w = tid >> 6, lane = tid & 63, g = lane >> 4, cl = lane & 15;

  if (tid < 128) {
    const int sc = (tid < 64) ? c : ((c + CHUNKS_ - 1) & (CHUNKS_ - 1));
    const int tick = sticker[(size_t)bh * NTICK_ + sc * 64 + (tid & 63)];
    const int t = tick & (T_ - 1);
    tks[tid] = t;
    invs[tid] = invn[bh * T_ + t];
  }
  __syncthreads();

  // stage qk + v rows via global_load_lds: linear LDS dest, pre-swizzled
  // global source (rule #21 — source and read share the XOR involution)
  {
    const int sr = lane >> 3, gq = lane & 7;
#pragma unroll
    for (int l = 0; l < 4; ++l) {
      const int row = l * 32 + w * 8 + sr;
      const size_t gb = ((size_t)b * T_ + tks[row]) * D_ + hd * DH_
                      + ((gq ^ swf(row)) << 3);
      const int dst = (l * 32 + w * 8) * 64 + lane * 8;
      gld_lds16(&qkb[gb], &Rs[dst]);
      gld_lds16(&vb[gb],  &Vs[dst]);
    }
  }
  __syncthreads();

  // dots (MFMA from Rs) + V transpose-read (b64) into regs
  f32x4 sacc[8];
#pragma unroll
  for (int j = 0; j < 8; ++j) sacc[j] = (f32x4){0.f, 0.f, 0.f, 0.f};
  __builtin_amdgcn_s_setprio(1);
#pragma unroll
  for (int kk = 0; kk < 2; ++kk) {
    const bf16x8 aq = *(const bf16x8*)&Rs[off64(w * 16 + cl, kk * 32 + g * 8)];
#pragma unroll
    for (int j = 0; j < 8; ++j) {
      const bf16x8 bk = *(const bf16x8*)&Rs[off64(j * 16 + cl, kk * 32 + g * 8)];
      sacc[j] = __builtin_amdgcn_mfma_f32_16x16x32_bf16(aq, bk, sacc[j], 0, 0, 0);
    }
  }
  __builtin_amdgcn_s_setprio(0);
  const int d0 = (tid & 15) * 4, tg = tid >> 4;
  unsigned int qw[8][2];
#pragma unroll
  for (int e = 0; e < 8; ++e) {
    const uint2 q = *(const uint2*)&Vs[off64(tg * 8 + e, d0)];
    qw[e][0] = q.x; qw[e][1] = q.y;
  }
  __syncthreads();

  // write V^T into Vs region; softmax (skip-max) -> unnormalized P into Rs
  {
    unsigned short col[4][8];
#pragma unroll
    for (int e = 0; e < 8; ++e) {
      col[0][e] = (unsigned short)(qw[e][0] & 0xffffu);
      col[1][e] = (unsigned short)(qw[e][0] >> 16);
      col[2][e] = (unsigned short)(qw[e][1] & 0xffffu);
      col[3][e] = (unsigned short)(qw[e][1] >> 16);
    }
#pragma unroll
    for (int dd = 0; dd < 4; ++dd)
      *(uint4*)&Vs[off128(d0 + dd, tg * 8)] = *(const uint4*)&col[dd][0];
  }

  float iv[8]; int tk[8];
#pragma unroll
  for (int j = 0; j < 8; ++j) {
    iv[j] = invs[j * 16 + cl] * 0.125f;
    tk[j] = tks[j * 16 + cl];
  }
  float pinv[4];
#pragma unroll
  for (int r = 0; r < 4; ++r) {
    const int row = w * 16 + g * 4 + r;
    const int tq = tks[row];
    float e8[8];
    float sum = 0.f;
#pragma unroll
    for (int j = 0; j < 8; ++j) {
      float e = __expf(sacc[j][r] * iv[j]);
      if (tq == tk[j]) e = 0.f;
      e8[j] = e;
      sum += e;
    }
    sum += __shfl_xor(sum, 1); sum += __shfl_xor(sum, 2);
    sum += __shfl_xor(sum, 4); sum += __shfl_xor(sum, 8);
    pinv[r] = 1.f / sum;
#pragma unroll
    for (int j = 0; j < 8; j += 2) {
      const unsigned int pk = cvt_pk_bf16(e8[j], e8[j + 1]);
      Rs[off128(row, j * 16 + cl)]       = (unsigned short)pk;
      Rs[off128(row, (j + 1) * 16 + cl)] = (unsigned short)(pk >> 16);
    }
    if (cl == 0)
      logits[((size_t)bh * T_ + tq) * NH_ + hr] = __logf(sum);
  }
  __syncthreads();

  // PV: A = P (Rs), B = V^T (Vs)
  f32x4 oacc[4];
#pragma unroll
  for (int jd = 0; jd < 4; ++jd) oacc[jd] = (f32x4){0.f, 0.f, 0.f, 0.f};
  __builtin_amdgcn_s_setprio(1);
#pragma unroll
  for (int ks = 0; ks < 4; ++ks) {
    const bf16x8 pa = *(const bf16x8*)&Rs[off128(w * 16 + cl, ks * 32 + g * 8)];
#pragma unroll
    for (int jd = 0; jd < 4; ++jd) {
      const bf16x8 vv = *(const bf16x8*)&Vs[off128(jd * 16 + cl, ks * 32 + g * 8)];
      oacc[jd] = __builtin_amdgcn_mfma_f32_16x16x32_bf16(pa, vv, oacc[jd], 0, 0, 0);
    }
  }
  __builtin_amdgcn_s_setprio(0);
  __syncthreads();

  // O (scaled by 1/sum) into Rs, then coalesced scatter to global
#pragma unroll
  for (int r = 0; r < 4; ++r) {
    const int row = w * 16 + g * 4 + r;
    const unsigned int q01 = cvt_pk_bf16(oacc[0][r] * pinv[r], oacc[1][r] * pinv[r]);
    const unsigned int q23 = cvt_pk_bf16(oacc[2][r] * pinv[r], oacc[3][r] * pinv[r]);
    Rs[off64(row,      cl)] = (unsigned short)q01;
    Rs[off64(row, 16 + cl)] = (unsigned short)(q01 >> 16);
    Rs[off64(row, 32 + cl)] = (unsigned short)q23;
    Rs[off64(row, 48 + cl)] = (unsigned short)(q23 >> 16);
  }
  __syncthreads();

#pragma unroll
  for (int l = 0; l < 2; ++l) {
    const int idx = tid + l * 256;
    const int row = idx >> 3, k0 = (idx & 7) * 8;
    *(uint4*)&orowsb[(((size_t)bh * T_ + tks[row]) * NH_ + hr) * DH_ + k0] =
        *(const uint4*)&Rs[off64(row, k0)];
  }
}

// ---------- LayerNorm (bf16 in, fp32 out) ----------
__global__ __launch_bounds__(256) void ln_kernel(
    const unsigned short* __restrict__ yb, const float* __restrict__ gamma,
    const float* __restrict__ beta, float* __restrict__ out)
{
  const int row = blockIdx.x * 4 + (threadIdx.x >> 6);
  const int lane = threadIdx.x & 63;
  const size_t base = (size_t)row * D_ + lane * 8;
  const uint4 u = *(const uint4*)&yb[base];
  const unsigned short* up = (const unsigned short*)&u;
  float x[8];
#pragma unroll
  for (int i = 0; i < 8; ++i) x[i] = bf2f(up[i]);
  float s = 0.f;
#pragma unroll
  for (int i = 0; i < 8; ++i) s += x[i];
#pragma unroll
  for (int m = 32; m >= 1; m >>= 1) s += __shfl_xor(s, m);
  const float mu = s * (1.f / D_);
  float vs = 0.f;
#pragma unroll
  for (int i = 0; i < 8; ++i) { const float d = x[i] - mu; vs += d * d; }
#pragma unroll
  for (int m = 32; m >= 1; m >>= 1) vs += __shfl_xor(vs, m);
  const float rstd = rsqrtf(vs * (1.f / D_) + 1e-6f);
  float gm[8], bt[8];
  *(float4*)&gm[0] = *(const float4*)&gamma[lane * 8];
  *(float4*)&gm[4] = *(const float4*)&gamma[lane * 8 + 4];
  *(float4*)&bt[0] = *(const float4*)&beta[lane * 8];
  *(float4*)&bt[4] = *(const float4*)&beta[lane * 8 + 4];
  float o[8];
#pragma unroll
  for (int i = 0; i < 8; ++i) o[i] = (x[i] - mu) * rstd * gm[i] + bt[i];
  *(float4*)&out[base]     = make_float4(o[0], o[1], o[2], o[3]);
  *(float4*)&out[base + 4] = make_float4(o[4], o[5], o[6], o[7]);
}

extern "C" void kernel_launch(void* const* d_in, const int* in_sizes, int n_in,
                              void* d_out, int out_size, void* d_ws, size_t ws_size,
                              hipStream_t stream) {
  (void)in_sizes; (void)n_in; (void)out_size; (void)ws_size;
  const float* src   = (const float*)d_in[0];
  const float* Wqk   = (const float*)d_in[1];
  const float* Wv    = (const float*)d_in[2];
  const float* Wout  = (const float*)d_in[3];
  const float* bout  = (const float*)d_in[4];
  const float* W1    = (const float*)d_in[5];
  const float* b1    = (const float*)d_in[6];
  const float* W2    = (const float*)d_in[7];
  const float* b2    = (const float*)d_in[8];
  const float* gamma = (const float*)d_in[9];
  const float* beta  = (const float*)d_in[10];
  const float* rot   = (const float*)d_in[11];
  float* out = (float*)d_out;

  // ---- workspace layout ----
  char* ws = (char*)d_ws;
  const size_t MB = 1024 * 1024;
  float*          qk       = (float*)(ws);                     // 32 MB; dead after hash
  unsigned short* src_pair = (unsigned short*)(ws + 32 * MB);  // 32 MB [hi|lo]
  unsigned short* v_b      = (unsigned short*)(ws + 64 * MB);  // 16 MB; -> x_b
  unsigned short* orows_b  = (unsigned short*)(ws + 80 * MB);  // 64 MB; -> hidden_b
  unsigned short* qk_b     = (unsigned short*)(ws + 144 * MB); // 16 MB
  char* p = ws + 160 * MB;
  float* logits  = (float*)p; p += (size_t)BH_ * T_ * NH_ * 4;
  int*   buckets = (int*)p;   p += (size_t)BH_ * NH_ * T_ * 4;
  int*   sticker = (int*)p;   p += (size_t)BH_ * NTICK_ * 4;
  int*   bstart  = (int*)p;   p += (size_t)BH_ * 256 * 4;
  float* invn    = (float*)p; p += (size_t)BH_ * T_ * 4;
  unsigned short* WqkvTp = (unsigned short*)p; p += (size_t)1024 * 1024 * 2;
  unsigned short* WoutT  = (unsigned short*)p; p += (size_t)D_ * D_ * 2;
  unsigned short* W1T    = (unsigned short*)p; p += (size_t)FFN_ * D_ * 2;
  unsigned short* W2T    = (unsigned short*)p; p += (size_t)D_ * FFN_ * 2;

  unsigned short* x_b      = v_b;                  // after attn consumed v_b
  unsigned short* hidden_b = orows_b;              // after Wout consumed orows
  unsigned short* ybuf_b   = (unsigned short*)ws;  // after hash consumed qk f32

  // 0: all conversions in one launch (weights + src split)
  prep_all<<<2816 + M_ * D_ / 8 / 256, 256, 0, stream>>>(
      Wqk, Wv, Wout, W1, W2, src, WqkvTp, WoutT, W1T, W2T, src_pair);

  // 1: fused qk+v projection — qk K=1024 split (fp32-exact) + invn; v K=512 hi
  gemm_bf16<128, 3, false, false, false, false>
      <<<dim3(1024 / 128, M_ / 128), 256, 0, stream>>>(
      src_pair, WqkvTp, nullptr, nullptr, qk, qk_b, v_b, nullptr, invn,
      M_, 1024, 2 * D_, 2 * D_, 2 * D_, 0);
  // 2: LSH buckets (GEMM + fused argmax)
  hash_gemm_kernel<<<dim3(T_ / 128, BH_), 256, 0, stream>>>(qk, rot, buckets);
  // 3-4: counting sort
  hist_kernel<<<BH_, 256, 0, stream>>>(buckets, bstart);
  compact_kernel<<<dim3(256, BH_), 64, 0, stream>>>(buckets, bstart, sticker);
  // 5: chunked attention (MFMA)
  attn_kernel<<<dim3(CHUNKS_, BH_), 256, 0, stream>>>(
      qk_b, v_b, sticker, invn, orows_b, logits);
  // 6: out projection + fused hash-round combine (A = orows) + bias + resid(src)
  gemm_bf16<128, 1, true, false, true, true>
      <<<dim3(D_ / 128, M_ / 128), 256, 0, stream>>>(
      orows_b, WoutT, bout, src_pair, nullptr, x_b, nullptr, logits, nullptr,
      M_, D_, D_, 0, D_, 2 * D_);
  // 7: FFN1 (relu)
  gemm_bf16<128, 1, true, true, false, false>
      <<<dim3(FFN_ / 128, M_ / 128), 256, 0, stream>>>(
      x_b, W1T, b1, nullptr, nullptr, hidden_b, nullptr, nullptr, nullptr,
      M_, FFN_, D_, D_, D_, 0);
  // 8: FFN2 + bias + residual(x_b) -> bf16 y
  gemm_bf16<128, 1, true, false, true, false>
      <<<dim3(D_ / 128, M_ / 128), 256, 0, stream>>>(
      hidden_b, W2T, b2, x_b, nullptr, ybuf_b, nullptr, nullptr, nullptr,
      M_, D_, FFN_, FFN_, FFN_, D_);
  // 9: LayerNorm
  ln_kernel<<<M_ / 4, 256, 0, stream>>>(ybuf_b, gamma, beta, out);
}

// Round 9
// 353.034 us; speedup vs baseline: 1.0805x; 1.0805x over previous
//
#include <hip/hip_runtime.h>

#define B_ 4
#define T_ 4096
#define D_ 512
#define H_ 8
#define DH_ 64
#define NH_ 4
#define NB_ 64            // n_buckets = T/BUCKET
#define BH_ (B_*H_)       // 32
#define CHUNKS_ (NH_*NB_) // 256
#define NTICK_ (NH_*T_)   // 16384
#define M_ (B_*T_)        // 16384
#define FFN_ 2048

typedef __attribute__((ext_vector_type(8))) short bf16x8;
typedef __attribute__((ext_vector_type(4))) float f32x4;

// ---------- bf16 helpers ----------
__device__ __forceinline__ unsigned short f2bf(float x) {
  unsigned int u = __float_as_uint(x);
  return (unsigned short)((u + 0x7FFFu + ((u >> 16) & 1u)) >> 16);
}
__device__ __forceinline__ float bf2f(unsigned short s) {
  return __uint_as_float(((unsigned int)s) << 16);
}
__device__ __forceinline__ unsigned int cvt_pk_bf16(float lo, float hi) {
  unsigned int r;
  asm("v_cvt_pk_bf16_f32 %0, %1, %2" : "=v"(r) : "v"(lo), "v"(hi));
  return r;
}

// ---------- async global->LDS, 16B per lane ----------
__device__ __forceinline__ void gld_lds16(const void* g, void* l) {
  __builtin_amdgcn_global_load_lds(
      (const __attribute__((address_space(1))) unsigned int*)g,
      (__attribute__((address_space(3))) unsigned int*)l, 16, 0, 0);
}

// swizzled LDS offsets (shorts): XOR 16B-granule with (row ^ row>>3)&7
__device__ __forceinline__ int swf(int row) { return (row ^ (row >> 3)) & 7; }
__device__ __forceinline__ int off64(int row, int k) {
  return row * 64 + (((k >> 3) ^ swf(row)) << 3) + (k & 7);
}
__device__ __forceinline__ int off128(int row, int k) {
  return row * 128 + (((k >> 3) ^ swf(row)) << 3) + (k & 7);
}

// ---------- bf16 MFMA GEMM: C = op(A @ BT^T) ----------
// MODE 1: bf16 out (stride N).
// MODE 3: fused qk+v — N logical 1024, all K=512:
//   n0<512: qk cols -> f32 Cf (stride 512) + bf16 Cb + fused invn;
//   n0>=512: v cols -> bf16 Cb2 at col n0-512.
template<int BM, int MODE, bool HAS_BIAS, bool RELU, bool HAS_RESID>
__global__ __launch_bounds__(256) void gemm_bf16(
    const unsigned short* __restrict__ A, const unsigned short* __restrict__ BT,
    const float* __restrict__ bias, const unsigned short* __restrict__ resid,
    float* __restrict__ Cf, unsigned short* __restrict__ Cb,
    unsigned short* __restrict__ Cb2, float* __restrict__ invn,
    int M, int N, int K, int lda, int ldbt, int ldr)
{
  constexpr int MI = BM / 32;
  __shared__ __align__(16) unsigned short smem[(BM + 128) * 64];  // As|Bs, then C-tile
  unsigned short* As = smem;
  unsigned short* Bs = smem + BM * 64;
  const int tid = threadIdx.x;
  const int lane = tid & 63;
  const int w = tid >> 6;
  const int wm = (w >> 1) * (BM / 2), wn = (w & 1) * 64;
  const int g = lane >> 4, cl = lane & 15;

  // XCD-aware block swizzle (T1)
  const int gx = gridDim.x;
  const int id = blockIdx.x + blockIdx.y * gx;
  const int cpx = (gx * gridDim.y) >> 3;
  const int swz = (id & 7) * cpx + (id >> 3);
  const int m0 = (swz / gx) * BM, n0 = (swz % gx) * 128;

  const bool isv = (MODE == 3) && (n0 >= 512);

  f32x4 acc[MI][4];
#pragma unroll
  for (int i = 0; i < MI; ++i)
#pragma unroll
    for (int j = 0; j < 4; ++j) acc[i][j] = (f32x4){0.f, 0.f, 0.f, 0.f};

  const int srow = tid >> 3;
  const int skc  = (tid & 7) * 8;

  for (int k0 = 0; k0 < K; k0 += 64) {
#pragma unroll
    for (int ci = 0; ci < BM / 32; ++ci)
      gld_lds16(&A[(size_t)(m0 + ci * 32 + srow) * lda + k0 + skc],
                &As[ci * 2048 + tid * 8]);
#pragma unroll
    for (int ci = 0; ci < 4; ++ci)
      gld_lds16(&BT[(size_t)(n0 + ci * 32 + srow) * ldbt + k0 + skc],
                &Bs[ci * 2048 + tid * 8]);
    __syncthreads();
#pragma unroll
    for (int kk = 0; kk < 64; kk += 32) {
      bf16x8 af[MI], bfr[4];
#pragma unroll
      for (int i = 0; i < MI; ++i)
        af[i] = *(const bf16x8*)&As[(wm + i * 16 + cl) * 64 + kk + g * 8];
#pragma unroll
      for (int j = 0; j < 4; ++j)
        bfr[j] = *(const bf16x8*)&Bs[(wn + j * 16 + cl) * 64 + kk + g * 8];
#pragma unroll
      for (int i = 0; i < MI; ++i)
#pragma unroll
        for (int j = 0; j < 4; ++j)
          acc[i][j] = __builtin_amdgcn_mfma_f32_16x16x32_bf16(af[i], bfr[j], acc[i][j], 0, 0, 0);
    }
    __syncthreads();
  }

  // ---- epilogue: regs -> LDS C-tile (swizzled) -> coalesced out
  float bv[4];
  if constexpr (HAS_BIAS) {
#pragma unroll
    for (int j = 0; j < 4; ++j) bv[j] = bias[n0 + wn + j * 16 + cl];
  }
#pragma unroll
  for (int i = 0; i < MI; ++i) {
#pragma unroll
    for (int r = 0; r < 4; ++r) {
      const int lrow = wm + i * 16 + g * 4 + r;
      float v4[4];
      float ss = 0.f;
#pragma unroll
      for (int j = 0; j < 4; ++j) {
        float val = acc[i][j][r];
        if constexpr (HAS_BIAS) val += bv[j];
        if constexpr (RELU) val = fmaxf(val, 0.f);
        v4[j] = val;
        if constexpr (MODE == 3) {
          if (!isv) {
            ss += val * val;
            Cf[(size_t)(m0 + lrow) * 512 + n0 + wn + j * 16 + cl] = val;
          }
        }
      }
      const unsigned int p01 = cvt_pk_bf16(v4[0], v4[1]);
      const unsigned int p23 = cvt_pk_bf16(v4[2], v4[3]);
      const int sw = (lrow & 7) << 3;
      smem[lrow * 128 + ((wn +  0 + cl) ^ sw)] = (unsigned short)p01;
      smem[lrow * 128 + ((wn + 16 + cl) ^ sw)] = (unsigned short)(p01 >> 16);
      smem[lrow * 128 + ((wn + 32 + cl) ^ sw)] = (unsigned short)p23;
      smem[lrow * 128 + ((wn + 48 + cl) ^ sw)] = (unsigned short)(p23 >> 16);
      if constexpr (MODE == 3) {
        if (!isv) {
          ss += __shfl_xor(ss, 1); ss += __shfl_xor(ss, 2);
          ss += __shfl_xor(ss, 4); ss += __shfl_xor(ss, 8);
          if (cl == 0) {
            const int m = m0 + lrow;
            const int bb = m >> 12, t = m & (T_ - 1);
            const int hh = ((n0 + wn) >> 6) & 7;
            invn[((size_t)(bb * 8 + hh)) * T_ + t] = 1.0f / (sqrtf(ss) + 1e-6f);
          }
        }
      }
    }
  }
  __syncthreads();
#pragma unroll
  for (int l = 0; l < BM / 16; ++l) {
    const int idx = tid + l * 256;
    const int row = idx >> 4, c8 = (idx & 15) * 8;
    uint4 u = *(const uint4*)&smem[row * 128 + (c8 ^ ((row & 7) << 3))];
    if constexpr (HAS_RESID) {
      const uint4 rv = *(const uint4*)&resid[(size_t)(m0 + row) * ldr + n0 + c8];
      const unsigned short* sp = (const unsigned short*)&u;
      const unsigned short* rp = (const unsigned short*)&rv;
      float f[8];
#pragma unroll
      for (int e = 0; e < 8; ++e) f[e] = bf2f(sp[e]) + bf2f(rp[e]);
      u.x = cvt_pk_bf16(f[0], f[1]); u.y = cvt_pk_bf16(f[2], f[3]);
      u.z = cvt_pk_bf16(f[4], f[5]); u.w = cvt_pk_bf16(f[6], f[7]);
    }
    if constexpr (MODE == 3) {
      if (isv)
        *(uint4*)&Cb2[(size_t)(m0 + row) * 512 + (n0 - 512) + c8] = u;
      else
        *(uint4*)&Cb[(size_t)(m0 + row) * 512 + n0 + c8] = u;
    } else {
      *(uint4*)&Cb[(size_t)(m0 + row) * N + n0 + c8] = u;
    }
  }
}

// ---------- fused prep: transpose 5 weights + convert src rows ----------
__global__ __launch_bounds__(256) void prep_all(
    const float* __restrict__ Wqk, const float* __restrict__ Wv,
    const float* __restrict__ Wout, const float* __restrict__ W1,
    const float* __restrict__ W2, const float* __restrict__ src,
    unsigned short* __restrict__ WqkvT, unsigned short* __restrict__ WoutT,
    unsigned short* __restrict__ W1T, unsigned short* __restrict__ W2T,
    unsigned short* __restrict__ src_b)
{
  __shared__ float tile[32][33];
  int bid = blockIdx.x;
  if (bid >= 2816) {
    // src: fp32 -> bf16
    const int i = (bid - 2816) * 256 + threadIdx.x;   // < M*D/8
    const int m = i >> 6, d0 = (i & 63) * 8;
    float x[8];
    *(float4*)&x[0] = *(const float4*)&src[(size_t)m * D_ + d0];
    *(float4*)&x[4] = *(const float4*)&src[(size_t)m * D_ + d0 + 4];
    unsigned short hi[8];
#pragma unroll
    for (int e = 0; e < 8; ++e) hi[e] = f2bf(x[e]);
    *(uint4*)&src_b[(size_t)m * D_ + d0] = *(const uint4*)&hi[0];
    return;
  }
  const float* W; unsigned short* WT; int K, N, bx, by;
  if (bid < 256)        { W = Wqk;  WT = WqkvT; K = 512;  N = 512;
                          bx = bid & 15; by = bid >> 4; }
  else if (bid < 512)   { bid -= 256;  W = Wv; WT = WqkvT + (size_t)512 * 512;
                          K = 512; N = 512;
                          bx = bid & 15; by = bid >> 4; }
  else if (bid < 768)   { bid -= 512;  W = Wout; WT = WoutT; K = 512;  N = 512;
                          bx = bid & 15; by = bid >> 4; }
  else if (bid < 1792)  { bid -= 768;  W = W1;   WT = W1T;   K = 512;  N = 2048;
                          bx = bid & 63; by = bid >> 6; }
  else                  { bid -= 1792; W = W2;   WT = W2T;   K = 2048; N = 512;
                          bx = bid & 15; by = bid >> 4; }
  const int k0 = by * 32, n0 = bx * 32;
  const int tx = threadIdx.x & 31, ty = threadIdx.x >> 5;
#pragma unroll
  for (int r = 0; r < 32; r += 8)
    tile[ty + r][tx] = W[(size_t)(k0 + ty + r) * N + n0 + tx];
  __syncthreads();
#pragma unroll
  for (int r = 0; r < 32; r += 8)
    WT[(size_t)(n0 + ty + r) * K + k0 + tx] = f2bf(tile[tx][ty + r]);
}

// ---------- LSH hashing as GEMM + fused argmax (reads fp32 qk) ----------
__global__ __launch_bounds__(256) void hash_gemm_kernel(
    const float* __restrict__ qk, const float* __restrict__ rot,
    int* __restrict__ buckets)
{
  __shared__ __align__(16) float As[64][136];   // [k][m]
  __shared__ __align__(16) float Bs[64][132];   // [k][n]
  const int tid = threadIdx.x;
  const int tx = tid & 15, ty = tid >> 4;
  const int t0 = blockIdx.x * 128, bh = blockIdx.y;
  const int b = bh >> 3, hd = bh & 7;

#pragma unroll
  for (int l = 0; l < 8; ++l) {
    const int idx = tid + l * 256;
    const int row = idx >> 4;
    const int kq = (idx & 15) << 2;
    const float4 a = *(const float4*)&qk[((size_t)b * T_ + t0 + row) * D_ + hd * DH_ + kq];
    As[kq + 0][row] = a.x; As[kq + 1][row] = a.y;
    As[kq + 2][row] = a.z; As[kq + 3][row] = a.w;
  }
#pragma unroll
  for (int l = 0; l < 8; ++l) {
    const int idx = tid + l * 256;
    const int kr = idx >> 5;
    const int c4 = (idx & 31) << 2;
    *(float4*)&Bs[kr][c4] = *(const float4*)&rot[kr * 128 + c4];
  }
  __syncthreads();

  float acc[8][8];
#pragma unroll
  for (int i = 0; i < 8; ++i)
#pragma unroll
    for (int j = 0; j < 8; ++j) acc[i][j] = 0.f;

#pragma unroll 4
  for (int kk = 0; kk < 64; ++kk) {
    float a[8], bq[8];
    *(float4*)&a[0]  = *(const float4*)&As[kk][ty * 8];
    *(float4*)&a[4]  = *(const float4*)&As[kk][ty * 8 + 4];
    *(float4*)&bq[0] = *(const float4*)&Bs[kk][tx * 8];
    *(float4*)&bq[4] = *(const float4*)&Bs[kk][tx * 8 + 4];
#pragma unroll
    for (int i = 0; i < 8; ++i)
#pragma unroll
      for (int j = 0; j < 8; ++j)
        acc[i][j] = fmaf(a[i], bq[j], acc[i][j]);
  }
  __syncthreads();

  float* pval = &As[0][0];
  int*   pidx = (int*)&Bs[0][0];
  const int i0 = (tx & 3) * 8;
#pragma unroll
  for (int r = 0; r < 8; ++r) {
    float v = -3.0e38f; int idx = 127;
#pragma unroll
    for (int j = 0; j < 8; ++j) {
      const float p = acc[r][j];
      const int li = i0 + j;
      if (p > v || (p == v && li < idx)) { v = p; idx = li; }
      const float n = -p;
      const int ni = 32 + li;
      if (n > v || (n == v && ni < idx)) { v = n; idx = ni; }
    }
    pval[(ty * 8 + r) * 16 + tx] = v;
    pidx[(ty * 8 + r) * 16 + tx] = idx;
  }
  __syncthreads();

#pragma unroll
  for (int l = 0; l < 2; ++l) {
    const int id = tid + l * 256;
    const int tok = id >> 2, hh = id & 3;
    float v = pval[tok * 16 + hh * 4];
    int idx = pidx[tok * 16 + hh * 4];
#pragma unroll
    for (int e = 1; e < 4; ++e) {
      const float ov = pval[tok * 16 + hh * 4 + e];
      const int oi = pidx[tok * 16 + hh * 4 + e];
      if (ov > v || (ov == v && oi < idx)) { v = ov; idx = oi; }
    }
    buckets[((size_t)bh * NH_ + hh) * T_ + t0 + tok] = idx + hh * NB_;
  }
}

// ---------- per-bh bucket histogram + exclusive scan ----------
__global__ __launch_bounds__(256) void hist_kernel(
    const int* __restrict__ buckets, int* __restrict__ bstart)
{
  __shared__ int bins[256];
  const int bh = blockIdx.x;
  bins[threadIdx.x] = 0;
  __syncthreads();
  for (int e = threadIdx.x; e < NTICK_; e += 256)
    atomicAdd(&bins[buckets[(size_t)bh * NTICK_ + e]], 1);
  __syncthreads();
  if (threadIdx.x == 0) {
    int run = 0;
    for (int i = 0; i < 256; ++i) { const int c = bins[i]; bins[i] = run; run += c; }
  }
  __syncthreads();
  bstart[bh * 256 + threadIdx.x] = bins[threadIdx.x];
}

// ---------- stable compaction ----------
__global__ __launch_bounds__(64) void compact_kernel(
    const int* __restrict__ buckets, const int* __restrict__ bstart,
    int* __restrict__ sticker)
{
  const int bucket = blockIdx.x, bh = blockIdx.y;
  const int h = bucket >> 6;
  const int lane = threadIdx.x;
  int base = bstart[bh * 256 + bucket];
  const int* bk = buckets + (size_t)bh * NTICK_ + (size_t)h * T_;
  for (int it = 0; it < 64; ++it) {
    const int t = it * 64 + lane;
    const bool m = (bk[t] == bucket);
    const unsigned long long bal = __ballot(m);
    if (m) {
      const int pos = base + __popcll(bal & ((1ull << lane) - 1ull));
      sticker[(size_t)bh * NTICK_ + pos] = h * T_ + t;
    }
    base += __popcll(bal);
  }
}

// ---------- chunked LSH attention — MFMA, async staging ----------
__global__ __launch_bounds__(256) void attn_kernel(
    const unsigned short* __restrict__ qkb, const unsigned short* __restrict__ vb,
    const int* __restrict__ sticker, const float* __restrict__ invn,
    unsigned short* __restrict__ orowsb, float* __restrict__ logits)
{
  __shared__ __align__(16) unsigned short Rs[128 * 64];
  __shared__ __align__(16) unsigned short Vs[128 * 64];
  __shared__ int tks[128];
  __shared__ float invs[128];

  const int cx = blockIdx.x;
  const int c = (cx & 7) * 32 + (cx >> 3);   // XCD-aware chunk swizzle
  const int bh = blockIdx.y;
  const int b = bh >> 3, hd = bh & 7;
  const int tid = threadIdx.x;
  const int hr = c >> 6;
  const int w = tid >> 6, lane = tid & 63, g = lane >> 4, cl = lane & 15;

  if (tid < 128) {
    const int sc = (tid < 64) ? c : ((c + CHUNKS_ - 1) & (CHUNKS_ - 1));
    const int tick = sticker[(size_t)bh * NTICK_ + sc * 64 + (tid & 63)];
    const int t = tick & (T_ - 1);
    tks[tid] = t;
    invs[tid] = invn[bh * T_ + t];
  }
  __syncthreads();

  // stage qk + v rows via global_load_lds: linear LDS dest, pre-swizzled source
  {
    const int sr = lane >> 3, gq = lane & 7;
#pragma unroll
    for (int l = 0; l < 4; ++l) {
      const int row = l * 32 + w * 8 + sr;
      const size_t gb = ((size_t)b * T_ + tks[row]) * D_ + hd * DH_
                      + ((gq ^ swf(row)) << 3);
      const int dst = (l * 32 + w * 8) * 64 + lane * 8;
      gld_lds16(&qkb[gb], &Rs[dst]);
      gld_lds16(&vb[gb],  &Vs[dst]);
    }
  }
  __syncthreads();

  // dots (MFMA from Rs) + V transpose-read (b64) into regs
  f32x4 sacc[8];
#pragma unroll
  for (int j = 0; j < 8; ++j) sacc[j] = (f32x4){0.f, 0.f, 0.f, 0.f};
  __builtin_amdgcn_s_setprio(1);
#pragma unroll
  for (int kk = 0; kk < 2; ++kk) {
    const bf16x8 aq = *(const bf16x8*)&Rs[off64(w * 16 + cl, kk * 32 + g * 8)];
#pragma unroll
    for (int j = 0; j < 8; ++j) {
      const bf16x8 bk = *(const bf16x8*)&Rs[off64(j * 16 + cl, kk * 32 + g * 8)];
      sacc[j] = __builtin_amdgcn_mfma_f32_16x16x32_bf16(aq, bk, sacc[j], 0, 0, 0);
    }
  }
  __builtin_amdgcn_s_setprio(0);
  const int d0 = (tid & 15) * 4, tg = tid >> 4;
  unsigned int qw[8][2];
#pragma unroll
  for (int e = 0; e < 8; ++e) {
    const uint2 q = *(const uint2*)&Vs[off64(tg * 8 + e, d0)];
    qw[e][0] = q.x; qw[e][1] = q.y;
  }
  __syncthreads();

  // write V^T into Vs region; softmax (skip-max) -> unnormalized P into Rs
  {
    unsigned short col[4][8];
#pragma unroll
    for (int e = 0; e < 8; ++e) {
      col[0][e] = (unsigned short)(qw[e][0] & 0xffffu);
      col[1][e] = (unsigned short)(qw[e][0] >> 16);
      col[2][e] = (unsigned short)(qw[e][1] & 0xffffu);
      col[3][e] = (unsigned short)(qw[e][1] >> 16);
    }
#pragma unroll
    for (int dd = 0; dd < 4; ++dd)
      *(uint4*)&Vs[off128(d0 + dd, tg * 8)] = *(const uint4*)&col[dd][0];
  }

  float iv[8]; int tk[8];
#pragma unroll
  for (int j = 0; j < 8; ++j) {
    iv[j] = invs[j * 16 + cl] * 0.125f;
    tk[j] = tks[j * 16 + cl];
  }
  float pinv[4];
#pragma unroll
  for (int r = 0; r < 4; ++r) {
    const int row = w * 16 + g * 4 + r;
    const int tq = tks[row];
    float e8[8];
    float sum = 0.f;
#pragma unroll
    for (int j = 0; j < 8; ++j) {
      float e = __expf(sacc[j][r] * iv[j]);
      if (tq == tk[j]) e = 0.f;
      e8[j] = e;
      sum += e;
    }
    sum += __shfl_xor(sum, 1); sum += __shfl_xor(sum, 2);
    sum += __shfl_xor(sum, 4); sum += __shfl_xor(sum, 8);
    pinv[r] = 1.f / sum;
#pragma unroll
    for (int j = 0; j < 8; j += 2) {
      const unsigned int pk = cvt_pk_bf16(e8[j], e8[j + 1]);
      Rs[off128(row, j * 16 + cl)]       = (unsigned short)pk;
      Rs[off128(row, (j + 1) * 16 + cl)] = (unsigned short)(pk >> 16);
    }
    if (cl == 0)
      logits[((size_t)bh * T_ + tq) * NH_ + hr] = __logf(sum);
  }
  __syncthreads();

  // PV: A = P (Rs), B = V^T (Vs)
  f32x4 oacc[4];
#pragma unroll
  for (int jd = 0; jd < 4; ++jd) oacc[jd] = (f32x4){0.f, 0.f, 0.f, 0.f};
  __builtin_amdgcn_s_setprio(1);
#pragma unroll
  for (int ks = 0; ks < 4; ++ks) {
    const bf16x8 pa = *(const bf16x8*)&Rs[off128(w * 16 + cl, ks * 32 + g * 8)];
#pragma unroll
    for (int jd = 0; jd < 4; ++jd) {
      const bf16x8 vv = *(const bf16x8*)&Vs[off128(jd * 16 + cl, ks * 32 + g * 8)];
      oacc[jd] = __builtin_amdgcn_mfma_f32_16x16x32_bf16(pa, vv, oacc[jd], 0, 0, 0);
    }
  }
  __builtin_amdgcn_s_setprio(0);
  __syncthreads();

  // O (scaled by 1/sum) into Rs, then coalesced scatter to global
#pragma unroll
  for (int r = 0; r < 4; ++r) {
    const int row = w * 16 + g * 4 + r;
    const unsigned int q01 = cvt_pk_bf16(oacc[0][r] * pinv[r], oacc[1][r] * pinv[r]);
    const unsigned int q23 = cvt_pk_bf16(oacc[2][r] * pinv[r], oacc[3][r] * pinv[r]);
    Rs[off64(row,      cl)] = (unsigned short)q01;
    Rs[off64(row, 16 + cl)] = (unsigned short)(q01 >> 16);
    Rs[off64(row, 32 + cl)] = (unsigned short)q23;
    Rs[off64(row, 48 + cl)] = (unsigned short)(q23 >> 16);
  }
  __syncthreads();

#pragma unroll
  for (int l = 0; l < 2; ++l) {
    const int idx = tid + l * 256;
    const int row = idx >> 3, k0 = (idx & 7) * 8;
    *(uint4*)&orowsb[(((size_t)bh * T_ + tks[row]) * NH_ + hr) * DH_ + k0] =
        *(const uint4*)&Rs[off64(row, k0)];
  }
}

// ---------- combine hash rounds (contiguous per-token layout) ----------
__global__ __launch_bounds__(256) void combine_kernel(
    const unsigned short* __restrict__ orowsb, const float* __restrict__ logits,
    unsigned short* __restrict__ ocombb)
{
  const int gid = blockIdx.x * 4 + (threadIdx.x >> 6);
  const int lane = threadIdx.x & 63;
  const int bh = gid >> 12, t = gid & (T_ - 1);
  const int b = bh >> 3, hd = bh & 7;
  const float4 lg = *(const float4*)&logits[((size_t)bh * T_ + t) * NH_];
  const float m = fmaxf(fmaxf(lg.x, lg.y), fmaxf(lg.z, lg.w));
  const float w0 = __expf(lg.x - m), w1 = __expf(lg.y - m);
  const float w2 = __expf(lg.z - m), w3 = __expf(lg.w - m);
  const float inv = 1.f / (w0 + w1 + w2 + w3);
  const size_t rb = ((size_t)bh * T_ + t) * (NH_ * DH_) + lane;
  const float o = w0 * bf2f(orowsb[rb])
                + w1 * bf2f(orowsb[rb + DH_])
                + w2 * bf2f(orowsb[rb + 2 * DH_])
                + w3 * bf2f(orowsb[rb + 3 * DH_]);
  ocombb[((size_t)b * T_ + t) * D_ + hd * DH_ + lane] = f2bf(o * inv);
}

// ---------- LayerNorm (bf16 in, fp32 out) ----------
__global__ __launch_bounds__(256) void ln_kernel(
    const unsigned short* __restrict__ yb, const float* __restrict__ gamma,
    const float* __restrict__ beta, float* __restrict__ out)
{
  const int row = blockIdx.x * 4 + (threadIdx.x >> 6);
  const int lane = threadIdx.x & 63;
  const size_t base = (size_t)row * D_ + lane * 8;
  const uint4 u = *(const uint4*)&yb[base];
  const unsigned short* up = (const unsigned short*)&u;
  float x[8];
#pragma unroll
  for (int i = 0; i < 8; ++i) x[i] = bf2f(up[i]);
  float s = 0.f;
#pragma unroll
  for (int i = 0; i < 8; ++i) s += x[i];
#pragma unroll
  for (int m = 32; m >= 1; m >>= 1) s += __shfl_xor(s, m);
  const float mu = s * (1.f / D_);
  float vs = 0.f;
#pragma unroll
  for (int i = 0; i < 8; ++i) { const float d = x[i] - mu; vs += d * d; }
#pragma unroll
  for (int m = 32; m >= 1; m >>= 1) vs += __shfl_xor(vs, m);
  const float rstd = rsqrtf(vs * (1.f / D_) + 1e-6f);
  float gm[8], bt[8];
  *(float4*)&gm[0] = *(const float4*)&gamma[lane * 8];
  *(float4*)&gm[4] = *(const float4*)&gamma[lane * 8 + 4];
  *(float4*)&bt[0] = *(const float4*)&beta[lane * 8];
  *(float4*)&bt[4] = *(const float4*)&beta[lane * 8 + 4];
  float o[8];
#pragma unroll
  for (int i = 0; i < 8; ++i) o[i] = (x[i] - mu) * rstd * gm[i] + bt[i];
  *(float4*)&out[base]     = make_float4(o[0], o[1], o[2], o[3]);
  *(float4*)&out[base + 4] = make_float4(o[4], o[5], o[6], o[7]);
}

extern "C" void kernel_launch(void* const* d_in, const int* in_sizes, int n_in,
                              void* d_out, int out_size, void* d_ws, size_t ws_size,
                              hipStream_t stream) {
  (void)in_sizes; (void)n_in; (void)out_size; (void)ws_size;
  const float* src   = (const float*)d_in[0];
  const float* Wqk   = (const float*)d_in[1];
  const float* Wv    = (const float*)d_in[2];
  const float* Wout  = (const float*)d_in[3];
  const float* bout  = (const float*)d_in[4];
  const float* W1    = (const float*)d_in[5];
  const float* b1    = (const float*)d_in[6];
  const float* W2    = (const float*)d_in[7];
  const float* b2    = (const float*)d_in[8];
  const float* gamma = (const float*)d_in[9];
  const float* beta  = (const float*)d_in[10];
  const float* rot   = (const float*)d_in[11];
  float* out = (float*)d_out;

  // ---- workspace layout ----
  char* ws = (char*)d_ws;
  const size_t MB = 1024 * 1024;
  float*          qk      = (float*)(ws);                     // 32 MB; dead after hash
  unsigned short* src_b   = (unsigned short*)(ws + 32 * MB);  // 16 MB; live thru Wout resid
  unsigned short* v_b     = (unsigned short*)(ws + 48 * MB);  // 16 MB; -> x_b
  unsigned short* orows_b = (unsigned short*)(ws + 64 * MB);  // 64 MB; -> hidden_b
  unsigned short* qk_b    = (unsigned short*)(ws + 128 * MB); // 16 MB; -> ocomb_b
  char* p = ws + 144 * MB;
  float* logits  = (float*)p; p += (size_t)BH_ * T_ * NH_ * 4;
  int*   buckets = (int*)p;   p += (size_t)BH_ * NH_ * T_ * 4;
  int*   sticker = (int*)p;   p += (size_t)BH_ * NTICK_ * 4;
  int*   bstart  = (int*)p;   p += (size_t)BH_ * 256 * 4;
  float* invn    = (float*)p; p += (size_t)BH_ * T_ * 4;
  unsigned short* WqkvT = (unsigned short*)p; p += (size_t)1024 * 512 * 2;
  unsigned short* WoutT = (unsigned short*)p; p += (size_t)D_ * D_ * 2;
  unsigned short* W1T   = (unsigned short*)p; p += (size_t)FFN_ * D_ * 2;
  unsigned short* W2T   = (unsigned short*)p; p += (size_t)D_ * FFN_ * 2;

  unsigned short* ocomb_b  = qk_b;                 // after attn consumed qk_b
  unsigned short* x_b      = v_b;                  // after attn consumed v_b
  unsigned short* hidden_b = orows_b;              // after combine consumed orows
  unsigned short* ybuf_b   = (unsigned short*)ws;  // after hash consumed qk f32

  // 0: all conversions in one launch (weights + src convert)
  prep_all<<<2816 + M_ * D_ / 8 / 256, 256, 0, stream>>>(
      Wqk, Wv, Wout, W1, W2, src, WqkvT, WoutT, W1T, W2T, src_b);

  // 1: fused qk+v projection (K=512; qk cols emit fp32 + invn)
  gemm_bf16<128, 3, false, false, false>
      <<<dim3(1024 / 128, M_ / 128), 256, 0, stream>>>(
      src_b, WqkvT, nullptr, nullptr, qk, qk_b, v_b, invn,
      M_, 1024, D_, D_, D_, 0);
  // 2: LSH buckets (GEMM + fused argmax)
  hash_gemm_kernel<<<dim3(T_ / 128, BH_), 256, 0, stream>>>(qk, rot, buckets);
  // 3-4: counting sort
  hist_kernel<<<BH_, 256, 0, stream>>>(buckets, bstart);
  compact_kernel<<<dim3(256, BH_), 64, 0, stream>>>(buckets, bstart, sticker);
  // 5: chunked attention (MFMA)
  attn_kernel<<<dim3(CHUNKS_, BH_), 256, 0, stream>>>(
      qk_b, v_b, sticker, invn, orows_b, logits);
  // 6: combine hash rounds (writes into qk_b region)
  combine_kernel<<<BH_ * T_ / 4, 256, 0, stream>>>(orows_b, logits, ocomb_b);
  // 7: out projection + bias + residual(src_b)
  gemm_bf16<128, 1, true, false, true>
      <<<dim3(D_ / 128, M_ / 128), 256, 0, stream>>>(
      ocomb_b, WoutT, bout, src_b, nullptr, x_b, nullptr, nullptr,
      M_, D_, D_, D_, D_, D_);
  // 8: FFN1 (relu)
  gemm_bf16<128, 1, true, true, false>
      <<<dim3(FFN_ / 128, M_ / 128), 256, 0, stream>>>(
      x_b, W1T, b1, nullptr, nullptr, hidden_b, nullptr, nullptr,
      M_, FFN_, D_, D_, D_, 0);
  // 9: FFN2 + bias + residual(x_b) -> bf16 y
  gemm_bf16<128, 1, true, false, true>
      <<<dim3(D_ / 128, M_ / 128), 256, 0, stream>>>(
      hidden_b, W2T, b2, x_b, nullptr, ybuf_b, nullptr, nullptr,
      M_, D_, FFN_, FFN_, FFN_, D_);
  // 10: LayerNorm
  ln_kernel<<<M_ / 4, 256, 0, stream>>>(ybuf_b, gamma, beta, out);
}

// Round 10
// 334.284 us; speedup vs baseline: 1.1411x; 1.0561x over previous
//
#include <hip/hip_runtime.h>

#define B_ 4
#define T_ 4096
#define D_ 512
#define H_ 8
#define DH_ 64
#define NH_ 4
#define NB_ 64            // n_buckets = T/BUCKET
#define BH_ (B_*H_)       // 32
#define CHUNKS_ (NH_*NB_) // 256
#define NTICK_ (NH_*T_)   // 16384
#define M_ (B_*T_)        // 16384
#define FFN_ 2048

typedef __attribute__((ext_vector_type(8))) short bf16x8;
typedef __attribute__((ext_vector_type(4))) float f32x4;

// ---------- bf16 helpers ----------
__device__ __forceinline__ unsigned short f2bf(float x) {
  unsigned int u = __float_as_uint(x);
  return (unsigned short)((u + 0x7FFFu + ((u >> 16) & 1u)) >> 16);
}
__device__ __forceinline__ float bf2f(unsigned short s) {
  return __uint_as_float(((unsigned int)s) << 16);
}
__device__ __forceinline__ unsigned int cvt_pk_bf16(float lo, float hi) {
  unsigned int r;
  asm("v_cvt_pk_bf16_f32 %0, %1, %2" : "=v"(r) : "v"(lo), "v"(hi));
  return r;
}

// ---------- async global->LDS, 16B per lane ----------
__device__ __forceinline__ void gld_lds16(const void* g, void* l) {
  __builtin_amdgcn_global_load_lds(
      (const __attribute__((address_space(1))) unsigned int*)g,
      (__attribute__((address_space(3))) unsigned int*)l, 16, 0, 0);
}

// swizzled LDS offsets (shorts): XOR 16B-granule with (row ^ row>>3)&7
__device__ __forceinline__ int swf(int row) { return (row ^ (row >> 3)) & 7; }
__device__ __forceinline__ int off64(int row, int k) {
  return row * 64 + (((k >> 3) ^ swf(row)) << 3) + (k & 7);
}
__device__ __forceinline__ int off128(int row, int k) {
  return row * 128 + (((k >> 3) ^ swf(row)) << 3) + (k & 7);
}

// ---------- bf16 MFMA GEMM (double-buffered, issue-early staging) ----------
// MODE 1: bf16 out (stride N).
// MODE 3: fused qk+v — N logical 1024, all K=512:
//   n0<512: qk cols -> f32 Cf (stride 512) + bf16 Cb + fused invn;
//   n0>=512: v cols -> bf16 Cb2 at col n0-512.
template<int BM, int MODE, bool HAS_BIAS, bool RELU, bool HAS_RESID>
__global__ __launch_bounds__(256) void gemm_bf16(
    const unsigned short* __restrict__ A, const unsigned short* __restrict__ BT,
    const float* __restrict__ bias, const unsigned short* __restrict__ resid,
    float* __restrict__ Cf, unsigned short* __restrict__ Cb,
    unsigned short* __restrict__ Cb2, float* __restrict__ invn,
    int M, int N, int K, int lda, int ldbt, int ldr)
{
  constexpr int MI = BM / 32;
  constexpr int ABSZ = (BM + 128) * 64;     // shorts per K-tile buffer (As|Bs)
  __shared__ __align__(16) unsigned short smem[2 * ABSZ];
  const int tid = threadIdx.x;
  const int lane = tid & 63;
  const int w = tid >> 6;
  const int wm = (w >> 1) * (BM / 2), wn = (w & 1) * 64;
  const int g = lane >> 4, cl = lane & 15;

  // XCD-aware block swizzle (T1)
  const int gx = gridDim.x;
  const int id = blockIdx.x + blockIdx.y * gx;
  const int cpx = (gx * gridDim.y) >> 3;
  const int swz = (id & 7) * cpx + (id >> 3);
  const int m0 = (swz / gx) * BM, n0 = (swz % gx) * 128;

  const bool isv = (MODE == 3) && (n0 >= 512);

  f32x4 acc[MI][4];
#pragma unroll
  for (int i = 0; i < MI; ++i)
#pragma unroll
    for (int j = 0; j < 4; ++j) acc[i][j] = (f32x4){0.f, 0.f, 0.f, 0.f};

  const int srow = tid >> 3;
  const int skc  = (tid & 7) * 8;

  // ---- K-loop: double-buffered; stage(k+1) issued BEFORE MFMA(k) so the
  // HBM latency hides under the MFMA block (T3-minimum; m97's drain stall
  // is ~60% here because K is short).
#define STAGE(BUF, K0)                                                        \
  do {                                                                        \
    unsigned short* As_ = smem + (BUF) * ABSZ;                                \
    unsigned short* Bs_ = As_ + BM * 64;                                      \
    _Pragma("unroll")                                                         \
    for (int ci = 0; ci < BM / 32; ++ci)                                      \
      gld_lds16(&A[(size_t)(m0 + ci * 32 + srow) * lda + (K0) + skc],         \
                &As_[ci * 2048 + tid * 8]);                                   \
    _Pragma("unroll")                                                         \
    for (int ci = 0; ci < 4; ++ci)                                            \
      gld_lds16(&BT[(size_t)(n0 + ci * 32 + srow) * ldbt + (K0) + skc],       \
                &Bs_[ci * 2048 + tid * 8]);                                   \
  } while (0)

  STAGE(0, 0);
  __syncthreads();
  const int KT = K >> 6;
  for (int kt = 0; kt < KT; ++kt) {
    if (kt + 1 < KT) STAGE((kt + 1) & 1, (kt + 1) * 64);
    const unsigned short* As = smem + (kt & 1) * ABSZ;
    const unsigned short* Bs = As + BM * 64;
#pragma unroll
    for (int kk = 0; kk < 64; kk += 32) {
      bf16x8 af[MI], bfr[4];
#pragma unroll
      for (int i = 0; i < MI; ++i)
        af[i] = *(const bf16x8*)&As[(wm + i * 16 + cl) * 64 + kk + g * 8];
#pragma unroll
      for (int j = 0; j < 4; ++j)
        bfr[j] = *(const bf16x8*)&Bs[(wn + j * 16 + cl) * 64 + kk + g * 8];
#pragma unroll
      for (int i = 0; i < MI; ++i)
#pragma unroll
        for (int j = 0; j < 4; ++j)
          acc[i][j] = __builtin_amdgcn_mfma_f32_16x16x32_bf16(af[i], bfr[j], acc[i][j], 0, 0, 0);
    }
    __syncthreads();
  }
#undef STAGE

  // ---- epilogue: regs -> LDS C-tile (swizzled, in buf0) -> coalesced out
  float bv[4];
  if constexpr (HAS_BIAS) {
#pragma unroll
    for (int j = 0; j < 4; ++j) bv[j] = bias[n0 + wn + j * 16 + cl];
  }
#pragma unroll
  for (int i = 0; i < MI; ++i) {
#pragma unroll
    for (int r = 0; r < 4; ++r) {
      const int lrow = wm + i * 16 + g * 4 + r;
      float v4[4];
      float ss = 0.f;
#pragma unroll
      for (int j = 0; j < 4; ++j) {
        float val = acc[i][j][r];
        if constexpr (HAS_BIAS) val += bv[j];
        if constexpr (RELU) val = fmaxf(val, 0.f);
        v4[j] = val;
        if constexpr (MODE == 3) {
          if (!isv) {
            ss += val * val;
            Cf[(size_t)(m0 + lrow) * 512 + n0 + wn + j * 16 + cl] = val;
          }
        }
      }
      const unsigned int p01 = cvt_pk_bf16(v4[0], v4[1]);
      const unsigned int p23 = cvt_pk_bf16(v4[2], v4[3]);
      const int sw = (lrow & 7) << 3;
      smem[lrow * 128 + ((wn +  0 + cl) ^ sw)] = (unsigned short)p01;
      smem[lrow * 128 + ((wn + 16 + cl) ^ sw)] = (unsigned short)(p01 >> 16);
      smem[lrow * 128 + ((wn + 32 + cl) ^ sw)] = (unsigned short)p23;
      smem[lrow * 128 + ((wn + 48 + cl) ^ sw)] = (unsigned short)(p23 >> 16);
      if constexpr (MODE == 3) {
        if (!isv) {
          ss += __shfl_xor(ss, 1); ss += __shfl_xor(ss, 2);
          ss += __shfl_xor(ss, 4); ss += __shfl_xor(ss, 8);
          if (cl == 0) {
            const int m = m0 + lrow;
            const int bb = m >> 12, t = m & (T_ - 1);
            const int hh = ((n0 + wn) >> 6) & 7;
            invn[((size_t)(bb * 8 + hh)) * T_ + t] = 1.0f / (sqrtf(ss) + 1e-6f);
          }
        }
      }
    }
  }
  __syncthreads();
#pragma unroll
  for (int l = 0; l < BM / 16; ++l) {
    const int idx = tid + l * 256;
    const int row = idx >> 4, c8 = (idx & 15) * 8;
    uint4 u = *(const uint4*)&smem[row * 128 + (c8 ^ ((row & 7) << 3))];
    if constexpr (HAS_RESID) {
      const uint4 rv = *(const uint4*)&resid[(size_t)(m0 + row) * ldr + n0 + c8];
      const unsigned short* sp = (const unsigned short*)&u;
      const unsigned short* rp = (const unsigned short*)&rv;
      float f[8];
#pragma unroll
      for (int e = 0; e < 8; ++e) f[e] = bf2f(sp[e]) + bf2f(rp[e]);
      u.x = cvt_pk_bf16(f[0], f[1]); u.y = cvt_pk_bf16(f[2], f[3]);
      u.z = cvt_pk_bf16(f[4], f[5]); u.w = cvt_pk_bf16(f[6], f[7]);
    }
    if constexpr (MODE == 3) {
      if (isv)
        *(uint4*)&Cb2[(size_t)(m0 + row) * 512 + (n0 - 512) + c8] = u;
      else
        *(uint4*)&Cb[(size_t)(m0 + row) * 512 + n0 + c8] = u;
    } else {
      *(uint4*)&Cb[(size_t)(m0 + row) * N + n0 + c8] = u;
    }
  }
}

// ---------- fused prep: transpose 5 weights + convert src rows ----------
__global__ __launch_bounds__(256) void prep_all(
    const float* __restrict__ Wqk, const float* __restrict__ Wv,
    const float* __restrict__ Wout, const float* __restrict__ W1,
    const float* __restrict__ W2, const float* __restrict__ src,
    unsigned short* __restrict__ WqkvT, unsigned short* __restrict__ WoutT,
    unsigned short* __restrict__ W1T, unsigned short* __restrict__ W2T,
    unsigned short* __restrict__ src_b)
{
  __shared__ float tile[32][33];
  int bid = blockIdx.x;
  if (bid >= 2816) {
    const int i = (bid - 2816) * 256 + threadIdx.x;   // < M*D/8
    const int m = i >> 6, d0 = (i & 63) * 8;
    float x[8];
    *(float4*)&x[0] = *(const float4*)&src[(size_t)m * D_ + d0];
    *(float4*)&x[4] = *(const float4*)&src[(size_t)m * D_ + d0 + 4];
    unsigned short hi[8];
#pragma unroll
    for (int e = 0; e < 8; ++e) hi[e] = f2bf(x[e]);
    *(uint4*)&src_b[(size_t)m * D_ + d0] = *(const uint4*)&hi[0];
    return;
  }
  const float* W; unsigned short* WT; int K, N, bx, by;
  if (bid < 256)        { W = Wqk;  WT = WqkvT; K = 512;  N = 512;
                          bx = bid & 15; by = bid >> 4; }
  else if (bid < 512)   { bid -= 256;  W = Wv; WT = WqkvT + (size_t)512 * 512;
                          K = 512; N = 512;
                          bx = bid & 15; by = bid >> 4; }
  else if (bid < 768)   { bid -= 512;  W = Wout; WT = WoutT; K = 512;  N = 512;
                          bx = bid & 15; by = bid >> 4; }
  else if (bid < 1792)  { bid -= 768;  W = W1;   WT = W1T;   K = 512;  N = 2048;
                          bx = bid & 63; by = bid >> 6; }
  else                  { bid -= 1792; W = W2;   WT = W2T;   K = 2048; N = 512;
                          bx = bid & 15; by = bid >> 4; }
  const int k0 = by * 32, n0 = bx * 32;
  const int tx = threadIdx.x & 31, ty = threadIdx.x >> 5;
#pragma unroll
  for (int r = 0; r < 32; r += 8)
    tile[ty + r][tx] = W[(size_t)(k0 + ty + r) * N + n0 + tx];
  __syncthreads();
#pragma unroll
  for (int r = 0; r < 32; r += 8)
    WT[(size_t)(n0 + ty + r) * K + k0 + tx] = f2bf(tile[tx][ty + r]);
}

// ---------- LSH hashing as GEMM + fused argmax (reads fp32 qk) ----------
__global__ __launch_bounds__(256) void hash_gemm_kernel(
    const float* __restrict__ qk, const float* __restrict__ rot,
    int* __restrict__ buckets)
{
  __shared__ __align__(16) float As[64][136];   // [k][m]
  __shared__ __align__(16) float Bs[64][132];   // [k][n]
  const int tid = threadIdx.x;
  const int tx = tid & 15, ty = tid >> 4;
  const int t0 = blockIdx.x * 128, bh = blockIdx.y;
  const int b = bh >> 3, hd = bh & 7;

#pragma unroll
  for (int l = 0; l < 8; ++l) {
    const int idx = tid + l * 256;
    const int row = idx >> 4;
    const int kq = (idx & 15) << 2;
    const float4 a = *(const float4*)&qk[((size_t)b * T_ + t0 + row) * D_ + hd * DH_ + kq];
    As[kq + 0][row] = a.x; As[kq + 1][row] = a.y;
    As[kq + 2][row] = a.z; As[kq + 3][row] = a.w;
  }
#pragma unroll
  for (int l = 0; l < 8; ++l) {
    const int idx = tid + l * 256;
    const int kr = idx >> 5;
    const int c4 = (idx & 31) << 2;
    *(float4*)&Bs[kr][c4] = *(const float4*)&rot[kr * 128 + c4];
  }
  __syncthreads();

  float acc[8][8];
#pragma unroll
  for (int i = 0; i < 8; ++i)
#pragma unroll
    for (int j = 0; j < 8; ++j) acc[i][j] = 0.f;

#pragma unroll 4
  for (int kk = 0; kk < 64; ++kk) {
    float a[8], bq[8];
    *(float4*)&a[0]  = *(const float4*)&As[kk][ty * 8];
    *(float4*)&a[4]  = *(const float4*)&As[kk][ty * 8 + 4];
    *(float4*)&bq[0] = *(const float4*)&Bs[kk][tx * 8];
    *(float4*)&bq[4] = *(const float4*)&Bs[kk][tx * 8 + 4];
#pragma unroll
    for (int i = 0; i < 8; ++i)
#pragma unroll
      for (int j = 0; j < 8; ++j)
        acc[i][j] = fmaf(a[i], bq[j], acc[i][j]);
  }
  __syncthreads();

  float* pval = &As[0][0];
  int*   pidx = (int*)&Bs[0][0];
  const int i0 = (tx & 3) * 8;
#pragma unroll
  for (int r = 0; r < 8; ++r) {
    float v = -3.0e38f; int idx = 127;
#pragma unroll
    for (int j = 0; j < 8; ++j) {
      const float p = acc[r][j];
      const int li = i0 + j;
      if (p > v || (p == v && li < idx)) { v = p; idx = li; }
      const float n = -p;
      const int ni = 32 + li;
      if (n > v || (n == v && ni < idx)) { v = n; idx = ni; }
    }
    pval[(ty * 8 + r) * 16 + tx] = v;
    pidx[(ty * 8 + r) * 16 + tx] = idx;
  }
  __syncthreads();

#pragma unroll
  for (int l = 0; l < 2; ++l) {
    const int id = tid + l * 256;
    const int tok = id >> 2, hh = id & 3;
    float v = pval[tok * 16 + hh * 4];
    int idx = pidx[tok * 16 + hh * 4];
#pragma unroll
    for (int e = 1; e < 4; ++e) {
      const float ov = pval[tok * 16 + hh * 4 + e];
      const int oi = pidx[tok * 16 + hh * 4 + e];
      if (ov > v || (ov == v && oi < idx)) { v = ov; idx = oi; }
    }
    buckets[((size_t)bh * NH_ + hh) * T_ + t0 + tok] = idx + hh * NB_;
  }
}

// ---------- per-bh bucket histogram + exclusive scan ----------
__global__ __launch_bounds__(256) void hist_kernel(
    const int* __restrict__ buckets, int* __restrict__ bstart)
{
  __shared__ int bins[256];
  const int bh = blockIdx.x;
  bins[threadIdx.x] = 0;
  __syncthreads();
  for (int e = threadIdx.x; e < NTICK_; e += 256)
    atomicAdd(&bins[buckets[(size_t)bh * NTICK_ + e]], 1);
  __syncthreads();
  if (threadIdx.x == 0) {
    int run = 0;
    for (int i = 0; i < 256; ++i) { const int c = bins[i]; bins[i] = run; run += c; }
  }
  __syncthreads();
  bstart[bh * 256 + threadIdx.x] = bins[threadIdx.x];
}

// ---------- stable compaction ----------
__global__ __launch_bounds__(64) void compact_kernel(
    const int* __restrict__ buckets, const int* __restrict__ bstart,
    int* __restrict__ sticker)
{
  const int bucket = blockIdx.x, bh = blockIdx.y;
  const int h = bucket >> 6;
  const int lane = threadIdx.x;
  int base = bstart[bh * 256 + bucket];
  const int* bk = buckets + (size_t)bh * NTICK_ + (size_t)h * T_;
  for (int it = 0; it < 64; ++it) {
    const int t = it * 64 + lane;
    const bool m = (bk[t] == bucket);
    const unsigned long long bal = __ballot(m);
    if (m) {
      const int pos = base + __popcll(bal & ((1ull << lane) - 1ull));
      sticker[(size_t)bh * NTICK_ + pos] = h * T_ + t;
    }
    base += __popcll(bal);
  }
}

// ---------- chunked LSH attention — MFMA, async staging ----------
__global__ __launch_bounds__(256) void attn_kernel(
    const unsigned short* __restrict__ qkb, const unsigned short* __restrict__ vb,
    const int* __restrict__ sticker, const float* __restrict__ invn,
    unsigned short* __restrict__ orowsb, float* __restrict__ logits)
{
  __shared__ __align__(16) unsigned short Rs[128 * 64];
  __shared__ __align__(16) unsigned short Vs[128 * 64];
  __shared__ int tks[128];
  __shared__ float invs[128];

  const int cx = blockIdx.x;
  const int c = (cx & 7) * 32 + (cx >> 3);   // XCD-aware chunk swizzle
  const int bh = blockIdx.y;
  const int b = bh >> 3, hd = bh & 7;
  const int tid = threadIdx.x;
  const int hr = c >> 6;
  const int w = tid >> 6, lane = tid & 63, g = lane >> 4, cl = lane & 15;

  if (tid < 128) {
    const int sc = (tid < 64) ? c : ((c + CHUNKS_ - 1) & (CHUNKS_ - 1));
    const int tick = sticker[(size_t)bh * NTICK_ + sc * 64 + (tid & 63)];
    const int t = tick & (T_ - 1);
    tks[tid] = t;
    invs[tid] = invn[bh * T_ + t];
  }
  __syncthreads();

  // stage qk + v rows via global_load_lds: linear LDS dest, pre-swizzled source
  {
    const int sr = lane >> 3, gq = lane & 7;
#pragma unroll
    for (int l = 0; l < 4; ++l) {
      const int row = l * 32 + w * 8 + sr;
      const size_t gb = ((size_t)b * T_ + tks[row]) * D_ + hd * DH_
                      + ((gq ^ swf(row)) << 3);
      const int dst = (l * 32 + w * 8) * 64 + lane * 8;
      gld_lds16(&qkb[gb], &Rs[dst]);
      gld_lds16(&vb[gb],  &Vs[dst]);
    }
  }
  __syncthreads();

  // dots (MFMA from Rs) + V transpose-read (b64) into regs
  f32x4 sacc[8];
#pragma unroll
  for (int j = 0; j < 8; ++j) sacc[j] = (f32x4){0.f, 0.f, 0.f, 0.f};
  __builtin_amdgcn_s_setprio(1);
#pragma unroll
  for (int kk = 0; kk < 2; ++kk) {
    const bf16x8 aq = *(const bf16x8*)&Rs[off64(w * 16 + cl, kk * 32 + g * 8)];
#pragma unroll
    for (int j = 0; j < 8; ++j) {
      const bf16x8 bk = *(const bf16x8*)&Rs[off64(j * 16 + cl, kk * 32 + g * 8)];
      sacc[j] = __builtin_amdgcn_mfma_f32_16x16x32_bf16(aq, bk, sacc[j], 0, 0, 0);
    }
  }
  __builtin_amdgcn_s_setprio(0);
  const int d0 = (tid & 15) * 4, tg = tid >> 4;
  unsigned int qw[8][2];
#pragma unroll
  for (int e = 0; e < 8; ++e) {
    const uint2 q = *(const uint2*)&Vs[off64(tg * 8 + e, d0)];
    qw[e][0] = q.x; qw[e][1] = q.y;
  }
  __syncthreads();

  // write V^T into Vs region; softmax (skip-max) -> unnormalized P into Rs
  {
    unsigned short col[4][8];
#pragma unroll
    for (int e = 0; e < 8; ++e) {
      col[0][e] = (unsigned short)(qw[e][0] & 0xffffu);
      col[1][e] = (unsigned short)(qw[e][0] >> 16);
      col[2][e] = (unsigned short)(qw[e][1] & 0xffffu);
      col[3][e] = (unsigned short)(qw[e][1] >> 16);
    }
#pragma unroll
    for (int dd = 0; dd < 4; ++dd)
      *(uint4*)&Vs[off128(d0 + dd, tg * 8)] = *(const uint4*)&col[dd][0];
  }

  float iv[8]; int tk[8];
#pragma unroll
  for (int j = 0; j < 8; ++j) {
    iv[j] = invs[j * 16 + cl] * 0.125f;
    tk[j] = tks[j * 16 + cl];
  }
  float pinv[4];
#pragma unroll
  for (int r = 0; r < 4; ++r) {
    const int row = w * 16 + g * 4 + r;
    const int tq = tks[row];
    float e8[8];
    float sum = 0.f;
#pragma unroll
    for (int j = 0; j < 8; ++j) {
      float e = __expf(sacc[j][r] * iv[j]);
      if (tq == tk[j]) e = 0.f;
      e8[j] = e;
      sum += e;
    }
    sum += __shfl_xor(sum, 1); sum += __shfl_xor(sum, 2);
    sum += __shfl_xor(sum, 4); sum += __shfl_xor(sum, 8);
    pinv[r] = 1.f / sum;
#pragma unroll
    for (int j = 0; j < 8; j += 2) {
      const unsigned int pk = cvt_pk_bf16(e8[j], e8[j + 1]);
      Rs[off128(row, j * 16 + cl)]       = (unsigned short)pk;
      Rs[off128(row, (j + 1) * 16 + cl)] = (unsigned short)(pk >> 16);
    }
    if (cl == 0)
      logits[((size_t)bh * T_ + tq) * NH_ + hr] = __logf(sum);
  }
  __syncthreads();

  // PV: A = P (Rs), B = V^T (Vs)
  f32x4 oacc[4];
#pragma unroll
  for (int jd = 0; jd < 4; ++jd) oacc[jd] = (f32x4){0.f, 0.f, 0.f, 0.f};
  __builtin_amdgcn_s_setprio(1);
#pragma unroll
  for (int ks = 0; ks < 4; ++ks) {
    const bf16x8 pa = *(const bf16x8*)&Rs[off128(w * 16 + cl, ks * 32 + g * 8)];
#pragma unroll
    for (int jd = 0; jd < 4; ++jd) {
      const bf16x8 vv = *(const bf16x8*)&Vs[off128(jd * 16 + cl, ks * 32 + g * 8)];
      oacc[jd] = __builtin_amdgcn_mfma_f32_16x16x32_bf16(pa, vv, oacc[jd], 0, 0, 0);
    }
  }
  __builtin_amdgcn_s_setprio(0);
  __syncthreads();

  // O (scaled by 1/sum) into Rs, then coalesced scatter to global
#pragma unroll
  for (int r = 0; r < 4; ++r) {
    const int row = w * 16 + g * 4 + r;
    const unsigned int q01 = cvt_pk_bf16(oacc[0][r] * pinv[r], oacc[1][r] * pinv[r]);
    const unsigned int q23 = cvt_pk_bf16(oacc[2][r] * pinv[r], oacc[3][r] * pinv[r]);
    Rs[off64(row,      cl)] = (unsigned short)q01;
    Rs[off64(row, 16 + cl)] = (unsigned short)(q01 >> 16);
    Rs[off64(row, 32 + cl)] = (unsigned short)q23;
    Rs[off64(row, 48 + cl)] = (unsigned short)(q23 >> 16);
  }
  __syncthreads();

#pragma unroll
  for (int l = 0; l < 2; ++l) {
    const int idx = tid + l * 256;
    const int row = idx >> 3, k0 = (idx & 7) * 8;
    *(uint4*)&orowsb[(((size_t)bh * T_ + tks[row]) * NH_ + hr) * DH_ + k0] =
        *(const uint4*)&Rs[off64(row, k0)];
  }
}

// ---------- combine hash rounds (contiguous per-token layout) ----------
__global__ __launch_bounds__(256) void combine_kernel(
    const unsigned short* __restrict__ orowsb, const float* __restrict__ logits,
    unsigned short* __restrict__ ocombb)
{
  const int gid = blockIdx.x * 4 + (threadIdx.x >> 6);
  const int lane = threadIdx.x & 63;
  const int bh = gid >> 12, t = gid & (T_ - 1);
  const int b = bh >> 3, hd = bh & 7;
  const float4 lg = *(const float4*)&logits[((size_t)bh * T_ + t) * NH_];
  const float m = fmaxf(fmaxf(lg.x, lg.y), fmaxf(lg.z, lg.w));
  const float w0 = __expf(lg.x - m), w1 = __expf(lg.y - m);
  const float w2 = __expf(lg.z - m), w3 = __expf(lg.w - m);
  const float inv = 1.f / (w0 + w1 + w2 + w3);
  const size_t rb = ((size_t)bh * T_ + t) * (NH_ * DH_) + lane;
  const float o = w0 * bf2f(orowsb[rb])
                + w1 * bf2f(orowsb[rb + DH_])
                + w2 * bf2f(orowsb[rb + 2 * DH_])
                + w3 * bf2f(orowsb[rb + 3 * DH_]);
  ocombb[((size_t)b * T_ + t) * D_ + hd * DH_ + lane] = f2bf(o * inv);
}

// ---------- LayerNorm (bf16 in, fp32 out) ----------
__global__ __launch_bounds__(256) void ln_kernel(
    const unsigned short* __restrict__ yb, const float* __restrict__ gamma,
    const float* __restrict__ beta, float* __restrict__ out)
{
  const int row = blockIdx.x * 4 + (threadIdx.x >> 6);
  const int lane = threadIdx.x & 63;
  const size_t base = (size_t)row * D_ + lane * 8;
  const uint4 u = *(const uint4*)&yb[base];
  const unsigned short* up = (const unsigned short*)&u;
  float x[8];
#pragma unroll
  for (int i = 0; i < 8; ++i) x[i] = bf2f(up[i]);
  float s = 0.f;
#pragma unroll
  for (int i = 0; i < 8; ++i) s += x[i];
#pragma unroll
  for (int m = 32; m >= 1; m >>= 1) s += __shfl_xor(s, m);
  const float mu = s * (1.f / D_);
  float vs = 0.f;
#pragma unroll
  for (int i = 0; i < 8; ++i) { const float d = x[i] - mu; vs += d * d; }
#pragma unroll
  for (int m = 32; m >= 1; m >>= 1) vs += __shfl_xor(vs, m);
  const float rstd = rsqrtf(vs * (1.f / D_) + 1e-6f);
  float gm[8], bt[8];
  *(float4*)&gm[0] = *(const float4*)&gamma[lane * 8];
  *(float4*)&gm[4] = *(const float4*)&gamma[lane * 8 + 4];
  *(float4*)&bt[0] = *(const float4*)&beta[lane * 8];
  *(float4*)&bt[4] = *(const float4*)&beta[lane * 8 + 4];
  float o[8];
#pragma unroll
  for (int i = 0; i < 8; ++i) o[i] = (x[i] - mu) * rstd * gm[i] + bt[i];
  *(float4*)&out[base]     = make_float4(o[0], o[1], o[2], o[3]);
  *(float4*)&out[base + 4] = make_float4(o[4], o[5], o[6], o[7]);
}

extern "C" void kernel_launch(void* const* d_in, const int* in_sizes, int n_in,
                              void* d_out, int out_size, void* d_ws, size_t ws_size,
                              hipStream_t stream) {
  (void)in_sizes; (void)n_in; (void)out_size; (void)ws_size;
  const float* src   = (const float*)d_in[0];
  const float* Wqk   = (const float*)d_in[1];
  const float* Wv    = (const float*)d_in[2];
  const float* Wout  = (const float*)d_in[3];
  const float* bout  = (const float*)d_in[4];
  const float* W1    = (const float*)d_in[5];
  const float* b1    = (const float*)d_in[6];
  const float* W2    = (const float*)d_in[7];
  const float* b2    = (const float*)d_in[8];
  const float* gamma = (const float*)d_in[9];
  const float* beta  = (const float*)d_in[10];
  const float* rot   = (const float*)d_in[11];
  float* out = (float*)d_out;

  // ---- workspace layout ----
  char* ws = (char*)d_ws;
  const size_t MB = 1024 * 1024;
  float*          qk      = (float*)(ws);                     // 32 MB; dead after hash
  unsigned short* src_b   = (unsigned short*)(ws + 32 * MB);  // 16 MB; live thru Wout resid
  unsigned short* v_b     = (unsigned short*)(ws + 48 * MB);  // 16 MB; -> x_b
  unsigned short* orows_b = (unsigned short*)(ws + 64 * MB);  // 64 MB; -> hidden_b
  unsigned short* qk_b    = (unsigned short*)(ws + 128 * MB); // 16 MB; -> ocomb_b
  char* p = ws + 144 * MB;
  float* logits  = (float*)p; p += (size_t)BH_ * T_ * NH_ * 4;
  int*   buckets = (int*)p;   p += (size_t)BH_ * NH_ * T_ * 4;
  int*   sticker = (int*)p;   p += (size_t)BH_ * NTICK_ * 4;
  int*   bstart  = (int*)p;   p += (size_t)BH_ * 256 * 4;
  float* invn    = (float*)p; p += (size_t)BH_ * T_ * 4;
  unsigned short* WqkvT = (unsigned short*)p; p += (size_t)1024 * 512 * 2;
  unsigned short* WoutT = (unsigned short*)p; p += (size_t)D_ * D_ * 2;
  unsigned short* W1T   = (unsigned short*)p; p += (size_t)FFN_ * D_ * 2;
  unsigned short* W2T   = (unsigned short*)p; p += (size_t)D_ * FFN_ * 2;

  unsigned short* ocomb_b  = qk_b;                 // after attn consumed qk_b
  unsigned short* x_b      = v_b;                  // after attn consumed v_b
  unsigned short* hidden_b = orows_b;              // after combine consumed orows
  unsigned short* ybuf_b   = (unsigned short*)ws;  // after hash consumed qk f32

  // 0: all conversions in one launch (weights + src convert)
  prep_all<<<2816 + M_ * D_ / 8 / 256, 256, 0, stream>>>(
      Wqk, Wv, Wout, W1, W2, src, WqkvT, WoutT, W1T, W2T, src_b);

  // 1: fused qk+v projection (K=512; qk cols emit fp32 + invn)
  gemm_bf16<128, 3, false, false, false>
      <<<dim3(1024 / 128, M_ / 128), 256, 0, stream>>>(
      src_b, WqkvT, nullptr, nullptr, qk, qk_b, v_b, invn,
      M_, 1024, D_, D_, D_, 0);
  // 2: LSH buckets (GEMM + fused argmax)
  hash_gemm_kernel<<<dim3(T_ / 128, BH_), 256, 0, stream>>>(qk, rot, buckets);
  // 3-4: counting sort
  hist_kernel<<<BH_, 256, 0, stream>>>(buckets, bstart);
  compact_kernel<<<dim3(256, BH_), 64, 0, stream>>>(buckets, bstart, sticker);
  // 5: chunked attention (MFMA)
  attn_kernel<<<dim3(CHUNKS_, BH_), 256, 0, stream>>>(
      qk_b, v_b, sticker, invn, orows_b, logits);
  // 6: combine hash rounds (writes into qk_b region)
  combine_kernel<<<BH_ * T_ / 4, 256, 0, stream>>>(orows_b, logits, ocomb_b);
  // 7: out projection + bias + residual(src_b)
  gemm_bf16<128, 1, true, false, true>
      <<<dim3(D_ / 128, M_ / 128), 256, 0, stream>>>(
      ocomb_b, WoutT, bout, src_b, nullptr, x_b, nullptr, nullptr,
      M_, D_, D_, D_, D_, D_);
  // 8: FFN1 (relu)
  gemm_bf16<128, 1, true, true, false>
      <<<dim3(FFN_ / 128, M_ / 128), 256, 0, stream>>>(
      x_b, W1T, b1, nullptr, nullptr, hidden_b, nullptr, nullptr,
      M_, FFN_, D_, D_, D_, 0);
  // 9: FFN2 + bias + residual(x_b) -> bf16 y
  gemm_bf16<128, 1, true, false, true>
      <<<dim3(D_ / 128, M_ / 128), 256, 0, stream>>>(
      hidden_b, W2T, b2, x_b, nullptr, ybuf_b, nullptr, nullptr,
      M_, D_, FFN_, FFN_, FFN_, D_);
  // 10: LayerNorm
  ln_kernel<<<M_ / 4, 256, 0, stream>>>(ybuf_b, gamma, beta, out);
}

// Round 11
// 332.617 us; speedup vs baseline: 1.1468x; 1.0050x over previous
//
#include <hip/hip_runtime.h>

#define B_ 4
#define T_ 4096
#define D_ 512
#define H_ 8
#define DH_ 64
#define NH_ 4
#define NB_ 64            // n_buckets = T/BUCKET
#define BH_ (B_*H_)       // 32
#define CHUNKS_ (NH_*NB_) // 256
#define NTICK_ (NH_*T_)   // 16384
#define M_ (B_*T_)        // 16384
#define FFN_ 2048

typedef __attribute__((ext_vector_type(8))) short bf16x8;
typedef __attribute__((ext_vector_type(4))) float f32x4;

// ---------- bf16 helpers ----------
__device__ __forceinline__ unsigned short f2bf(float x) {
  unsigned int u = __float_as_uint(x);
  return (unsigned short)((u + 0x7FFFu + ((u >> 16) & 1u)) >> 16);
}
__device__ __forceinline__ float bf2f(unsigned short s) {
  return __uint_as_float(((unsigned int)s) << 16);
}
__device__ __forceinline__ unsigned int cvt_pk_bf16(float lo, float hi) {
  unsigned int r;
  asm("v_cvt_pk_bf16_f32 %0, %1, %2" : "=v"(r) : "v"(lo), "v"(hi));
  return r;
}

// ---------- async global->LDS, 16B per lane ----------
__device__ __forceinline__ void gld_lds16(const void* g, void* l) {
  __builtin_amdgcn_global_load_lds(
      (const __attribute__((address_space(1))) unsigned int*)g,
      (__attribute__((address_space(3))) unsigned int*)l, 16, 0, 0);
}

// swizzled LDS offsets (shorts): XOR 16B-granule with (row ^ row>>3)&7
__device__ __forceinline__ int swf(int row) { return (row ^ (row >> 3)) & 7; }
__device__ __forceinline__ int off64(int row, int k) {
  return row * 64 + (((k >> 3) ^ swf(row)) << 3) + (k & 7);
}
__device__ __forceinline__ int off128(int row, int k) {
  return row * 128 + (((k >> 3) ^ swf(row)) << 3) + (k & 7);
}

// ---------- bf16 MFMA GEMM (counted-vmcnt double-buffer, T3/T4) ----------
// MODE 1: bf16 out (stride N).
// MODE 3: fused qk+v — N logical 1024, all K=512:
//   n0<512: qk cols -> f32 Cf (stride 512) + bf16 Cb + fused invn;
//   n0>=512: v cols -> bf16 Cb2 at col n0-512.
template<int BM, int MODE, bool HAS_BIAS, bool RELU, bool HAS_RESID>
__global__ __launch_bounds__(256) void gemm_bf16(
    const unsigned short* __restrict__ A, const unsigned short* __restrict__ BT,
    const float* __restrict__ bias, const unsigned short* __restrict__ resid,
    float* __restrict__ Cf, unsigned short* __restrict__ Cb,
    unsigned short* __restrict__ Cb2, float* __restrict__ invn,
    int M, int N, int K, int lda, int ldbt, int ldr)
{
  constexpr int MI = BM / 32;
  constexpr int ABSZ = (BM + 128) * 64;     // shorts per K-tile buffer (As|Bs)
  __shared__ __align__(16) unsigned short smem[2 * ABSZ];
  const int tid = threadIdx.x;
  const int lane = tid & 63;
  const int w = tid >> 6;
  const int wm = (w >> 1) * (BM / 2), wn = (w & 1) * 64;
  const int g = lane >> 4, cl = lane & 15;

  // XCD-aware block swizzle (T1)
  const int gx = gridDim.x;
  const int id = blockIdx.x + blockIdx.y * gx;
  const int cpx = (gx * gridDim.y) >> 3;
  const int swz = (id & 7) * cpx + (id >> 3);
  const int m0 = (swz / gx) * BM, n0 = (swz % gx) * 128;

  const bool isv = (MODE == 3) && (n0 >= 512);

  f32x4 acc[MI][4];
#pragma unroll
  for (int i = 0; i < MI; ++i)
#pragma unroll
    for (int j = 0; j < 4; ++j) acc[i][j] = (f32x4){0.f, 0.f, 0.f, 0.f};

  const int srow = tid >> 3;
  const int skc  = (tid & 7) * 8;

  // K-loop: counted-vmcnt double buffer. Each STAGE = 8 gld_lds16/thread.
  // barrier#1 waits ONLY for tile t (vmcnt(8): t+1's 8 stay in flight);
  // barrier#2 is a raw s_barrier (no vmcnt drain) — the fix for R10's
  // half-broken dbuf where __syncthreads' vmcnt(0) drained the prefetch.
#define STAGE(BUF, K0)                                                        \
  do {                                                                        \
    unsigned short* As_ = smem + (BUF) * ABSZ;                                \
    unsigned short* Bs_ = As_ + BM * 64;                                      \
    _Pragma("unroll")                                                         \
    for (int ci = 0; ci < BM / 32; ++ci)                                      \
      gld_lds16(&A[(size_t)(m0 + ci * 32 + srow) * lda + (K0) + skc],         \
                &As_[ci * 2048 + tid * 8]);                                   \
    _Pragma("unroll")                                                         \
    for (int ci = 0; ci < 4; ++ci)                                            \
      gld_lds16(&BT[(size_t)(n0 + ci * 32 + srow) * ldbt + (K0) + skc],       \
                &Bs_[ci * 2048 + tid * 8]);                                   \
  } while (0)

  STAGE(0, 0);
  const int KT = K >> 6;
  for (int kt = 0; kt < KT; ++kt) {
    if (kt + 1 < KT) {
      STAGE((kt + 1) & 1, (kt + 1) * 64);
      asm volatile("s_waitcnt vmcnt(8)" ::: "memory");   // tile kt landed
    } else {
      asm volatile("s_waitcnt vmcnt(0)" ::: "memory");
    }
    __builtin_amdgcn_s_barrier();
    const unsigned short* As = smem + (kt & 1) * ABSZ;
    const unsigned short* Bs = As + BM * 64;
#pragma unroll
    for (int kk = 0; kk < 64; kk += 32) {
      bf16x8 af[MI], bfr[4];
#pragma unroll
      for (int i = 0; i < MI; ++i)
        af[i] = *(const bf16x8*)&As[(wm + i * 16 + cl) * 64 + kk + g * 8];
#pragma unroll
      for (int j = 0; j < 4; ++j)
        bfr[j] = *(const bf16x8*)&Bs[(wn + j * 16 + cl) * 64 + kk + g * 8];
#pragma unroll
      for (int i = 0; i < MI; ++i)
#pragma unroll
        for (int j = 0; j < 4; ++j)
          acc[i][j] = __builtin_amdgcn_mfma_f32_16x16x32_bf16(af[i], bfr[j], acc[i][j], 0, 0, 0);
    }
    // all waves done reading buf kt&1 before next iter's STAGE overwrites it
    asm volatile("" ::: "memory");
    __builtin_amdgcn_s_barrier();
  }
#undef STAGE

  // ---- epilogue: regs -> LDS C-tile (swizzled, in buf0) -> coalesced out
  float bv[4];
  if constexpr (HAS_BIAS) {
#pragma unroll
    for (int j = 0; j < 4; ++j) bv[j] = bias[n0 + wn + j * 16 + cl];
  }
#pragma unroll
  for (int i = 0; i < MI; ++i) {
#pragma unroll
    for (int r = 0; r < 4; ++r) {
      const int lrow = wm + i * 16 + g * 4 + r;
      float v4[4];
      float ss = 0.f;
#pragma unroll
      for (int j = 0; j < 4; ++j) {
        float val = acc[i][j][r];
        if constexpr (HAS_BIAS) val += bv[j];
        if constexpr (RELU) val = fmaxf(val, 0.f);
        v4[j] = val;
        if constexpr (MODE == 3) {
          if (!isv) {
            ss += val * val;
            Cf[(size_t)(m0 + lrow) * 512 + n0 + wn + j * 16 + cl] = val;
          }
        }
      }
      const unsigned int p01 = cvt_pk_bf16(v4[0], v4[1]);
      const unsigned int p23 = cvt_pk_bf16(v4[2], v4[3]);
      const int sw = (lrow & 7) << 3;
      smem[lrow * 128 + ((wn +  0 + cl) ^ sw)] = (unsigned short)p01;
      smem[lrow * 128 + ((wn + 16 + cl) ^ sw)] = (unsigned short)(p01 >> 16);
      smem[lrow * 128 + ((wn + 32 + cl) ^ sw)] = (unsigned short)p23;
      smem[lrow * 128 + ((wn + 48 + cl) ^ sw)] = (unsigned short)(p23 >> 16);
      if constexpr (MODE == 3) {
        if (!isv) {
          ss += __shfl_xor(ss, 1); ss += __shfl_xor(ss, 2);
          ss += __shfl_xor(ss, 4); ss += __shfl_xor(ss, 8);
          if (cl == 0) {
            const int m = m0 + lrow;
            const int bb = m >> 12, t = m & (T_ - 1);
            const int hh = ((n0 + wn) >> 6) & 7;
            invn[((size_t)(bb * 8 + hh)) * T_ + t] = 1.0f / (sqrtf(ss) + 1e-6f);
          }
        }
      }
    }
  }
  __syncthreads();
#pragma unroll
  for (int l = 0; l < BM / 16; ++l) {
    const int idx = tid + l * 256;
    const int row = idx >> 4, c8 = (idx & 15) * 8;
    uint4 u = *(const uint4*)&smem[row * 128 + (c8 ^ ((row & 7) << 3))];
    if constexpr (HAS_RESID) {
      const uint4 rv = *(const uint4*)&resid[(size_t)(m0 + row) * ldr + n0 + c8];
      const unsigned short* sp = (const unsigned short*)&u;
      const unsigned short* rp = (const unsigned short*)&rv;
      float f[8];
#pragma unroll
      for (int e = 0; e < 8; ++e) f[e] = bf2f(sp[e]) + bf2f(rp[e]);
      u.x = cvt_pk_bf16(f[0], f[1]); u.y = cvt_pk_bf16(f[2], f[3]);
      u.z = cvt_pk_bf16(f[4], f[5]); u.w = cvt_pk_bf16(f[6], f[7]);
    }
    if constexpr (MODE == 3) {
      if (isv)
        *(uint4*)&Cb2[(size_t)(m0 + row) * 512 + (n0 - 512) + c8] = u;
      else
        *(uint4*)&Cb[(size_t)(m0 + row) * 512 + n0 + c8] = u;
    } else {
      *(uint4*)&Cb[(size_t)(m0 + row) * N + n0 + c8] = u;
    }
  }
}

// ---------- fused prep: transpose 5 weights + convert src rows ----------
__global__ __launch_bounds__(256) void prep_all(
    const float* __restrict__ Wqk, const float* __restrict__ Wv,
    const float* __restrict__ Wout, const float* __restrict__ W1,
    const float* __restrict__ W2, const float* __restrict__ src,
    unsigned short* __restrict__ WqkvT, unsigned short* __restrict__ WoutT,
    unsigned short* __restrict__ W1T, unsigned short* __restrict__ W2T,
    unsigned short* __restrict__ src_b)
{
  __shared__ float tile[32][33];
  int bid = blockIdx.x;
  if (bid >= 2816) {
    const int i = (bid - 2816) * 256 + threadIdx.x;   // < M*D/8
    const int m = i >> 6, d0 = (i & 63) * 8;
    float x[8];
    *(float4*)&x[0] = *(const float4*)&src[(size_t)m * D_ + d0];
    *(float4*)&x[4] = *(const float4*)&src[(size_t)m * D_ + d0 + 4];
    unsigned short hi[8];
#pragma unroll
    for (int e = 0; e < 8; ++e) hi[e] = f2bf(x[e]);
    *(uint4*)&src_b[(size_t)m * D_ + d0] = *(const uint4*)&hi[0];
    return;
  }
  const float* W; unsigned short* WT; int K, N, bx, by;
  if (bid < 256)        { W = Wqk;  WT = WqkvT; K = 512;  N = 512;
                          bx = bid & 15; by = bid >> 4; }
  else if (bid < 512)   { bid -= 256;  W = Wv; WT = WqkvT + (size_t)512 * 512;
                          K = 512; N = 512;
                          bx = bid & 15; by = bid >> 4; }
  else if (bid < 768)   { bid -= 512;  W = Wout; WT = WoutT; K = 512;  N = 512;
                          bx = bid & 15; by = bid >> 4; }
  else if (bid < 1792)  { bid -= 768;  W = W1;   WT = W1T;   K = 512;  N = 2048;
                          bx = bid & 63; by = bid >> 6; }
  else                  { bid -= 1792; W = W2;   WT = W2T;   K = 2048; N = 512;
                          bx = bid & 15; by = bid >> 4; }
  const int k0 = by * 32, n0 = bx * 32;
  const int tx = threadIdx.x & 31, ty = threadIdx.x >> 5;
#pragma unroll
  for (int r = 0; r < 32; r += 8)
    tile[ty + r][tx] = W[(size_t)(k0 + ty + r) * N + n0 + tx];
  __syncthreads();
#pragma unroll
  for (int r = 0; r < 32; r += 8)
    WT[(size_t)(n0 + ty + r) * K + k0 + tx] = f2bf(tile[tx][ty + r]);
}

// ---------- LSH hashing as GEMM + fused argmax (reads fp32 qk) ----------
__global__ __launch_bounds__(256) void hash_gemm_kernel(
    const float* __restrict__ qk, const float* __restrict__ rot,
    int* __restrict__ buckets)
{
  __shared__ __align__(16) float As[64][136];   // [k][m]
  __shared__ __align__(16) float Bs[64][132];   // [k][n]
  const int tid = threadIdx.x;
  const int tx = tid & 15, ty = tid >> 4;
  const int t0 = blockIdx.x * 128, bh = blockIdx.y;
  const int b = bh >> 3, hd = bh & 7;

#pragma unroll
  for (int l = 0; l < 8; ++l) {
    const int idx = tid + l * 256;
    const int row = idx >> 4;
    const int kq = (idx & 15) << 2;
    const float4 a = *(const float4*)&qk[((size_t)b * T_ + t0 + row) * D_ + hd * DH_ + kq];
    As[kq + 0][row] = a.x; As[kq + 1][row] = a.y;
    As[kq + 2][row] = a.z; As[kq + 3][row] = a.w;
  }
#pragma unroll
  for (int l = 0; l < 8; ++l) {
    const int idx = tid + l * 256;
    const int kr = idx >> 5;
    const int c4 = (idx & 31) << 2;
    *(float4*)&Bs[kr][c4] = *(const float4*)&rot[kr * 128 + c4];
  }
  __syncthreads();

  float acc[8][8];
#pragma unroll
  for (int i = 0; i < 8; ++i)
#pragma unroll
    for (int j = 0; j < 8; ++j) acc[i][j] = 0.f;

#pragma unroll 4
  for (int kk = 0; kk < 64; ++kk) {
    float a[8], bq[8];
    *(float4*)&a[0]  = *(const float4*)&As[kk][ty * 8];
    *(float4*)&a[4]  = *(const float4*)&As[kk][ty * 8 + 4];
    *(float4*)&bq[0] = *(const float4*)&Bs[kk][tx * 8];
    *(float4*)&bq[4] = *(const float4*)&Bs[kk][tx * 8 + 4];
#pragma unroll
    for (int i = 0; i < 8; ++i)
#pragma unroll
      for (int j = 0; j < 8; ++j)
        acc[i][j] = fmaf(a[i], bq[j], acc[i][j]);
  }
  __syncthreads();

  float* pval = &As[0][0];
  int*   pidx = (int*)&Bs[0][0];
  const int i0 = (tx & 3) * 8;
#pragma unroll
  for (int r = 0; r < 8; ++r) {
    float v = -3.0e38f; int idx = 127;
#pragma unroll
    for (int j = 0; j < 8; ++j) {
      const float p = acc[r][j];
      const int li = i0 + j;
      if (p > v || (p == v && li < idx)) { v = p; idx = li; }
      const float n = -p;
      const int ni = 32 + li;
      if (n > v || (n == v && ni < idx)) { v = n; idx = ni; }
    }
    pval[(ty * 8 + r) * 16 + tx] = v;
    pidx[(ty * 8 + r) * 16 + tx] = idx;
  }
  __syncthreads();

#pragma unroll
  for (int l = 0; l < 2; ++l) {
    const int id = tid + l * 256;
    const int tok = id >> 2, hh = id & 3;
    float v = pval[tok * 16 + hh * 4];
    int idx = pidx[tok * 16 + hh * 4];
#pragma unroll
    for (int e = 1; e < 4; ++e) {
      const float ov = pval[tok * 16 + hh * 4 + e];
      const int oi = pidx[tok * 16 + hh * 4 + e];
      if (ov > v || (ov == v && oi < idx)) { v = ov; idx = oi; }
    }
    buckets[((size_t)bh * NH_ + hh) * T_ + t0 + tok] = idx + hh * NB_;
  }
}

// ---------- per-bh bucket histogram + exclusive scan ----------
__global__ __launch_bounds__(256) void hist_kernel(
    const int* __restrict__ buckets, int* __restrict__ bstart)
{
  __shared__ int bins[256];
  const int bh = blockIdx.x;
  bins[threadIdx.x] = 0;
  __syncthreads();
  for (int e = threadIdx.x; e < NTICK_; e += 256)
    atomicAdd(&bins[buckets[(size_t)bh * NTICK_ + e]], 1);
  __syncthreads();
  if (threadIdx.x == 0) {
    int run = 0;
    for (int i = 0; i < 256; ++i) { const int c = bins[i]; bins[i] = run; run += c; }
  }
  __syncthreads();
  bstart[bh * 256 + threadIdx.x] = bins[threadIdx.x];
}

// ---------- stable compaction ----------
__global__ __launch_bounds__(64) void compact_kernel(
    const int* __restrict__ buckets, const int* __restrict__ bstart,
    int* __restrict__ sticker)
{
  const int bucket = blockIdx.x, bh = blockIdx.y;
  const int h = bucket >> 6;
  const int lane = threadIdx.x;
  int base = bstart[bh * 256 + bucket];
  const int* bk = buckets + (size_t)bh * NTICK_ + (size_t)h * T_;
  for (int it = 0; it < 64; ++it) {
    const int t = it * 64 + lane;
    const bool m = (bk[t] == bucket);
    const unsigned long long bal = __ballot(m);
    if (m) {
      const int pos = base + __popcll(bal & ((1ull << lane) - 1ull));
      sticker[(size_t)bh * NTICK_ + pos] = h * T_ + t;
    }
    base += __popcll(bal);
  }
}

// ---------- chunked LSH attention — MFMA, async staging ----------
__global__ __launch_bounds__(256) void attn_kernel(
    const unsigned short* __restrict__ qkb, const unsigned short* __restrict__ vb,
    const int* __restrict__ sticker, const float* __restrict__ invn,
    unsigned short* __restrict__ orowsb, float* __restrict__ logits)
{
  __shared__ __align__(16) unsigned short Rs[128 * 64];
  __shared__ __align__(16) unsigned short Vs[128 * 64];
  __shared__ int tks[128];
  __shared__ float invs[128];

  const int cx = blockIdx.x;
  const int c = (cx & 7) * 32 + (cx >> 3);   // XCD-aware chunk swizzle
  const int bh = blockIdx.y;
  const int b = bh >> 3, hd = bh & 7;
  const int tid = threadIdx.x;
  const int hr = c >> 6;
  const int w = tid >> 6, lane = tid & 63, g = lane >> 4, cl = lane & 15;

  if (tid < 128) {
    const int sc = (tid < 64) ? c : ((c + CHUNKS_ - 1) & (CHUNKS_ - 1));
    const int tick = sticker[(size_t)bh * NTICK_ + sc * 64 + (tid & 63)];
    const int t = tick & (T_ - 1);
    tks[tid] = t;
    invs[tid] = invn[bh * T_ + t];
  }
  __syncthreads();

  // stage qk + v rows via global_load_lds: linear LDS dest, pre-swizzled source
  {
    const int sr = lane >> 3, gq = lane & 7;
#pragma unroll
    for (int l = 0; l < 4; ++l) {
      const int row = l * 32 + w * 8 + sr;
      const size_t gb = ((size_t)b * T_ + tks[row]) * D_ + hd * DH_
                      + ((gq ^ swf(row)) << 3);
      const int dst = (l * 32 + w * 8) * 64 + lane * 8;
      gld_lds16(&qkb[gb], &Rs[dst]);
      gld_lds16(&vb[gb],  &Vs[dst]);
    }
  }
  __syncthreads();

  // dots (MFMA from Rs) + V transpose-read (b64) into regs
  f32x4 sacc[8];
#pragma unroll
  for (int j = 0; j < 8; ++j) sacc[j] = (f32x4){0.f, 0.f, 0.f, 0.f};
  __builtin_amdgcn_s_setprio(1);
#pragma unroll
  for (int kk = 0; kk < 2; ++kk) {
    const bf16x8 aq = *(const bf16x8*)&Rs[off64(w * 16 + cl, kk * 32 + g * 8)];
#pragma unroll
    for (int j = 0; j < 8; ++j) {
      const bf16x8 bk = *(const bf16x8*)&Rs[off64(j * 16 + cl, kk * 32 + g * 8)];
      sacc[j] = __builtin_amdgcn_mfma_f32_16x16x32_bf16(aq, bk, sacc[j], 0, 0, 0);
    }
  }
  __builtin_amdgcn_s_setprio(0);
  const int d0 = (tid & 15) * 4, tg = tid >> 4;
  unsigned int qw[8][2];
#pragma unroll
  for (int e = 0; e < 8; ++e) {
    const uint2 q = *(const uint2*)&Vs[off64(tg * 8 + e, d0)];
    qw[e][0] = q.x; qw[e][1] = q.y;
  }
  __syncthreads();

  // write V^T into Vs region; softmax (skip-max) -> unnormalized P into Rs
  {
    unsigned short col[4][8];
#pragma unroll
    for (int e = 0; e < 8; ++e) {
      col[0][e] = (unsigned short)(qw[e][0] & 0xffffu);
      col[1][e] = (unsigned short)(qw[e][0] >> 16);
      col[2][e] = (unsigned short)(qw[e][1] & 0xffffu);
      col[3][e] = (unsigned short)(qw[e][1] >> 16);
    }
#pragma unroll
    for (int dd = 0; dd < 4; ++dd)
      *(uint4*)&Vs[off128(d0 + dd, tg * 8)] = *(const uint4*)&col[dd][0];
  }

  float iv[8]; int tk[8];
#pragma unroll
  for (int j = 0; j < 8; ++j) {
    iv[j] = invs[j * 16 + cl] * 0.125f;
    tk[j] = tks[j * 16 + cl];
  }
  float pinv[4];
#pragma unroll
  for (int r = 0; r < 4; ++r) {
    const int row = w * 16 + g * 4 + r;
    const int tq = tks[row];
    float e8[8];
    float sum = 0.f;
#pragma unroll
    for (int j = 0; j < 8; ++j) {
      float e = __expf(sacc[j][r] * iv[j]);
      if (tq == tk[j]) e = 0.f;
      e8[j] = e;
      sum += e;
    }
    sum += __shfl_xor(sum, 1); sum += __shfl_xor(sum, 2);
    sum += __shfl_xor(sum, 4); sum += __shfl_xor(sum, 8);
    pinv[r] = 1.f / sum;
#pragma unroll
    for (int j = 0; j < 8; j += 2) {
      const unsigned int pk = cvt_pk_bf16(e8[j], e8[j + 1]);
      Rs[off128(row, j * 16 + cl)]       = (unsigned short)pk;
      Rs[off128(row, (j + 1) * 16 + cl)] = (unsigned short)(pk >> 16);
    }
    if (cl == 0)
      logits[((size_t)bh * T_ + tq) * NH_ + hr] = __logf(sum);
  }
  __syncthreads();

  // PV: A = P (Rs), B = V^T (Vs)
  f32x4 oacc[4];
#pragma unroll
  for (int jd = 0; jd < 4; ++jd) oacc[jd] = (f32x4){0.f, 0.f, 0.f, 0.f};
  __builtin_amdgcn_s_setprio(1);
#pragma unroll
  for (int ks = 0; ks < 4; ++ks) {
    const bf16x8 pa = *(const bf16x8*)&Rs[off128(w * 16 + cl, ks * 32 + g * 8)];
#pragma unroll
    for (int jd = 0; jd < 4; ++jd) {
      const bf16x8 vv = *(const bf16x8*)&Vs[off128(jd * 16 + cl, ks * 32 + g * 8)];
      oacc[jd] = __builtin_amdgcn_mfma_f32_16x16x32_bf16(pa, vv, oacc[jd], 0, 0, 0);
    }
  }
  __builtin_amdgcn_s_setprio(0);
  __syncthreads();

  // O (scaled by 1/sum) into Rs, then coalesced scatter to global
#pragma unroll
  for (int r = 0; r < 4; ++r) {
    const int row = w * 16 + g * 4 + r;
    const unsigned int q01 = cvt_pk_bf16(oacc[0][r] * pinv[r], oacc[1][r] * pinv[r]);
    const unsigned int q23 = cvt_pk_bf16(oacc[2][r] * pinv[r], oacc[3][r] * pinv[r]);
    Rs[off64(row,      cl)] = (unsigned short)q01;
    Rs[off64(row, 16 + cl)] = (unsigned short)(q01 >> 16);
    Rs[off64(row, 32 + cl)] = (unsigned short)q23;
    Rs[off64(row, 48 + cl)] = (unsigned short)(q23 >> 16);
  }
  __syncthreads();

#pragma unroll
  for (int l = 0; l < 2; ++l) {
    const int idx = tid + l * 256;
    const int row = idx >> 3, k0 = (idx & 7) * 8;
    *(uint4*)&orowsb[(((size_t)bh * T_ + tks[row]) * NH_ + hr) * DH_ + k0] =
        *(const uint4*)&Rs[off64(row, k0)];
  }
}

// ---------- combine hash rounds (contiguous per-token layout) ----------
__global__ __launch_bounds__(256) void combine_kernel(
    const unsigned short* __restrict__ orowsb, const float* __restrict__ logits,
    unsigned short* __restrict__ ocombb)
{
  const int gid = blockIdx.x * 4 + (threadIdx.x >> 6);
  const int lane = threadIdx.x & 63;
  const int bh = gid >> 12, t = gid & (T_ - 1);
  const int b = bh >> 3, hd = bh & 7;
  const float4 lg = *(const float4*)&logits[((size_t)bh * T_ + t) * NH_];
  const float m = fmaxf(fmaxf(lg.x, lg.y), fmaxf(lg.z, lg.w));
  const float w0 = __expf(lg.x - m), w1 = __expf(lg.y - m);
  const float w2 = __expf(lg.z - m), w3 = __expf(lg.w - m);
  const float inv = 1.f / (w0 + w1 + w2 + w3);
  const size_t rb = ((size_t)bh * T_ + t) * (NH_ * DH_) + lane;
  const float o = w0 * bf2f(orowsb[rb])
                + w1 * bf2f(orowsb[rb + DH_])
                + w2 * bf2f(orowsb[rb + 2 * DH_])
                + w3 * bf2f(orowsb[rb + 3 * DH_]);
  ocombb[((size_t)b * T_ + t) * D_ + hd * DH_ + lane] = f2bf(o * inv);
}

// ---------- LayerNorm (bf16 in, fp32 out) ----------
__global__ __launch_bounds__(256) void ln_kernel(
    const unsigned short* __restrict__ yb, const float* __restrict__ gamma,
    const float* __restrict__ beta, float* __restrict__ out)
{
  const int row = blockIdx.x * 4 + (threadIdx.x >> 6);
  const int lane = threadIdx.x & 63;
  const size_t base = (size_t)row * D_ + lane * 8;
  const uint4 u = *(const uint4*)&yb[base];
  const unsigned short* up = (const unsigned short*)&u;
  float x[8];
#pragma unroll
  for (int i = 0; i < 8; ++i) x[i] = bf2f(up[i]);
  float s = 0.f;
#pragma unroll
  for (int i = 0; i < 8; ++i) s += x[i];
#pragma unroll
  for (int m = 32; m >= 1; m >>= 1) s += __shfl_xor(s, m);
  const float mu = s * (1.f / D_);
  float vs = 0.f;
#pragma unroll
  for (int i = 0; i < 8; ++i) { const float d = x[i] - mu; vs += d * d; }
#pragma unroll
  for (int m = 32; m >= 1; m >>= 1) vs += __shfl_xor(vs, m);
  const float rstd = rsqrtf(vs * (1.f / D_) + 1e-6f);
  float gm[8], bt[8];
  *(float4*)&gm[0] = *(const float4*)&gamma[lane * 8];
  *(float4*)&gm[4] = *(const float4*)&gamma[lane * 8 + 4];
  *(float4*)&bt[0] = *(const float4*)&beta[lane * 8];
  *(float4*)&bt[4] = *(const float4*)&beta[lane * 8 + 4];
  float o[8];
#pragma unroll
  for (int i = 0; i < 8; ++i) o[i] = (x[i] - mu) * rstd * gm[i] + bt[i];
  *(float4*)&out[base]     = make_float4(o[0], o[1], o[2], o[3]);
  *(float4*)&out[base + 4] = make_float4(o[4], o[5], o[6], o[7]);
}

extern "C" void kernel_launch(void* const* d_in, const int* in_sizes, int n_in,
                              void* d_out, int out_size, void* d_ws, size_t ws_size,
                              hipStream_t stream) {
  (void)in_sizes; (void)n_in; (void)out_size; (void)ws_size;
  const float* src   = (const float*)d_in[0];
  const float* Wqk   = (const float*)d_in[1];
  const float* Wv    = (const float*)d_in[2];
  const float* Wout  = (const float*)d_in[3];
  const float* bout  = (const float*)d_in[4];
  const float* W1    = (const float*)d_in[5];
  const float* b1    = (const float*)d_in[6];
  const float* W2    = (const float*)d_in[7];
  const float* b2    = (const float*)d_in[8];
  const float* gamma = (const float*)d_in[9];
  const float* beta  = (const float*)d_in[10];
  const float* rot   = (const float*)d_in[11];
  float* out = (float*)d_out;

  // ---- workspace layout ----
  char* ws = (char*)d_ws;
  const size_t MB = 1024 * 1024;
  float*          qk      = (float*)(ws);                     // 32 MB; dead after hash
  unsigned short* src_b   = (unsigned short*)(ws + 32 * MB);  // 16 MB; live thru Wout resid
  unsigned short* v_b     = (unsigned short*)(ws + 48 * MB);  // 16 MB; -> x_b
  unsigned short* orows_b = (unsigned short*)(ws + 64 * MB);  // 64 MB; -> hidden_b
  unsigned short* qk_b    = (unsigned short*)(ws + 128 * MB); // 16 MB; -> ocomb_b
  char* p = ws + 144 * MB;
  float* logits  = (float*)p; p += (size_t)BH_ * T_ * NH_ * 4;
  int*   buckets = (int*)p;   p += (size_t)BH_ * NH_ * T_ * 4;
  int*   sticker = (int*)p;   p += (size_t)BH_ * NTICK_ * 4;
  int*   bstart  = (int*)p;   p += (size_t)BH_ * 256 * 4;
  float* invn    = (float*)p; p += (size_t)BH_ * T_ * 4;
  unsigned short* WqkvT = (unsigned short*)p; p += (size_t)1024 * 512 * 2;
  unsigned short* WoutT = (unsigned short*)p; p += (size_t)D_ * D_ * 2;
  unsigned short* W1T   = (unsigned short*)p; p += (size_t)FFN_ * D_ * 2;
  unsigned short* W2T   = (unsigned short*)p; p += (size_t)D_ * FFN_ * 2;

  unsigned short* ocomb_b  = qk_b;                 // after attn consumed qk_b
  unsigned short* x_b      = v_b;                  // after attn consumed v_b
  unsigned short* hidden_b = orows_b;              // after combine consumed orows
  unsigned short* ybuf_b   = (unsigned short*)ws;  // after hash consumed qk f32

  // 0: all conversions in one launch (weights + src convert)
  prep_all<<<2816 + M_ * D_ / 8 / 256, 256, 0, stream>>>(
      Wqk, Wv, Wout, W1, W2, src, WqkvT, WoutT, W1T, W2T, src_b);

  // 1: fused qk+v projection (K=512; qk cols emit fp32 + invn)
  gemm_bf16<128, 3, false, false, false>
      <<<dim3(1024 / 128, M_ / 128), 256, 0, stream>>>(
      src_b, WqkvT, nullptr, nullptr, qk, qk_b, v_b, invn,
      M_, 1024, D_, D_, D_, 0);
  // 2: LSH buckets (GEMM + fused argmax)
  hash_gemm_kernel<<<dim3(T_ / 128, BH_), 256, 0, stream>>>(qk, rot, buckets);
  // 3-4: counting sort
  hist_kernel<<<BH_, 256, 0, stream>>>(buckets, bstart);
  compact_kernel<<<dim3(256, BH_), 64, 0, stream>>>(buckets, bstart, sticker);
  // 5: chunked attention (MFMA)
  attn_kernel<<<dim3(CHUNKS_, BH_), 256, 0, stream>>>(
      qk_b, v_b, sticker, invn, orows_b, logits);
  // 6: combine hash rounds (writes into qk_b region)
  combine_kernel<<<BH_ * T_ / 4, 256, 0, stream>>>(orows_b, logits, ocomb_b);
  // 7: out projection + bias + residual(src_b)
  gemm_bf16<128, 1, true, false, true>
      <<<dim3(D_ / 128, M_ / 128), 256, 0, stream>>>(
      ocomb_b, WoutT, bout, src_b, nullptr, x_b, nullptr, nullptr,
      M_, D_, D_, D_, D_, D_);
  // 8: FFN1 (relu)
  gemm_bf16<128, 1, true, true, false>
      <<<dim3(FFN_ / 128, M_ / 128), 256, 0, stream>>>(
      x_b, W1T, b1, nullptr, nullptr, hidden_b, nullptr, nullptr,
      M_, FFN_, D_, D_, D_, 0);
  // 9: FFN2 + bias + residual(x_b) -> bf16 y
  gemm_bf16<128, 1, true, false, true>
      <<<dim3(D_ / 128, M_ / 128), 256, 0, stream>>>(
      hidden_b, W2T, b2, x_b, nullptr, ybuf_b, nullptr, nullptr,
      M_, D_, FFN_, FFN_, FFN_, D_);
  // 10: LayerNorm
  ln_kernel<<<M_ / 4, 256, 0, stream>>>(ybuf_b, gamma, beta, out);
}

// Round 12
// 325.572 us; speedup vs baseline: 1.1716x; 1.0216x over previous
//
#include <hip/hip_runtime.h>

#define B_ 4
#define T_ 4096
#define D_ 512
#define H_ 8
#define DH_ 64
#define NH_ 4
#define NB_ 64            // n_buckets = T/BUCKET
#define BH_ (B_*H_)       // 32
#define CHUNKS_ (NH_*NB_) // 256
#define NTICK_ (NH_*T_)   // 16384
#define M_ (B_*T_)        // 16384
#define FFN_ 2048

typedef __attribute__((ext_vector_type(8))) short bf16x8;
typedef __attribute__((ext_vector_type(4))) float f32x4;

// ---------- bf16 helpers ----------
__device__ __forceinline__ unsigned short f2bf(float x) {
  unsigned int u = __float_as_uint(x);
  return (unsigned short)((u + 0x7FFFu + ((u >> 16) & 1u)) >> 16);
}
__device__ __forceinline__ float bf2f(unsigned short s) {
  return __uint_as_float(((unsigned int)s) << 16);
}
__device__ __forceinline__ unsigned int cvt_pk_bf16(float lo, float hi) {
  unsigned int r;
  asm("v_cvt_pk_bf16_f32 %0, %1, %2" : "=v"(r) : "v"(lo), "v"(hi));
  return r;
}

// ---------- async global->LDS, 16B per lane ----------
__device__ __forceinline__ void gld_lds16(const void* g, void* l) {
  __builtin_amdgcn_global_load_lds(
      (const __attribute__((address_space(1))) unsigned int*)g,
      (__attribute__((address_space(3))) unsigned int*)l, 16, 0, 0);
}

// swizzled LDS offsets (shorts): XOR 16B-granule with (row ^ row>>3)&7
__device__ __forceinline__ int swf(int row) { return (row ^ (row >> 3)) & 7; }
__device__ __forceinline__ int off64(int row, int k) {
  return row * 64 + (((k >> 3) ^ swf(row)) << 3) + (k & 7);
}
__device__ __forceinline__ int off128(int row, int k) {
  return row * 128 + (((k >> 3) ^ swf(row)) << 3) + (k & 7);
}

// ---------- 256x256 8-wave phase-interleaved GEMM (T2+T3+T4+T5) ----------
// C = relu(A @ BT^T + bias), bf16 out. 512 threads. K % 64 == 0, K/64 >= 2.
// Per K-tile: 4 phases, each {stage half-tile of t+1 || 12 swizzled ds_read
// || 16 MFMA (one output quadrant)}; vmcnt(2)+barrier once per tile (counted,
// never 0 mid-loop); end-of-tile barrier. LDS: 2 x 64KB dbuf (A|B), reused
// as 128KB C-tile for coalesced writeback.
__global__ __launch_bounds__(512) void gemm256_relu(
    const unsigned short* __restrict__ A, const unsigned short* __restrict__ BT,
    const float* __restrict__ bias, unsigned short* __restrict__ Cb,
    int M, int N, int K)
{
  constexpr int ABSZ = 32768;   // shorts per buffer: A 256x64 + B 256x64
  __shared__ __align__(16) unsigned short smem[2 * ABSZ];
  const int tid = threadIdx.x;              // 0..511
  const int lane = tid & 63, w = tid >> 6;  // 8 waves
  const int wm = (w >> 2) * 128, wn = (w & 3) * 64;
  const int g = lane >> 4, cl = lane & 15;

  // XCD-aware block swizzle (T1)
  const int gx = gridDim.x;
  const int id = blockIdx.x + blockIdx.y * gx;
  const int cpx = (gx * gridDim.y) >> 3;
  const int swz = (id & 7) * cpx + (id >> 3);
  const int m0 = (swz / gx) * 256, n0 = (swz % gx) * 256;

  f32x4 acc[8][4];
#pragma unroll
  for (int i = 0; i < 8; ++i)
#pragma unroll
    for (int j = 0; j < 4; ++j) acc[i][j] = (f32x4){0.f, 0.f, 0.f, 0.f};

  // stage one half-tile (128 rows x 64 k): 2 gld16/thread; linear LDS dest,
  // pre-swizzled global k-granule (rule #21: same involution as off64 read).
#define STG256(BUF, KB, P)                                                    \
  do {                                                                        \
    const bool isA_ = (P) < 2;                                                \
    const int half_ = (P) & 1;                                                \
    const unsigned short* Mp_ = isA_ ? A : BT;                                \
    const int gb_ = isA_ ? m0 : n0;                                           \
    const int ro_ = isA_ ? 0 : 16384;                                         \
    _Pragma("unroll")                                                         \
    for (int c2 = 0; c2 < 2; ++c2) {                                          \
      const int r_ = half_ * 128 + w * 16 + c2 * 8 + (lane >> 3);             \
      const int kg_ = (lane & 7) ^ swf(r_);                                   \
      gld_lds16(&Mp_[(size_t)(gb_ + r_) * K + (KB) + kg_ * 8],                \
                &smem[(BUF) * ABSZ + ro_ +                                    \
                      (half_ * 128 + w * 16 + c2 * 8) * 64 + lane * 8]);      \
    }                                                                         \
  } while (0)

  // prologue: all 4 half-tiles of tile 0 (8 gld/thread)
#pragma unroll
  for (int p = 0; p < 4; ++p) STG256(0, 0, p);

  const int KT = K >> 6;
  for (int kt = 0; kt < KT; ++kt) {
    const int cur = kt & 1;
    const unsigned short* As = smem + cur * ABSZ;
    const unsigned short* Bs = As + 16384;
#pragma unroll
    for (int p = 0; p < 4; ++p) {
      if (kt + 1 < KT) STG256(cur ^ 1, (kt + 1) * 64, p);
      if (p == 0) {
        if (kt + 1 < KT) asm volatile("s_waitcnt vmcnt(2)" ::: "memory");
        else             asm volatile("s_waitcnt vmcnt(0)" ::: "memory");
        __builtin_amdgcn_s_barrier();   // tile kt visible to all waves
      }
      const int rq = wm + (p >> 1) * 64, cq = wn + (p & 1) * 32;
      bf16x8 af[4][2], bfr[2][2];
#pragma unroll
      for (int i = 0; i < 4; ++i)
#pragma unroll
        for (int kk = 0; kk < 2; ++kk)
          af[i][kk] = *(const bf16x8*)&As[off64(rq + i * 16 + cl, kk * 32 + g * 8)];
#pragma unroll
      for (int j = 0; j < 2; ++j)
#pragma unroll
        for (int kk = 0; kk < 2; ++kk)
          bfr[j][kk] = *(const bf16x8*)&Bs[off64(cq + j * 16 + cl, kk * 32 + g * 8)];
      __builtin_amdgcn_s_setprio(1);
#pragma unroll
      for (int kk = 0; kk < 2; ++kk)
#pragma unroll
        for (int i = 0; i < 4; ++i)
#pragma unroll
          for (int j = 0; j < 2; ++j)
            acc[(p >> 1) * 4 + i][(p & 1) * 2 + j] =
                __builtin_amdgcn_mfma_f32_16x16x32_bf16(
                    af[i][kk], bfr[j][kk], acc[(p >> 1) * 4 + i][(p & 1) * 2 + j], 0, 0, 0);
      __builtin_amdgcn_s_setprio(0);
      if (p == 3) __builtin_amdgcn_s_barrier();  // tile kt reads done
    }
  }
#undef STG256

  // epilogue: bias+relu -> swizzled 256x256 C-tile in LDS -> coalesced out
  float bv[4];
#pragma unroll
  for (int j4 = 0; j4 < 4; ++j4) bv[j4] = bias[n0 + wn + j4 * 16 + cl];
#pragma unroll
  for (int i = 0; i < 8; ++i) {
#pragma unroll
    for (int r = 0; r < 4; ++r) {
      const int lrow = wm + i * 16 + g * 4 + r;
      const int sw = (lrow & 7) << 3;
#pragma unroll
      for (int j4 = 0; j4 < 4; j4 += 2) {
        const float v0 = fmaxf(acc[i][j4][r] + bv[j4], 0.f);
        const float v1 = fmaxf(acc[i][j4 + 1][r] + bv[j4 + 1], 0.f);
        const unsigned int pk = cvt_pk_bf16(v0, v1);
        smem[lrow * 256 + ((wn + j4 * 16 + cl) ^ sw)]       = (unsigned short)pk;
        smem[lrow * 256 + ((wn + (j4 + 1) * 16 + cl) ^ sw)] = (unsigned short)(pk >> 16);
      }
    }
  }
  __syncthreads();
#pragma unroll
  for (int l = 0; l < 16; ++l) {
    const int idx = tid + l * 512;
    const int row = idx >> 5, c8 = (idx & 31) * 8;
    const uint4 u = *(const uint4*)&smem[row * 256 + (c8 ^ ((row & 7) << 3))];
    *(uint4*)&Cb[(size_t)(m0 + row) * N + n0 + c8] = u;
  }
}

// ---------- bf16 MFMA GEMM (counted-vmcnt double-buffer) ----------
// MODE 1: bf16 out (stride N).
// MODE 3: fused qk+v — N logical 1024, all K=512:
//   n0<512: qk cols -> f32 Cf (stride 512) + bf16 Cb + fused invn;
//   n0>=512: v cols -> bf16 Cb2 at col n0-512.
template<int BM, int MODE, bool HAS_BIAS, bool RELU, bool HAS_RESID>
__global__ __launch_bounds__(256) void gemm_bf16(
    const unsigned short* __restrict__ A, const unsigned short* __restrict__ BT,
    const float* __restrict__ bias, const unsigned short* __restrict__ resid,
    float* __restrict__ Cf, unsigned short* __restrict__ Cb,
    unsigned short* __restrict__ Cb2, float* __restrict__ invn,
    int M, int N, int K, int lda, int ldbt, int ldr)
{
  constexpr int MI = BM / 32;
  constexpr int ABSZ = (BM + 128) * 64;     // shorts per K-tile buffer (As|Bs)
  __shared__ __align__(16) unsigned short smem[2 * ABSZ];
  const int tid = threadIdx.x;
  const int lane = tid & 63;
  const int w = tid >> 6;
  const int wm = (w >> 1) * (BM / 2), wn = (w & 1) * 64;
  const int g = lane >> 4, cl = lane & 15;

  // XCD-aware block swizzle (T1)
  const int gx = gridDim.x;
  const int id = blockIdx.x + blockIdx.y * gx;
  const int cpx = (gx * gridDim.y) >> 3;
  const int swz = (id & 7) * cpx + (id >> 3);
  const int m0 = (swz / gx) * BM, n0 = (swz % gx) * 128;

  const bool isv = (MODE == 3) && (n0 >= 512);

  f32x4 acc[MI][4];
#pragma unroll
  for (int i = 0; i < MI; ++i)
#pragma unroll
    for (int j = 0; j < 4; ++j) acc[i][j] = (f32x4){0.f, 0.f, 0.f, 0.f};

  const int srow = tid >> 3;
  const int skc  = (tid & 7) * 8;

#define STAGE(BUF, K0)                                                        \
  do {                                                                        \
    unsigned short* As_ = smem + (BUF) * ABSZ;                                \
    unsigned short* Bs_ = As_ + BM * 64;                                      \
    _Pragma("unroll")                                                         \
    for (int ci = 0; ci < BM / 32; ++ci)                                      \
      gld_lds16(&A[(size_t)(m0 + ci * 32 + srow) * lda + (K0) + skc],         \
                &As_[ci * 2048 + tid * 8]);                                   \
    _Pragma("unroll")                                                         \
    for (int ci = 0; ci < 4; ++ci)                                            \
      gld_lds16(&BT[(size_t)(n0 + ci * 32 + srow) * ldbt + (K0) + skc],       \
                &Bs_[ci * 2048 + tid * 8]);                                   \
  } while (0)

  STAGE(0, 0);
  const int KT = K >> 6;
  for (int kt = 0; kt < KT; ++kt) {
    if (kt + 1 < KT) {
      STAGE((kt + 1) & 1, (kt + 1) * 64);
      asm volatile("s_waitcnt vmcnt(8)" ::: "memory");   // tile kt landed
    } else {
      asm volatile("s_waitcnt vmcnt(0)" ::: "memory");
    }
    __builtin_amdgcn_s_barrier();
    const unsigned short* As = smem + (kt & 1) * ABSZ;
    const unsigned short* Bs = As + BM * 64;
#pragma unroll
    for (int kk = 0; kk < 64; kk += 32) {
      bf16x8 af[MI], bfr[4];
#pragma unroll
      for (int i = 0; i < MI; ++i)
        af[i] = *(const bf16x8*)&As[(wm + i * 16 + cl) * 64 + kk + g * 8];
#pragma unroll
      for (int j = 0; j < 4; ++j)
        bfr[j] = *(const bf16x8*)&Bs[(wn + j * 16 + cl) * 64 + kk + g * 8];
#pragma unroll
      for (int i = 0; i < MI; ++i)
#pragma unroll
        for (int j = 0; j < 4; ++j)
          acc[i][j] = __builtin_amdgcn_mfma_f32_16x16x32_bf16(af[i], bfr[j], acc[i][j], 0, 0, 0);
    }
    asm volatile("" ::: "memory");
    __builtin_amdgcn_s_barrier();
  }
#undef STAGE

  // ---- epilogue: regs -> LDS C-tile (swizzled, in buf0) -> coalesced out
  float bv[4];
  if constexpr (HAS_BIAS) {
#pragma unroll
    for (int j = 0; j < 4; ++j) bv[j] = bias[n0 + wn + j * 16 + cl];
  }
#pragma unroll
  for (int i = 0; i < MI; ++i) {
#pragma unroll
    for (int r = 0; r < 4; ++r) {
      const int lrow = wm + i * 16 + g * 4 + r;
      float v4[4];
      float ss = 0.f;
#pragma unroll
      for (int j = 0; j < 4; ++j) {
        float val = acc[i][j][r];
        if constexpr (HAS_BIAS) val += bv[j];
        if constexpr (RELU) val = fmaxf(val, 0.f);
        v4[j] = val;
        if constexpr (MODE == 3) {
          if (!isv) {
            ss += val * val;
            Cf[(size_t)(m0 + lrow) * 512 + n0 + wn + j * 16 + cl] = val;
          }
        }
      }
      const unsigned int p01 = cvt_pk_bf16(v4[0], v4[1]);
      const unsigned int p23 = cvt_pk_bf16(v4[2], v4[3]);
      const int sw = (lrow & 7) << 3;
      smem[lrow * 128 + ((wn +  0 + cl) ^ sw)] = (unsigned short)p01;
      smem[lrow * 128 + ((wn + 16 + cl) ^ sw)] = (unsigned short)(p01 >> 16);
      smem[lrow * 128 + ((wn + 32 + cl) ^ sw)] = (unsigned short)p23;
      smem[lrow * 128 + ((wn + 48 + cl) ^ sw)] = (unsigned short)(p23 >> 16);
      if constexpr (MODE == 3) {
        if (!isv) {
          ss += __shfl_xor(ss, 1); ss += __shfl_xor(ss, 2);
          ss += __shfl_xor(ss, 4); ss += __shfl_xor(ss, 8);
          if (cl == 0) {
            const int m = m0 + lrow;
            const int bb = m >> 12, t = m & (T_ - 1);
            const int hh = ((n0 + wn) >> 6) & 7;
            invn[((size_t)(bb * 8 + hh)) * T_ + t] = 1.0f / (sqrtf(ss) + 1e-6f);
          }
        }
      }
    }
  }
  __syncthreads();
#pragma unroll
  for (int l = 0; l < BM / 16; ++l) {
    const int idx = tid + l * 256;
    const int row = idx >> 4, c8 = (idx & 15) * 8;
    uint4 u = *(const uint4*)&smem[row * 128 + (c8 ^ ((row & 7) << 3))];
    if constexpr (HAS_RESID) {
      const uint4 rv = *(const uint4*)&resid[(size_t)(m0 + row) * ldr + n0 + c8];
      const unsigned short* sp = (const unsigned short*)&u;
      const unsigned short* rp = (const unsigned short*)&rv;
      float f[8];
#pragma unroll
      for (int e = 0; e < 8; ++e) f[e] = bf2f(sp[e]) + bf2f(rp[e]);
      u.x = cvt_pk_bf16(f[0], f[1]); u.y = cvt_pk_bf16(f[2], f[3]);
      u.z = cvt_pk_bf16(f[4], f[5]); u.w = cvt_pk_bf16(f[6], f[7]);
    }
    if constexpr (MODE == 3) {
      if (isv)
        *(uint4*)&Cb2[(size_t)(m0 + row) * 512 + (n0 - 512) + c8] = u;
      else
        *(uint4*)&Cb[(size_t)(m0 + row) * 512 + n0 + c8] = u;
    } else {
      *(uint4*)&Cb[(size_t)(m0 + row) * N + n0 + c8] = u;
    }
  }
}

// ---------- fused prep: transpose 5 weights + convert src rows ----------
__global__ __launch_bounds__(256) void prep_all(
    const float* __restrict__ Wqk, const float* __restrict__ Wv,
    const float* __restrict__ Wout, const float* __restrict__ W1,
    const float* __restrict__ W2, const float* __restrict__ src,
    unsigned short* __restrict__ WqkvT, unsigned short* __restrict__ WoutT,
    unsigned short* __restrict__ W1T, unsigned short* __restrict__ W2T,
    unsigned short* __restrict__ src_b)
{
  __shared__ float tile[32][33];
  int bid = blockIdx.x;
  if (bid >= 2816) {
    const int i = (bid - 2816) * 256 + threadIdx.x;   // < M*D/8
    const int m = i >> 6, d0 = (i & 63) * 8;
    float x[8];
    *(float4*)&x[0] = *(const float4*)&src[(size_t)m * D_ + d0];
    *(float4*)&x[4] = *(const float4*)&src[(size_t)m * D_ + d0 + 4];
    unsigned short hi[8];
#pragma unroll
    for (int e = 0; e < 8; ++e) hi[e] = f2bf(x[e]);
    *(uint4*)&src_b[(size_t)m * D_ + d0] = *(const uint4*)&hi[0];
    return;
  }
  const float* W; unsigned short* WT; int K, N, bx, by;
  if (bid < 256)        { W = Wqk;  WT = WqkvT; K = 512;  N = 512;
                          bx = bid & 15; by = bid >> 4; }
  else if (bid < 512)   { bid -= 256;  W = Wv; WT = WqkvT + (size_t)512 * 512;
                          K = 512; N = 512;
                          bx = bid & 15; by = bid >> 4; }
  else if (bid < 768)   { bid -= 512;  W = Wout; WT = WoutT; K = 512;  N = 512;
                          bx = bid & 15; by = bid >> 4; }
  else if (bid < 1792)  { bid -= 768;  W = W1;   WT = W1T;   K = 512;  N = 2048;
                          bx = bid & 63; by = bid >> 6; }
  else                  { bid -= 1792; W = W2;   WT = W2T;   K = 2048; N = 512;
                          bx = bid & 15; by = bid >> 4; }
  const int k0 = by * 32, n0 = bx * 32;
  const int tx = threadIdx.x & 31, ty = threadIdx.x >> 5;
#pragma unroll
  for (int r = 0; r < 32; r += 8)
    tile[ty + r][tx] = W[(size_t)(k0 + ty + r) * N + n0 + tx];
  __syncthreads();
#pragma unroll
  for (int r = 0; r < 32; r += 8)
    WT[(size_t)(n0 + ty + r) * K + k0 + tx] = f2bf(tile[tx][ty + r]);
}

// ---------- LSH hashing as GEMM + fused argmax (reads fp32 qk) ----------
__global__ __launch_bounds__(256) void hash_gemm_kernel(
    const float* __restrict__ qk, const float* __restrict__ rot,
    int* __restrict__ buckets)
{
  __shared__ __align__(16) float As[64][136];   // [k][m]
  __shared__ __align__(16) float Bs[64][132];   // [k][n]
  const int tid = threadIdx.x;
  const int tx = tid & 15, ty = tid >> 4;
  const int t0 = blockIdx.x * 128, bh = blockIdx.y;
  const int b = bh >> 3, hd = bh & 7;

#pragma unroll
  for (int l = 0; l < 8; ++l) {
    const int idx = tid + l * 256;
    const int row = idx >> 4;
    const int kq = (idx & 15) << 2;
    const float4 a = *(const float4*)&qk[((size_t)b * T_ + t0 + row) * D_ + hd * DH_ + kq];
    As[kq + 0][row] = a.x; As[kq + 1][row] = a.y;
    As[kq + 2][row] = a.z; As[kq + 3][row] = a.w;
  }
#pragma unroll
  for (int l = 0; l < 8; ++l) {
    const int idx = tid + l * 256;
    const int kr = idx >> 5;
    const int c4 = (idx & 31) << 2;
    *(float4*)&Bs[kr][c4] = *(const float4*)&rot[kr * 128 + c4];
  }
  __syncthreads();

  float acc[8][8];
#pragma unroll
  for (int i = 0; i < 8; ++i)
#pragma unroll
    for (int j = 0; j < 8; ++j) acc[i][j] = 0.f;

#pragma unroll 4
  for (int kk = 0; kk < 64; ++kk) {
    float a[8], bq[8];
    *(float4*)&a[0]  = *(const float4*)&As[kk][ty * 8];
    *(float4*)&a[4]  = *(const float4*)&As[kk][ty * 8 + 4];
    *(float4*)&bq[0] = *(const float4*)&Bs[kk][tx * 8];
    *(float4*)&bq[4] = *(const float4*)&Bs[kk][tx * 8 + 4];
#pragma unroll
    for (int i = 0; i < 8; ++i)
#pragma unroll
      for (int j = 0; j < 8; ++j)
        acc[i][j] = fmaf(a[i], bq[j], acc[i][j]);
  }
  __syncthreads();

  float* pval = &As[0][0];
  int*   pidx = (int*)&Bs[0][0];
  const int i0 = (tx & 3) * 8;
#pragma unroll
  for (int r = 0; r < 8; ++r) {
    float v = -3.0e38f; int idx = 127;
#pragma unroll
    for (int j = 0; j < 8; ++j) {
      const float p = acc[r][j];
      const int li = i0 + j;
      if (p > v || (p == v && li < idx)) { v = p; idx = li; }
      const float n = -p;
      const int ni = 32 + li;
      if (n > v || (n == v && ni < idx)) { v = n; idx = ni; }
    }
    pval[(ty * 8 + r) * 16 + tx] = v;
    pidx[(ty * 8 + r) * 16 + tx] = idx;
  }
  __syncthreads();

#pragma unroll
  for (int l = 0; l < 2; ++l) {
    const int id = tid + l * 256;
    const int tok = id >> 2, hh = id & 3;
    float v = pval[tok * 16 + hh * 4];
    int idx = pidx[tok * 16 + hh * 4];
#pragma unroll
    for (int e = 1; e < 4; ++e) {
      const float ov = pval[tok * 16 + hh * 4 + e];
      const int oi = pidx[tok * 16 + hh * 4 + e];
      if (ov > v || (ov == v && oi < idx)) { v = ov; idx = oi; }
    }
    buckets[((size_t)bh * NH_ + hh) * T_ + t0 + tok] = idx + hh * NB_;
  }
}

// ---------- per-bh bucket histogram + exclusive scan ----------
__global__ __launch_bounds__(256) void hist_kernel(
    const int* __restrict__ buckets, int* __restrict__ bstart)
{
  __shared__ int bins[256];
  const int bh = blockIdx.x;
  bins[threadIdx.x] = 0;
  __syncthreads();
  for (int e = threadIdx.x; e < NTICK_; e += 256)
    atomicAdd(&bins[buckets[(size_t)bh * NTICK_ + e]], 1);
  __syncthreads();
  if (threadIdx.x == 0) {
    int run = 0;
    for (int i = 0; i < 256; ++i) { const int c = bins[i]; bins[i] = run; run += c; }
  }
  __syncthreads();
  bstart[bh * 256 + threadIdx.x] = bins[threadIdx.x];
}

// ---------- stable compaction ----------
__global__ __launch_bounds__(64) void compact_kernel(
    const int* __restrict__ buckets, const int* __restrict__ bstart,
    int* __restrict__ sticker)
{
  const int bucket = blockIdx.x, bh = blockIdx.y;
  const int h = bucket >> 6;
  const int lane = threadIdx.x;
  int base = bstart[bh * 256 + bucket];
  const int* bk = buckets + (size_t)bh * NTICK_ + (size_t)h * T_;
  for (int it = 0; it < 64; ++it) {
    const int t = it * 64 + lane;
    const bool m = (bk[t] == bucket);
    const unsigned long long bal = __ballot(m);
    if (m) {
      const int pos = base + __popcll(bal & ((1ull << lane) - 1ull));
      sticker[(size_t)bh * NTICK_ + pos] = h * T_ + t;
    }
    base += __popcll(bal);
  }
}

// ---------- chunked LSH attention — MFMA, async staging ----------
__global__ __launch_bounds__(256) void attn_kernel(
    const unsigned short* __restrict__ qkb, const unsigned short* __restrict__ vb,
    const int* __restrict__ sticker, const float* __restrict__ invn,
    unsigned short* __restrict__ orowsb, float* __restrict__ logits)
{
  __shared__ __align__(16) unsigned short Rs[128 * 64];
  __shared__ __align__(16) unsigned short Vs[128 * 64];
  __shared__ int tks[128];
  __shared__ float invs[128];

  const int cx = blockIdx.x;
  const int c = (cx & 7) * 32 + (cx >> 3);   // XCD-aware chunk swizzle
  const int bh = blockIdx.y;
  const int b = bh >> 3, hd = bh & 7;
  const int tid = threadIdx.x;
  const int hr = c >> 6;
  const int w = tid >> 6, lane = tid & 63, g = lane >> 4, cl = lane & 15;

  if (tid < 128) {
    const int sc = (tid < 64) ? c : ((c + CHUNKS_ - 1) & (CHUNKS_ - 1));
    const int tick = sticker[(size_t)bh * NTICK_ + sc * 64 + (tid & 63)];
    const int t = tick & (T_ - 1);
    tks[tid] = t;
    invs[tid] = invn[bh * T_ + t];
  }
  __syncthreads();

  // stage qk + v rows via global_load_lds: linear LDS dest, pre-swizzled source
  {
    const int sr = lane >> 3, gq = lane & 7;
#pragma unroll
    for (int l = 0; l < 4; ++l) {
      const int row = l * 32 + w * 8 + sr;
      const size_t gb = ((size_t)b * T_ + tks[row]) * D_ + hd * DH_
                      + ((gq ^ swf(row)) << 3);
      const int dst = (l * 32 + w * 8) * 64 + lane * 8;
      gld_lds16(&qkb[gb], &Rs[dst]);
      gld_lds16(&vb[gb],  &Vs[dst]);
    }
  }
  __syncthreads();

  // dots (MFMA from Rs) + V transpose-read (b64) into regs
  f32x4 sacc[8];
#pragma unroll
  for (int j = 0; j < 8; ++j) sacc[j] = (f32x4){0.f, 0.f, 0.f, 0.f};
  __builtin_amdgcn_s_setprio(1);
#pragma unroll
  for (int kk = 0; kk < 2; ++kk) {
    const bf16x8 aq = *(const bf16x8*)&Rs[off64(w * 16 + cl, kk * 32 + g * 8)];
#pragma unroll
    for (int j = 0; j < 8; ++j) {
      const bf16x8 bk = *(const bf16x8*)&Rs[off64(j * 16 + cl, kk * 32 + g * 8)];
      sacc[j] = __builtin_amdgcn_mfma_f32_16x16x32_bf16(aq, bk, sacc[j], 0, 0, 0);
    }
  }
  __builtin_amdgcn_s_setprio(0);
  const int d0 = (tid & 15) * 4, tg = tid >> 4;
  unsigned int qw[8][2];
#pragma unroll
  for (int e = 0; e < 8; ++e) {
    const uint2 q = *(const uint2*)&Vs[off64(tg * 8 + e, d0)];
    qw[e][0] = q.x; qw[e][1] = q.y;
  }
  __syncthreads();

  // write V^T into Vs region; softmax (skip-max) -> unnormalized P into Rs
  {
    unsigned short col[4][8];
#pragma unroll
    for (int e = 0; e < 8; ++e) {
      col[0][e] = (unsigned short)(qw[e][0] & 0xffffu);
      col[1][e] = (unsigned short)(qw[e][0] >> 16);
      col[2][e] = (unsigned short)(qw[e][1] & 0xffffu);
      col[3][e] = (unsigned short)(qw[e][1] >> 16);
    }
#pragma unroll
    for (int dd = 0; dd < 4; ++dd)
      *(uint4*)&Vs[off128(d0 + dd, tg * 8)] = *(const uint4*)&col[dd][0];
  }

  float iv[8]; int tk[8];
#pragma unroll
  for (int j = 0; j < 8; ++j) {
    iv[j] = invs[j * 16 + cl] * 0.125f;
    tk[j] = tks[j * 16 + cl];
  }
  float pinv[4];
#pragma unroll
  for (int r = 0; r < 4; ++r) {
    const int row = w * 16 + g * 4 + r;
    const int tq = tks[row];
    float e8[8];
    float sum = 0.f;
#pragma unroll
    for (int j = 0; j < 8; ++j) {
      float e = __expf(sacc[j][r] * iv[j]);
      if (tq == tk[j]) e = 0.f;
      e8[j] = e;
      sum += e;
    }
    sum += __shfl_xor(sum, 1); sum += __shfl_xor(sum, 2);
    sum += __shfl_xor(sum, 4); sum += __shfl_xor(sum, 8);
    pinv[r] = 1.f / sum;
#pragma unroll
    for (int j = 0; j < 8; j += 2) {
      const unsigned int pk = cvt_pk_bf16(e8[j], e8[j + 1]);
      Rs[off128(row, j * 16 + cl)]       = (unsigned short)pk;
      Rs[off128(row, (j + 1) * 16 + cl)] = (unsigned short)(pk >> 16);
    }
    if (cl == 0)
      logits[((size_t)bh * T_ + tq) * NH_ + hr] = __logf(sum);
  }
  __syncthreads();

  // PV: A = P (Rs), B = V^T (Vs)
  f32x4 oacc[4];
#pragma unroll
  for (int jd = 0; jd < 4; ++jd) oacc[jd] = (f32x4){0.f, 0.f, 0.f, 0.f};
  __builtin_amdgcn_s_setprio(1);
#pragma unroll
  for (int ks = 0; ks < 4; ++ks) {
    const bf16x8 pa = *(const bf16x8*)&Rs[off128(w * 16 + cl, ks * 32 + g * 8)];
#pragma unroll
    for (int jd = 0; jd < 4; ++jd) {
      const bf16x8 vv = *(const bf16x8*)&Vs[off128(jd * 16 + cl, ks * 32 + g * 8)];
      oacc[jd] = __builtin_amdgcn_mfma_f32_16x16x32_bf16(pa, vv, oacc[jd], 0, 0, 0);
    }
  }
  __builtin_amdgcn_s_setprio(0);
  __syncthreads();

  // O (scaled by 1/sum) into Rs, then coalesced scatter to global
#pragma unroll
  for (int r = 0; r < 4; ++r) {
    const int row = w * 16 + g * 4 + r;
    const unsigned int q01 = cvt_pk_bf16(oacc[0][r] * pinv[r], oacc[1][r] * pinv[r]);
    const unsigned int q23 = cvt_pk_bf16(oacc[2][r] * pinv[r], oacc[3][r] * pinv[r]);
    Rs[off64(row,      cl)] = (unsigned short)q01;
    Rs[off64(row, 16 + cl)] = (unsigned short)(q01 >> 16);
    Rs[off64(row, 32 + cl)] = (unsigned short)q23;
    Rs[off64(row, 48 + cl)] = (unsigned short)(q23 >> 16);
  }
  __syncthreads();

#pragma unroll
  for (int l = 0; l < 2; ++l) {
    const int idx = tid + l * 256;
    const int row = idx >> 3, k0 = (idx & 7) * 8;
    *(uint4*)&orowsb[(((size_t)bh * T_ + tks[row]) * NH_ + hr) * DH_ + k0] =
        *(const uint4*)&Rs[off64(row, k0)];
  }
}

// ---------- combine hash rounds (contiguous per-token layout) ----------
__global__ __launch_bounds__(256) void combine_kernel(
    const unsigned short* __restrict__ orowsb, const float* __restrict__ logits,
    unsigned short* __restrict__ ocombb)
{
  const int gid = blockIdx.x * 4 + (threadIdx.x >> 6);
  const int lane = threadIdx.x & 63;
  const int bh = gid >> 12, t = gid & (T_ - 1);
  const int b = bh >> 3, hd = bh & 7;
  const float4 lg = *(const float4*)&logits[((size_t)bh * T_ + t) * NH_];
  const float m = fmaxf(fmaxf(lg.x, lg.y), fmaxf(lg.z, lg.w));
  const float w0 = __expf(lg.x - m), w1 = __expf(lg.y - m);
  const float w2 = __expf(lg.z - m), w3 = __expf(lg.w - m);
  const float inv = 1.f / (w0 + w1 + w2 + w3);
  const size_t rb = ((size_t)bh * T_ + t) * (NH_ * DH_) + lane;
  const float o = w0 * bf2f(orowsb[rb])
                + w1 * bf2f(orowsb[rb + DH_])
                + w2 * bf2f(orowsb[rb + 2 * DH_])
                + w3 * bf2f(orowsb[rb + 3 * DH_]);
  ocombb[((size_t)b * T_ + t) * D_ + hd * DH_ + lane] = f2bf(o * inv);
}

// ---------- LayerNorm (bf16 in, fp32 out) ----------
__global__ __launch_bounds__(256) void ln_kernel(
    const unsigned short* __restrict__ yb, const float* __restrict__ gamma,
    const float* __restrict__ beta, float* __restrict__ out)
{
  const int row = blockIdx.x * 4 + (threadIdx.x >> 6);
  const int lane = threadIdx.x & 63;
  const size_t base = (size_t)row * D_ + lane * 8;
  const uint4 u = *(const uint4*)&yb[base];
  const unsigned short* up = (const unsigned short*)&u;
  float x[8];
#pragma unroll
  for (int i = 0; i < 8; ++i) x[i] = bf2f(up[i]);
  float s = 0.f;
#pragma unroll
  for (int i = 0; i < 8; ++i) s += x[i];
#pragma unroll
  for (int m = 32; m >= 1; m >>= 1) s += __shfl_xor(s, m);
  const float mu = s * (1.f / D_);
  float vs = 0.f;
#pragma unroll
  for (int i = 0; i < 8; ++i) { const float d = x[i] - mu; vs += d * d; }
#pragma unroll
  for (int m = 32; m >= 1; m >>= 1) vs += __shfl_xor(vs, m);
  const float rstd = rsqrtf(vs * (1.f / D_) + 1e-6f);
  float gm[8], bt[8];
  *(float4*)&gm[0] = *(const float4*)&gamma[lane * 8];
  *(float4*)&gm[4] = *(const float4*)&gamma[lane * 8 + 4];
  *(float4*)&bt[0] = *(const float4*)&beta[lane * 8];
  *(float4*)&bt[4] = *(const float4*)&beta[lane * 8 + 4];
  float o[8];
#pragma unroll
  for (int i = 0; i < 8; ++i) o[i] = (x[i] - mu) * rstd * gm[i] + bt[i];
  *(float4*)&out[base]     = make_float4(o[0], o[1], o[2], o[3]);
  *(float4*)&out[base + 4] = make_float4(o[4], o[5], o[6], o[7]);
}

extern "C" void kernel_launch(void* const* d_in, const int* in_sizes, int n_in,
                              void* d_out, int out_size, void* d_ws, size_t ws_size,
                              hipStream_t stream) {
  (void)in_sizes; (void)n_in; (void)out_size; (void)ws_size;
  const float* src   = (const float*)d_in[0];
  const float* Wqk   = (const float*)d_in[1];
  const float* Wv    = (const float*)d_in[2];
  const float* Wout  = (const float*)d_in[3];
  const float* bout  = (const float*)d_in[4];
  const float* W1    = (const float*)d_in[5];
  const float* b1    = (const float*)d_in[6];
  const float* W2    = (const float*)d_in[7];
  const float* b2    = (const float*)d_in[8];
  const float* gamma = (const float*)d_in[9];
  const float* beta  = (const float*)d_in[10];
  const float* rot   = (const float*)d_in[11];
  float* out = (float*)d_out;

  // ---- workspace layout ----
  char* ws = (char*)d_ws;
  const size_t MB = 1024 * 1024;
  float*          qk      = (float*)(ws);                     // 32 MB; dead after hash
  unsigned short* src_b   = (unsigned short*)(ws + 32 * MB);  // 16 MB; live thru Wout resid
  unsigned short* v_b     = (unsigned short*)(ws + 48 * MB);  // 16 MB; -> x_b
  unsigned short* orows_b = (unsigned short*)(ws + 64 * MB);  // 64 MB; -> hidden_b
  unsigned short* qk_b    = (unsigned short*)(ws + 128 * MB); // 16 MB; -> ocomb_b
  char* p = ws + 144 * MB;
  float* logits  = (float*)p; p += (size_t)BH_ * T_ * NH_ * 4;
  int*   buckets = (int*)p;   p += (size_t)BH_ * NH_ * T_ * 4;
  int*   sticker = (int*)p;   p += (size_t)BH_ * NTICK_ * 4;
  int*   bstart  = (int*)p;   p += (size_t)BH_ * 256 * 4;
  float* invn    = (float*)p; p += (size_t)BH_ * T_ * 4;
  unsigned short* WqkvT = (unsigned short*)p; p += (size_t)1024 * 512 * 2;
  unsigned short* WoutT = (unsigned short*)p; p += (size_t)D_ * D_ * 2;
  unsigned short* W1T   = (unsigned short*)p; p += (size_t)FFN_ * D_ * 2;
  unsigned short* W2T   = (unsigned short*)p; p += (size_t)D_ * FFN_ * 2;

  unsigned short* ocomb_b  = qk_b;                 // after attn consumed qk_b
  unsigned short* x_b      = v_b;                  // after attn consumed v_b
  unsigned short* hidden_b = orows_b;              // after combine consumed orows
  unsigned short* ybuf_b   = (unsigned short*)ws;  // after hash consumed qk f32

  // 0: all conversions in one launch (weights + src convert)
  prep_all<<<2816 + M_ * D_ / 8 / 256, 256, 0, stream>>>(
      Wqk, Wv, Wout, W1, W2, src, WqkvT, WoutT, W1T, W2T, src_b);

  // 1: fused qk+v projection (K=512; qk cols emit fp32 + invn)
  gemm_bf16<128, 3, false, false, false>
      <<<dim3(1024 / 128, M_ / 128), 256, 0, stream>>>(
      src_b, WqkvT, nullptr, nullptr, qk, qk_b, v_b, invn,
      M_, 1024, D_, D_, D_, 0);
  // 2: LSH buckets (GEMM + fused argmax)
  hash_gemm_kernel<<<dim3(T_ / 128, BH_), 256, 0, stream>>>(qk, rot, buckets);
  // 3-4: counting sort
  hist_kernel<<<BH_, 256, 0, stream>>>(buckets, bstart);
  compact_kernel<<<dim3(256, BH_), 64, 0, stream>>>(buckets, bstart, sticker);
  // 5: chunked attention (MFMA)
  attn_kernel<<<dim3(CHUNKS_, BH_), 256, 0, stream>>>(
      qk_b, v_b, sticker, invn, orows_b, logits);
  // 6: combine hash rounds (writes into qk_b region)
  combine_kernel<<<BH_ * T_ / 4, 256, 0, stream>>>(orows_b, logits, ocomb_b);
  // 7: out projection + bias + residual(src_b)
  gemm_bf16<128, 1, true, false, true>
      <<<dim3(D_ / 128, M_ / 128), 256, 0, stream>>>(
      ocomb_b, WoutT, bout, src_b, nullptr, x_b, nullptr, nullptr,
      M_, D_, D_, D_, D_, D_);
  // 8: FFN1 (relu) — 256² 8-wave phase-interleaved kernel (T2+T3+T4+T5)
  gemm256_relu<<<dim3(FFN_ / 256, M_ / 256), 512, 0, stream>>>(
      x_b, W1T, b1, hidden_b, M_, FFN_, D_);
  // 9: FFN2 + bias + residual(x_b) -> bf16 y
  gemm_bf16<128, 1, true, false, true>
      <<<dim3(D_ / 128, M_ / 128), 256, 0, stream>>>(
      hidden_b, W2T, b2, x_b, nullptr, ybuf_b, nullptr, nullptr,
      M_, D_, FFN_, FFN_, FFN_, D_);
  // 10: LayerNorm
  ln_kernel<<<M_ / 4, 256, 0, stream>>>(ybuf_b, gamma, beta, out);
}

// Round 13
// 320.944 us; speedup vs baseline: 1.1885x; 1.0144x over previous
//
#include <hip/hip_runtime.h>

#define B_ 4
#define T_ 4096
#define D_ 512
#define H_ 8
#define DH_ 64
#define NH_ 4
#define NB_ 64            // n_buckets = T/BUCKET
#define BH_ (B_*H_)       // 32
#define CHUNKS_ (NH_*NB_) // 256
#define NTICK_ (NH_*T_)   // 16384
#define M_ (B_*T_)        // 16384
#define FFN_ 2048

typedef __attribute__((ext_vector_type(8))) short bf16x8;
typedef __attribute__((ext_vector_type(4))) float f32x4;

// ---------- bf16 helpers ----------
__device__ __forceinline__ unsigned short f2bf(float x) {
  unsigned int u = __float_as_uint(x);
  return (unsigned short)((u + 0x7FFFu + ((u >> 16) & 1u)) >> 16);
}
__device__ __forceinline__ float bf2f(unsigned short s) {
  return __uint_as_float(((unsigned int)s) << 16);
}
__device__ __forceinline__ unsigned int cvt_pk_bf16(float lo, float hi) {
  unsigned int r;
  asm("v_cvt_pk_bf16_f32 %0, %1, %2" : "=v"(r) : "v"(lo), "v"(hi));
  return r;
}

// ---------- async global->LDS, 16B per lane ----------
__device__ __forceinline__ void gld_lds16(const void* g, void* l) {
  __builtin_amdgcn_global_load_lds(
      (const __attribute__((address_space(1))) unsigned int*)g,
      (__attribute__((address_space(3))) unsigned int*)l, 16, 0, 0);
}

// swizzled LDS offsets (shorts): XOR 16B-granule with (row ^ row>>3)&7
__device__ __forceinline__ int swf(int row) { return (row ^ (row >> 3)) & 7; }
__device__ __forceinline__ int off64(int row, int k) {
  return row * 64 + (((k >> 3) ^ swf(row)) << 3) + (k & 7);
}
__device__ __forceinline__ int off128(int row, int k) {
  return row * 128 + (((k >> 3) ^ swf(row)) << 3) + (k & 7);
}

// ---------- 256x256 8-wave phase-interleaved GEMM (T2+T3+T4+T5) ----------
// OM=0: C = relu(A @ BT^T + bias), bf16 out at stride N (FFN1).
// OM=1: fused qkv — logical N=1024, K=512; qk blocks (n0<512) emit fp32 Cf
//       (stride 512) + bf16 Cb + fused per-head invnorm; v blocks emit Cb2.
// 512 threads. Per K-tile: 4 phases {stage half-tile t+1 || swizzled ds_read
// || 16 MFMA quadrant}; vmcnt(2)+barrier once per tile; end-of-tile barrier.
template<int OM>
__global__ __launch_bounds__(512) void gemm256(
    const unsigned short* __restrict__ A, const unsigned short* __restrict__ BT,
    const float* __restrict__ bias, unsigned short* __restrict__ Cb,
    unsigned short* __restrict__ Cb2, float* __restrict__ Cf,
    float* __restrict__ invn, int M, int N, int K)
{
  constexpr int ABSZ = 32768;   // shorts per buffer: A 256x64 + B 256x64
  __shared__ __align__(16) unsigned short smem[2 * ABSZ];
  const int tid = threadIdx.x;              // 0..511
  const int lane = tid & 63, w = tid >> 6;  // 8 waves
  const int wm = (w >> 2) * 128, wn = (w & 3) * 64;
  const int g = lane >> 4, cl = lane & 15;

  // XCD-aware block swizzle (T1)
  const int gx = gridDim.x;
  const int id = blockIdx.x + blockIdx.y * gx;
  const int cpx = (gx * gridDim.y) >> 3;
  const int swz = (id & 7) * cpx + (id >> 3);
  const int m0 = (swz / gx) * 256, n0 = (swz % gx) * 256;

  const bool isv = (OM == 1) && (n0 >= 512);

  f32x4 acc[8][4];
#pragma unroll
  for (int i = 0; i < 8; ++i)
#pragma unroll
    for (int j = 0; j < 4; ++j) acc[i][j] = (f32x4){0.f, 0.f, 0.f, 0.f};

  // stage one half-tile (128 rows x 64 k): 2 gld16/thread; linear LDS dest,
  // pre-swizzled global k-granule (rule #21: same involution as off64 read).
#define STG256(BUF, KB, P)                                                    \
  do {                                                                        \
    const bool isA_ = (P) < 2;                                                \
    const int half_ = (P) & 1;                                                \
    const unsigned short* Mp_ = isA_ ? A : BT;                                \
    const int gb_ = isA_ ? m0 : n0;                                           \
    const int ro_ = isA_ ? 0 : 16384;                                         \
    _Pragma("unroll")                                                         \
    for (int c2 = 0; c2 < 2; ++c2) {                                          \
      const int r_ = half_ * 128 + w * 16 + c2 * 8 + (lane >> 3);             \
      const int kg_ = (lane & 7) ^ swf(r_);                                   \
      gld_lds16(&Mp_[(size_t)(gb_ + r_) * K + (KB) + kg_ * 8],                \
                &smem[(BUF) * ABSZ + ro_ +                                    \
                      (half_ * 128 + w * 16 + c2 * 8) * 64 + lane * 8]);      \
    }                                                                         \
  } while (0)

  // prologue: all 4 half-tiles of tile 0 (8 gld/thread)
#pragma unroll
  for (int p = 0; p < 4; ++p) STG256(0, 0, p);

  const int KT = K >> 6;
  for (int kt = 0; kt < KT; ++kt) {
    const int cur = kt & 1;
    const unsigned short* As = smem + cur * ABSZ;
    const unsigned short* Bs = As + 16384;
#pragma unroll
    for (int p = 0; p < 4; ++p) {
      if (kt + 1 < KT) STG256(cur ^ 1, (kt + 1) * 64, p);
      if (p == 0) {
        if (kt + 1 < KT) asm volatile("s_waitcnt vmcnt(2)" ::: "memory");
        else             asm volatile("s_waitcnt vmcnt(0)" ::: "memory");
        __builtin_amdgcn_s_barrier();   // tile kt visible to all waves
      }
      const int rq = wm + (p >> 1) * 64, cq = wn + (p & 1) * 32;
      bf16x8 af[4][2], bfr[2][2];
#pragma unroll
      for (int i = 0; i < 4; ++i)
#pragma unroll
        for (int kk = 0; kk < 2; ++kk)
          af[i][kk] = *(const bf16x8*)&As[off64(rq + i * 16 + cl, kk * 32 + g * 8)];
#pragma unroll
      for (int j = 0; j < 2; ++j)
#pragma unroll
        for (int kk = 0; kk < 2; ++kk)
          bfr[j][kk] = *(const bf16x8*)&Bs[off64(cq + j * 16 + cl, kk * 32 + g * 8)];
      __builtin_amdgcn_s_setprio(1);
#pragma unroll
      for (int kk = 0; kk < 2; ++kk)
#pragma unroll
        for (int i = 0; i < 4; ++i)
#pragma unroll
          for (int j = 0; j < 2; ++j)
            acc[(p >> 1) * 4 + i][(p & 1) * 2 + j] =
                __builtin_amdgcn_mfma_f32_16x16x32_bf16(
                    af[i][kk], bfr[j][kk], acc[(p >> 1) * 4 + i][(p & 1) * 2 + j], 0, 0, 0);
      __builtin_amdgcn_s_setprio(0);
      if (p == 3) __builtin_amdgcn_s_barrier();  // tile kt reads done
    }
  }
#undef STG256

  // epilogue: acc -> swizzled 256x256 C-tile in LDS -> coalesced out
  float bv[4];
  if constexpr (OM == 0) {
#pragma unroll
    for (int j4 = 0; j4 < 4; ++j4) bv[j4] = bias[n0 + wn + j4 * 16 + cl];
  }
#pragma unroll
  for (int i = 0; i < 8; ++i) {
#pragma unroll
    for (int r = 0; r < 4; ++r) {
      const int lrow = wm + i * 16 + g * 4 + r;
      const int sw = (lrow & 7) << 3;
      float v4[4];
      float ss = 0.f;
#pragma unroll
      for (int j4 = 0; j4 < 4; ++j4) {
        float val = acc[i][j4][r];
        if constexpr (OM == 0) val = fmaxf(val + bv[j4], 0.f);
        v4[j4] = val;
        if constexpr (OM == 1) {
          if (!isv) {
            ss += val * val;
            Cf[(size_t)(m0 + lrow) * 512 + n0 + wn + j4 * 16 + cl] = val;
          }
        }
      }
#pragma unroll
      for (int j4 = 0; j4 < 4; j4 += 2) {
        const unsigned int pk = cvt_pk_bf16(v4[j4], v4[j4 + 1]);
        smem[lrow * 256 + ((wn + j4 * 16 + cl) ^ sw)]       = (unsigned short)pk;
        smem[lrow * 256 + ((wn + (j4 + 1) * 16 + cl) ^ sw)] = (unsigned short)(pk >> 16);
      }
      if constexpr (OM == 1) {
        if (!isv) {
          ss += __shfl_xor(ss, 1); ss += __shfl_xor(ss, 2);
          ss += __shfl_xor(ss, 4); ss += __shfl_xor(ss, 8);
          if (cl == 0) {
            const int m = m0 + lrow;
            const int bb = m >> 12, t = m & (T_ - 1);
            const int hh = ((n0 + wn) >> 6) & 7;
            invn[((size_t)(bb * 8 + hh)) * T_ + t] = 1.0f / (sqrtf(ss) + 1e-6f);
          }
        }
      }
    }
  }
  __syncthreads();
#pragma unroll
  for (int l = 0; l < 16; ++l) {
    const int idx = tid + l * 512;
    const int row = idx >> 5, c8 = (idx & 31) * 8;
    const uint4 u = *(const uint4*)&smem[row * 256 + (c8 ^ ((row & 7) << 3))];
    if constexpr (OM == 1) {
      if (isv)
        *(uint4*)&Cb2[(size_t)(m0 + row) * 512 + (n0 - 512) + c8] = u;
      else
        *(uint4*)&Cb[(size_t)(m0 + row) * 512 + n0 + c8] = u;
    } else {
      *(uint4*)&Cb[(size_t)(m0 + row) * N + n0 + c8] = u;
    }
  }
}

// ---------- bf16 MFMA GEMM (counted-vmcnt double-buffer), 128x128 ----------
// MODE 1: bf16 out (stride N). Used for Wout / FFN2 (N=512 shapes).
template<int BM, int MODE, bool HAS_BIAS, bool RELU, bool HAS_RESID>
__global__ __launch_bounds__(256) void gemm_bf16(
    const unsigned short* __restrict__ A, const unsigned short* __restrict__ BT,
    const float* __restrict__ bias, const unsigned short* __restrict__ resid,
    float* __restrict__ Cf, unsigned short* __restrict__ Cb,
    unsigned short* __restrict__ Cb2, float* __restrict__ invn,
    int M, int N, int K, int lda, int ldbt, int ldr)
{
  constexpr int MI = BM / 32;
  constexpr int ABSZ = (BM + 128) * 64;     // shorts per K-tile buffer (As|Bs)
  __shared__ __align__(16) unsigned short smem[2 * ABSZ];
  const int tid = threadIdx.x;
  const int lane = tid & 63;
  const int w = tid >> 6;
  const int wm = (w >> 1) * (BM / 2), wn = (w & 1) * 64;
  const int g = lane >> 4, cl = lane & 15;

  // XCD-aware block swizzle (T1)
  const int gx = gridDim.x;
  const int id = blockIdx.x + blockIdx.y * gx;
  const int cpx = (gx * gridDim.y) >> 3;
  const int swz = (id & 7) * cpx + (id >> 3);
  const int m0 = (swz / gx) * BM, n0 = (swz % gx) * 128;

  f32x4 acc[MI][4];
#pragma unroll
  for (int i = 0; i < MI; ++i)
#pragma unroll
    for (int j = 0; j < 4; ++j) acc[i][j] = (f32x4){0.f, 0.f, 0.f, 0.f};

  const int srow = tid >> 3;
  const int skc  = (tid & 7) * 8;

#define STAGE(BUF, K0)                                                        \
  do {                                                                        \
    unsigned short* As_ = smem + (BUF) * ABSZ;                                \
    unsigned short* Bs_ = As_ + BM * 64;                                      \
    _Pragma("unroll")                                                         \
    for (int ci = 0; ci < BM / 32; ++ci)                                      \
      gld_lds16(&A[(size_t)(m0 + ci * 32 + srow) * lda + (K0) + skc],         \
                &As_[ci * 2048 + tid * 8]);                                   \
    _Pragma("unroll")                                                         \
    for (int ci = 0; ci < 4; ++ci)                                            \
      gld_lds16(&BT[(size_t)(n0 + ci * 32 + srow) * ldbt + (K0) + skc],       \
                &Bs_[ci * 2048 + tid * 8]);                                   \
  } while (0)

  STAGE(0, 0);
  const int KT = K >> 6;
  for (int kt = 0; kt < KT; ++kt) {
    if (kt + 1 < KT) {
      STAGE((kt + 1) & 1, (kt + 1) * 64);
      asm volatile("s_waitcnt vmcnt(8)" ::: "memory");   // tile kt landed
    } else {
      asm volatile("s_waitcnt vmcnt(0)" ::: "memory");
    }
    __builtin_amdgcn_s_barrier();
    const unsigned short* As = smem + (kt & 1) * ABSZ;
    const unsigned short* Bs = As + BM * 64;
#pragma unroll
    for (int kk = 0; kk < 64; kk += 32) {
      bf16x8 af[MI], bfr[4];
#pragma unroll
      for (int i = 0; i < MI; ++i)
        af[i] = *(const bf16x8*)&As[(wm + i * 16 + cl) * 64 + kk + g * 8];
#pragma unroll
      for (int j = 0; j < 4; ++j)
        bfr[j] = *(const bf16x8*)&Bs[(wn + j * 16 + cl) * 64 + kk + g * 8];
#pragma unroll
      for (int i = 0; i < MI; ++i)
#pragma unroll
        for (int j = 0; j < 4; ++j)
          acc[i][j] = __builtin_amdgcn_mfma_f32_16x16x32_bf16(af[i], bfr[j], acc[i][j], 0, 0, 0);
    }
    asm volatile("" ::: "memory");
    __builtin_amdgcn_s_barrier();
  }
#undef STAGE

  // ---- epilogue: regs -> LDS C-tile (swizzled, in buf0) -> coalesced out
  float bv[4];
  if constexpr (HAS_BIAS) {
#pragma unroll
    for (int j = 0; j < 4; ++j) bv[j] = bias[n0 + wn + j * 16 + cl];
  }
#pragma unroll
  for (int i = 0; i < MI; ++i) {
#pragma unroll
    for (int r = 0; r < 4; ++r) {
      const int lrow = wm + i * 16 + g * 4 + r;
      float v4[4];
#pragma unroll
      for (int j = 0; j < 4; ++j) {
        float val = acc[i][j][r];
        if constexpr (HAS_BIAS) val += bv[j];
        if constexpr (RELU) val = fmaxf(val, 0.f);
        v4[j] = val;
      }
      const unsigned int p01 = cvt_pk_bf16(v4[0], v4[1]);
      const unsigned int p23 = cvt_pk_bf16(v4[2], v4[3]);
      const int sw = (lrow & 7) << 3;
      smem[lrow * 128 + ((wn +  0 + cl) ^ sw)] = (unsigned short)p01;
      smem[lrow * 128 + ((wn + 16 + cl) ^ sw)] = (unsigned short)(p01 >> 16);
      smem[lrow * 128 + ((wn + 32 + cl) ^ sw)] = (unsigned short)p23;
      smem[lrow * 128 + ((wn + 48 + cl) ^ sw)] = (unsigned short)(p23 >> 16);
    }
  }
  __syncthreads();
#pragma unroll
  for (int l = 0; l < BM / 16; ++l) {
    const int idx = tid + l * 256;
    const int row = idx >> 4, c8 = (idx & 15) * 8;
    uint4 u = *(const uint4*)&smem[row * 128 + (c8 ^ ((row & 7) << 3))];
    if constexpr (HAS_RESID) {
      const uint4 rv = *(const uint4*)&resid[(size_t)(m0 + row) * ldr + n0 + c8];
      const unsigned short* sp = (const unsigned short*)&u;
      const unsigned short* rp = (const unsigned short*)&rv;
      float f[8];
#pragma unroll
      for (int e = 0; e < 8; ++e) f[e] = bf2f(sp[e]) + bf2f(rp[e]);
      u.x = cvt_pk_bf16(f[0], f[1]); u.y = cvt_pk_bf16(f[2], f[3]);
      u.z = cvt_pk_bf16(f[4], f[5]); u.w = cvt_pk_bf16(f[6], f[7]);
    }
    *(uint4*)&Cb[(size_t)(m0 + row) * N + n0 + c8] = u;
  }
}

// ---------- fused prep: transpose 5 weights + convert src rows ----------
__global__ __launch_bounds__(256) void prep_all(
    const float* __restrict__ Wqk, const float* __restrict__ Wv,
    const float* __restrict__ Wout, const float* __restrict__ W1,
    const float* __restrict__ W2, const float* __restrict__ src,
    unsigned short* __restrict__ WqkvT, unsigned short* __restrict__ WoutT,
    unsigned short* __restrict__ W1T, unsigned short* __restrict__ W2T,
    unsigned short* __restrict__ src_b)
{
  __shared__ float tile[32][33];
  int bid = blockIdx.x;
  if (bid >= 2816) {
    const int i = (bid - 2816) * 256 + threadIdx.x;   // < M*D/8
    const int m = i >> 6, d0 = (i & 63) * 8;
    float x[8];
    *(float4*)&x[0] = *(const float4*)&src[(size_t)m * D_ + d0];
    *(float4*)&x[4] = *(const float4*)&src[(size_t)m * D_ + d0 + 4];
    unsigned short hi[8];
#pragma unroll
    for (int e = 0; e < 8; ++e) hi[e] = f2bf(x[e]);
    *(uint4*)&src_b[(size_t)m * D_ + d0] = *(const uint4*)&hi[0];
    return;
  }
  const float* W; unsigned short* WT; int K, N, bx, by;
  if (bid < 256)        { W = Wqk;  WT = WqkvT; K = 512;  N = 512;
                          bx = bid & 15; by = bid >> 4; }
  else if (bid < 512)   { bid -= 256;  W = Wv; WT = WqkvT + (size_t)512 * 512;
                          K = 512; N = 512;
                          bx = bid & 15; by = bid >> 4; }
  else if (bid < 768)   { bid -= 512;  W = Wout; WT = WoutT; K = 512;  N = 512;
                          bx = bid & 15; by = bid >> 4; }
  else if (bid < 1792)  { bid -= 768;  W = W1;   WT = W1T;   K = 512;  N = 2048;
                          bx = bid & 63; by = bid >> 6; }
  else                  { bid -= 1792; W = W2;   WT = W2T;   K = 2048; N = 512;
                          bx = bid & 15; by = bid >> 4; }
  const int k0 = by * 32, n0 = bx * 32;
  const int tx = threadIdx.x & 31, ty = threadIdx.x >> 5;
#pragma unroll
  for (int r = 0; r < 32; r += 8)
    tile[ty + r][tx] = W[(size_t)(k0 + ty + r) * N + n0 + tx];
  __syncthreads();
#pragma unroll
  for (int r = 0; r < 32; r += 8)
    WT[(size_t)(n0 + ty + r) * K + k0 + tx] = f2bf(tile[tx][ty + r]);
}

// ---------- LSH hashing as GEMM + fused argmax (reads fp32 qk) ----------
__global__ __launch_bounds__(256) void hash_gemm_kernel(
    const float* __restrict__ qk, const float* __restrict__ rot,
    int* __restrict__ buckets)
{
  __shared__ __align__(16) float As[64][136];   // [k][m]
  __shared__ __align__(16) float Bs[64][132];   // [k][n]
  const int tid = threadIdx.x;
  const int tx = tid & 15, ty = tid >> 4;
  const int t0 = blockIdx.x * 128, bh = blockIdx.y;
  const int b = bh >> 3, hd = bh & 7;

#pragma unroll
  for (int l = 0; l < 8; ++l) {
    const int idx = tid + l * 256;
    const int row = idx >> 4;
    const int kq = (idx & 15) << 2;
    const float4 a = *(const float4*)&qk[((size_t)b * T_ + t0 + row) * D_ + hd * DH_ + kq];
    As[kq + 0][row] = a.x; As[kq + 1][row] = a.y;
    As[kq + 2][row] = a.z; As[kq + 3][row] = a.w;
  }
#pragma unroll
  for (int l = 0; l < 8; ++l) {
    const int idx = tid + l * 256;
    const int kr = idx >> 5;
    const int c4 = (idx & 31) << 2;
    *(float4*)&Bs[kr][c4] = *(const float4*)&rot[kr * 128 + c4];
  }
  __syncthreads();

  float acc[8][8];
#pragma unroll
  for (int i = 0; i < 8; ++i)
#pragma unroll
    for (int j = 0; j < 8; ++j) acc[i][j] = 0.f;

#pragma unroll 4
  for (int kk = 0; kk < 64; ++kk) {
    float a[8], bq[8];
    *(float4*)&a[0]  = *(const float4*)&As[kk][ty * 8];
    *(float4*)&a[4]  = *(const float4*)&As[kk][ty * 8 + 4];
    *(float4*)&bq[0] = *(const float4*)&Bs[kk][tx * 8];
    *(float4*)&bq[4] = *(const float4*)&Bs[kk][tx * 8 + 4];
#pragma unroll
    for (int i = 0; i < 8; ++i)
#pragma unroll
      for (int j = 0; j < 8; ++j)
        acc[i][j] = fmaf(a[i], bq[j], acc[i][j]);
  }
  __syncthreads();

  float* pval = &As[0][0];
  int*   pidx = (int*)&Bs[0][0];
  const int i0 = (tx & 3) * 8;
#pragma unroll
  for (int r = 0; r < 8; ++r) {
    float v = -3.0e38f; int idx = 127;
#pragma unroll
    for (int j = 0; j < 8; ++j) {
      const float p = acc[r][j];
      const int li = i0 + j;
      if (p > v || (p == v && li < idx)) { v = p; idx = li; }
      const float n = -p;
      const int ni = 32 + li;
      if (n > v || (n == v && ni < idx)) { v = n; idx = ni; }
    }
    pval[(ty * 8 + r) * 16 + tx] = v;
    pidx[(ty * 8 + r) * 16 + tx] = idx;
  }
  __syncthreads();

#pragma unroll
  for (int l = 0; l < 2; ++l) {
    const int id = tid + l * 256;
    const int tok = id >> 2, hh = id & 3;
    float v = pval[tok * 16 + hh * 4];
    int idx = pidx[tok * 16 + hh * 4];
#pragma unroll
    for (int e = 1; e < 4; ++e) {
      const float ov = pval[tok * 16 + hh * 4 + e];
      const int oi = pidx[tok * 16 + hh * 4 + e];
      if (ov > v || (ov == v && oi < idx)) { v = ov; idx = oi; }
    }
    buckets[((size_t)bh * NH_ + hh) * T_ + t0 + tok] = idx + hh * NB_;
  }
}

// ---------- per-bh bucket histogram + exclusive scan ----------
__global__ __launch_bounds__(256) void hist_kernel(
    const int* __restrict__ buckets, int* __restrict__ bstart)
{
  __shared__ int bins[256];
  const int bh = blockIdx.x;
  bins[threadIdx.x] = 0;
  __syncthreads();
  for (int e = threadIdx.x; e < NTICK_; e += 256)
    atomicAdd(&bins[buckets[(size_t)bh * NTICK_ + e]], 1);
  __syncthreads();
  if (threadIdx.x == 0) {
    int run = 0;
    for (int i = 0; i < 256; ++i) { const int c = bins[i]; bins[i] = run; run += c; }
  }
  __syncthreads();
  bstart[bh * 256 + threadIdx.x] = bins[threadIdx.x];
}

// ---------- stable compaction ----------
__global__ __launch_bounds__(64) void compact_kernel(
    const int* __restrict__ buckets, const int* __restrict__ bstart,
    int* __restrict__ sticker)
{
  const int bucket = blockIdx.x, bh = blockIdx.y;
  const int h = bucket >> 6;
  const int lane = threadIdx.x;
  int base = bstart[bh * 256 + bucket];
  const int* bk = buckets + (size_t)bh * NTICK_ + (size_t)h * T_;
  for (int it = 0; it < 64; ++it) {
    const int t = it * 64 + lane;
    const bool m = (bk[t] == bucket);
    const unsigned long long bal = __ballot(m);
    if (m) {
      const int pos = base + __popcll(bal & ((1ull << lane) - 1ull));
      sticker[(size_t)bh * NTICK_ + pos] = h * T_ + t;
    }
    base += __popcll(bal);
  }
}

// ---------- chunked LSH attention — MFMA, async staging ----------
__global__ __launch_bounds__(256) void attn_kernel(
    const unsigned short* __restrict__ qkb, const unsigned short* __restrict__ vb,
    const int* __restrict__ sticker, const float* __restrict__ invn,
    unsigned short* __restrict__ orowsb, float* __restrict__ logits)
{
  __shared__ __align__(16) unsigned short Rs[128 * 64];
  __shared__ __align__(16) unsigned short Vs[128 * 64];
  __shared__ int tks[128];
  __shared__ float invs[128];

  const int cx = blockIdx.x;
  const int c = (cx & 7) * 32 + (cx >> 3);   // XCD-aware chunk swizzle
  const int bh = blockIdx.y;
  const int b = bh >> 3, hd = bh & 7;
  const int tid = threadIdx.x;
  const int hr = c >> 6;
  const int w = tid >> 6, lane = tid & 63, g = lane >> 4, cl = lane & 15;

  if (tid < 128) {
    const int sc = (tid < 64) ? c : ((c + CHUNKS_ - 1) & (CHUNKS_ - 1));
    const int tick = sticker[(size_t)bh * NTICK_ + sc * 64 + (tid & 63)];
    const int t = tick & (T_ - 1);
    tks[tid] = t;
    invs[tid] = invn[bh * T_ + t];
  }
  __syncthreads();

  // stage qk + v rows via global_load_lds: linear LDS dest, pre-swizzled source
  {
    const int sr = lane >> 3, gq = lane & 7;
#pragma unroll
    for (int l = 0; l < 4; ++l) {
      const int row = l * 32 + w * 8 + sr;
      const size_t gb = ((size_t)b * T_ + tks[row]) * D_ + hd * DH_
                      + ((gq ^ swf(row)) << 3);
      const int dst = (l * 32 + w * 8) * 64 + lane * 8;
      gld_lds16(&qkb[gb], &Rs[dst]);
      gld_lds16(&vb[gb],  &Vs[dst]);
    }
  }
  __syncthreads();

  // dots (MFMA from Rs) + V transpose-read (b64) into regs
  f32x4 sacc[8];
#pragma unroll
  for (int j = 0; j < 8; ++j) sacc[j] = (f32x4){0.f, 0.f, 0.f, 0.f};
  __builtin_amdgcn_s_setprio(1);
#pragma unroll
  for (int kk = 0; kk < 2; ++kk) {
    const bf16x8 aq = *(const bf16x8*)&Rs[off64(w * 16 + cl, kk * 32 + g * 8)];
#pragma unroll
    for (int j = 0; j < 8; ++j) {
      const bf16x8 bk = *(const bf16x8*)&Rs[off64(j * 16 + cl, kk * 32 + g * 8)];
      sacc[j] = __builtin_amdgcn_mfma_f32_16x16x32_bf16(aq, bk, sacc[j], 0, 0, 0);
    }
  }
  __builtin_amdgcn_s_setprio(0);
  const int d0 = (tid & 15) * 4, tg = tid >> 4;
  unsigned int qw[8][2];
#pragma unroll
  for (int e = 0; e < 8; ++e) {
    const uint2 q = *(const uint2*)&Vs[off64(tg * 8 + e, d0)];
    qw[e][0] = q.x; qw[e][1] = q.y;
  }
  __syncthreads();

  // write V^T into Vs region; softmax (skip-max) -> unnormalized P into Rs
  {
    unsigned short col[4][8];
#pragma unroll
    for (int e = 0; e < 8; ++e) {
      col[0][e] = (unsigned short)(qw[e][0] & 0xffffu);
      col[1][e] = (unsigned short)(qw[e][0] >> 16);
      col[2][e] = (unsigned short)(qw[e][1] & 0xffffu);
      col[3][e] = (unsigned short)(qw[e][1] >> 16);
    }
#pragma unroll
    for (int dd = 0; dd < 4; ++dd)
      *(uint4*)&Vs[off128(d0 + dd, tg * 8)] = *(const uint4*)&col[dd][0];
  }

  float iv[8]; int tk[8];
#pragma unroll
  for (int j = 0; j < 8; ++j) {
    iv[j] = invs[j * 16 + cl] * 0.125f;
    tk[j] = tks[j * 16 + cl];
  }
  float pinv[4];
#pragma unroll
  for (int r = 0; r < 4; ++r) {
    const int row = w * 16 + g * 4 + r;
    const int tq = tks[row];
    float e8[8];
    float sum = 0.f;
#pragma unroll
    for (int j = 0; j < 8; ++j) {
      float e = __expf(sacc[j][r] * iv[j]);
      if (tq == tk[j]) e = 0.f;
      e8[j] = e;
      sum += e;
    }
    sum += __shfl_xor(sum, 1); sum += __shfl_xor(sum, 2);
    sum += __shfl_xor(sum, 4); sum += __shfl_xor(sum, 8);
    pinv[r] = 1.f / sum;
#pragma unroll
    for (int j = 0; j < 8; j += 2) {
      const unsigned int pk = cvt_pk_bf16(e8[j], e8[j + 1]);
      Rs[off128(row, j * 16 + cl)]       = (unsigned short)pk;
      Rs[off128(row, (j + 1) * 16 + cl)] = (unsigned short)(pk >> 16);
    }
    if (cl == 0)
      logits[((size_t)bh * T_ + tq) * NH_ + hr] = __logf(sum);
  }
  __syncthreads();

  // PV: A = P (Rs), B = V^T (Vs)
  f32x4 oacc[4];
#pragma unroll
  for (int jd = 0; jd < 4; ++jd) oacc[jd] = (f32x4){0.f, 0.f, 0.f, 0.f};
  __builtin_amdgcn_s_setprio(1);
#pragma unroll
  for (int ks = 0; ks < 4; ++ks) {
    const bf16x8 pa = *(const bf16x8*)&Rs[off128(w * 16 + cl, ks * 32 + g * 8)];
#pragma unroll
    for (int jd = 0; jd < 4; ++jd) {
      const bf16x8 vv = *(const bf16x8*)&Vs[off128(jd * 16 + cl, ks * 32 + g * 8)];
      oacc[jd] = __builtin_amdgcn_mfma_f32_16x16x32_bf16(pa, vv, oacc[jd], 0, 0, 0);
    }
  }
  __builtin_amdgcn_s_setprio(0);
  __syncthreads();

  // O (scaled by 1/sum) into Rs, then coalesced scatter to global
#pragma unroll
  for (int r = 0; r < 4; ++r) {
    const int row = w * 16 + g * 4 + r;
    const unsigned int q01 = cvt_pk_bf16(oacc[0][r] * pinv[r], oacc[1][r] * pinv[r]);
    const unsigned int q23 = cvt_pk_bf16(oacc[2][r] * pinv[r], oacc[3][r] * pinv[r]);
    Rs[off64(row,      cl)] = (unsigned short)q01;
    Rs[off64(row, 16 + cl)] = (unsigned short)(q01 >> 16);
    Rs[off64(row, 32 + cl)] = (unsigned short)q23;
    Rs[off64(row, 48 + cl)] = (unsigned short)(q23 >> 16);
  }
  __syncthreads();

#pragma unroll
  for (int l = 0; l < 2; ++l) {
    const int idx = tid + l * 256;
    const int row = idx >> 3, k0 = (idx & 7) * 8;
    *(uint4*)&orowsb[(((size_t)bh * T_ + tks[row]) * NH_ + hr) * DH_ + k0] =
        *(const uint4*)&Rs[off64(row, k0)];
  }
}

// ---------- combine hash rounds (contiguous per-token layout) ----------
__global__ __launch_bounds__(256) void combine_kernel(
    const unsigned short* __restrict__ orowsb, const float* __restrict__ logits,
    unsigned short* __restrict__ ocombb)
{
  const int gid = blockIdx.x * 4 + (threadIdx.x >> 6);
  const int lane = threadIdx.x & 63;
  const int bh = gid >> 12, t = gid & (T_ - 1);
  const int b = bh >> 3, hd = bh & 7;
  const float4 lg = *(const float4*)&logits[((size_t)bh * T_ + t) * NH_];
  const float m = fmaxf(fmaxf(lg.x, lg.y), fmaxf(lg.z, lg.w));
  const float w0 = __expf(lg.x - m), w1 = __expf(lg.y - m);
  const float w2 = __expf(lg.z - m), w3 = __expf(lg.w - m);
  const float inv = 1.f / (w0 + w1 + w2 + w3);
  const size_t rb = ((size_t)bh * T_ + t) * (NH_ * DH_) + lane;
  const float o = w0 * bf2f(orowsb[rb])
                + w1 * bf2f(orowsb[rb + DH_])
                + w2 * bf2f(orowsb[rb + 2 * DH_])
                + w3 * bf2f(orowsb[rb + 3 * DH_]);
  ocombb[((size_t)b * T_ + t) * D_ + hd * DH_ + lane] = f2bf(o * inv);
}

// ---------- LayerNorm (bf16 in, fp32 out) ----------
__global__ __launch_bounds__(256) void ln_kernel(
    const unsigned short* __restrict__ yb, const float* __restrict__ gamma,
    const float* __restrict__ beta, float* __restrict__ out)
{
  const int row = blockIdx.x * 4 + (threadIdx.x >> 6);
  const int lane = threadIdx.x & 63;
  const size_t base = (size_t)row * D_ + lane * 8;
  const uint4 u = *(const uint4*)&yb[base];
  const unsigned short* up = (const unsigned short*)&u;
  float x[8];
#pragma unroll
  for (int i = 0; i < 8; ++i) x[i] = bf2f(up[i]);
  float s = 0.f;
#pragma unroll
  for (int i = 0; i < 8; ++i) s += x[i];
#pragma unroll
  for (int m = 32; m >= 1; m >>= 1) s += __shfl_xor(s, m);
  const float mu = s * (1.f / D_);
  float vs = 0.f;
#pragma unroll
  for (int i = 0; i < 8; ++i) { const float d = x[i] - mu; vs += d * d; }
#pragma unroll
  for (int m = 32; m >= 1; m >>= 1) vs += __shfl_xor(vs, m);
  const float rstd = rsqrtf(vs * (1.f / D_) + 1e-6f);
  float gm[8], bt[8];
  *(float4*)&gm[0] = *(const float4*)&gamma[lane * 8];
  *(float4*)&gm[4] = *(const float4*)&gamma[lane * 8 + 4];
  *(float4*)&bt[0] = *(const float4*)&beta[lane * 8];
  *(float4*)&bt[4] = *(const float4*)&beta[lane * 8 + 4];
  float o[8];
#pragma unroll
  for (int i = 0; i < 8; ++i) o[i] = (x[i] - mu) * rstd * gm[i] + bt[i];
  *(float4*)&out[base]     = make_float4(o[0], o[1], o[2], o[3]);
  *(float4*)&out[base + 4] = make_float4(o[4], o[5], o[6], o[7]);
}

extern "C" void kernel_launch(void* const* d_in, const int* in_sizes, int n_in,
                              void* d_out, int out_size, void* d_ws, size_t ws_size,
                              hipStream_t stream) {
  (void)in_sizes; (void)n_in; (void)out_size; (void)ws_size;
  const float* src   = (const float*)d_in[0];
  const float* Wqk   = (const float*)d_in[1];
  const float* Wv    = (const float*)d_in[2];
  const float* Wout  = (const float*)d_in[3];
  const float* bout  = (const float*)d_in[4];
  const float* W1    = (const float*)d_in[5];
  const float* b1    = (const float*)d_in[6];
  const float* W2    = (const float*)d_in[7];
  const float* b2    = (const float*)d_in[8];
  const float* gamma = (const float*)d_in[9];
  const float* beta  = (const float*)d_in[10];
  const float* rot   = (const float*)d_in[11];
  float* out = (float*)d_out;

  // ---- workspace layout ----
  char* ws = (char*)d_ws;
  const size_t MB = 1024 * 1024;
  float*          qk      = (float*)(ws);                     // 32 MB; dead after hash
  unsigned short* src_b   = (unsigned short*)(ws + 32 * MB);  // 16 MB; live thru Wout resid
  unsigned short* v_b     = (unsigned short*)(ws + 48 * MB);  // 16 MB; -> x_b
  unsigned short* orows_b = (unsigned short*)(ws + 64 * MB);  // 64 MB; -> hidden_b
  unsigned short* qk_b    = (unsigned short*)(ws + 128 * MB); // 16 MB; -> ocomb_b
  char* p = ws + 144 * MB;
  float* logits  = (float*)p; p += (size_t)BH_ * T_ * NH_ * 4;
  int*   buckets = (int*)p;   p += (size_t)BH_ * NH_ * T_ * 4;
  int*   sticker = (int*)p;   p += (size_t)BH_ * NTICK_ * 4;
  int*   bstart  = (int*)p;   p += (size_t)BH_ * 256 * 4;
  float* invn    = (float*)p; p += (size_t)BH_ * T_ * 4;
  unsigned short* WqkvT = (unsigned short*)p; p += (size_t)1024 * 512 * 2;
  unsigned short* WoutT = (unsigned short*)p; p += (size_t)D_ * D_ * 2;
  unsigned short* W1T   = (unsigned short*)p; p += (size_t)FFN_ * D_ * 2;
  unsigned short* W2T   = (unsigned short*)p; p += (size_t)D_ * FFN_ * 2;

  unsigned short* ocomb_b  = qk_b;                 // after attn consumed qk_b
  unsigned short* x_b      = v_b;                  // after attn consumed v_b
  unsigned short* hidden_b = orows_b;              // after combine consumed orows
  unsigned short* ybuf_b   = (unsigned short*)ws;  // after hash consumed qk f32

  // 0: all conversions in one launch (weights + src convert)
  prep_all<<<2816 + M_ * D_ / 8 / 256, 256, 0, stream>>>(
      Wqk, Wv, Wout, W1, W2, src, WqkvT, WoutT, W1T, W2T, src_b);

  // 1: fused qk+v projection — 256² 8-phase (OM=1): qk fp32+bf16+invn, v bf16
  gemm256<1><<<dim3(1024 / 256, M_ / 256), 512, 0, stream>>>(
      src_b, WqkvT, nullptr, qk_b, v_b, qk, invn, M_, 1024, D_);
  // 2: LSH buckets (GEMM + fused argmax)
  hash_gemm_kernel<<<dim3(T_ / 128, BH_), 256, 0, stream>>>(qk, rot, buckets);
  // 3-4: counting sort
  hist_kernel<<<BH_, 256, 0, stream>>>(buckets, bstart);
  compact_kernel<<<dim3(256, BH_), 64, 0, stream>>>(buckets, bstart, sticker);
  // 5: chunked attention (MFMA)
  attn_kernel<<<dim3(CHUNKS_, BH_), 256, 0, stream>>>(
      qk_b, v_b, sticker, invn, orows_b, logits);
  // 6: combine hash rounds (writes into qk_b region)
  combine_kernel<<<BH_ * T_ / 4, 256, 0, stream>>>(orows_b, logits, ocomb_b);
  // 7: out projection + bias + residual(src_b)
  gemm_bf16<128, 1, true, false, true>
      <<<dim3(D_ / 128, M_ / 128), 256, 0, stream>>>(
      ocomb_b, WoutT, bout, src_b, nullptr, x_b, nullptr, nullptr,
      M_, D_, D_, D_, D_, D_);
  // 8: FFN1 (relu) — 256² 8-phase (OM=0)
  gemm256<0><<<dim3(FFN_ / 256, M_ / 256), 512, 0, stream>>>(
      x_b, W1T, b1, hidden_b, nullptr, nullptr, nullptr, M_, FFN_, D_);
  // 9: FFN2 + bias + residual(x_b) -> bf16 y
  gemm_bf16<128, 1, true, false, true>
      <<<dim3(D_ / 128, M_ / 128), 256, 0, stream>>>(
      hidden_b, W2T, b2, x_b, nullptr, ybuf_b, nullptr, nullptr,
      M_, D_, FFN_, FFN_, FFN_, D_);
  // 10: LayerNorm
  ln_kernel<<<M_ / 4, 256, 0, stream>>>(ybuf_b, gamma, beta, out);
}